// Round 1
// baseline (1707.219 us; speedup 1.0000x reference)
//
#include <hip/hip_runtime.h>

// AWFLN forward. All layers map onto one templated direct-conv kernel:
//   out[o,hw] = EPI( bias[o] + sum_{ic,p} w[o,ic,p] * att[p,hw] * in[ic, hw+d(p)] )
// EPI: 0=none 1=prelu 2=softmax-over-9-channels 3=+res,relu 4=+res
// HAS_ATT=false -> att[p]=1 (ordinary conv). Zero-padding folded into mul[p].

template<int CIN, int COUT, int OCB, int DIL, int H, int W, int EPI, bool HAS_ATT>
__launch_bounds__(256)
__global__ void conv_k(const float* __restrict__ in,
                       const float* __restrict__ wgt,
                       const float* __restrict__ bias,
                       const float* __restrict__ att,
                       const float* __restrict__ res,
                       const float* __restrict__ pal,
                       float* __restrict__ out,
                       int out_ctot, int out_coff, int res_ctot)
{
    constexpr int HWp  = H * W;
    constexpr int NOCB = COUT / OCB;
    const int tx = threadIdx.x;
    const int lx = tx & 63, ly = tx >> 6;
    const int gx = blockIdx.x * 64 + lx;
    const int gy = blockIdx.y * 4 + ly;
    const int b   = blockIdx.z / NOCB;
    const int ocb = blockIdx.z % NOCB;
    const int pix = gy * W + gx;

    const float* inb = in + (size_t)b * CIN * HWp;

    int   off[9];
    float mul[9];
#pragma unroll
    for (int dy = 0; dy < 3; ++dy) {
#pragma unroll
        for (int dx = 0; dx < 3; ++dx) {
            int p  = dy * 3 + dx;
            int yy = gy + (dy - 1) * DIL;
            int xx = gx + (dx - 1) * DIL;
            bool ok = ((unsigned)yy < (unsigned)H) && ((unsigned)xx < (unsigned)W);
            off[p] = ok ? (yy * W + xx) : 0;
            mul[p] = ok ? 1.f : 0.f;
        }
    }
    if (HAS_ATT) {
#pragma unroll
        for (int p = 0; p < 9; ++p)
            mul[p] *= __ldg(att + ((size_t)b * 9 + p) * HWp + pix);
    }

    float acc[OCB];
#pragma unroll
    for (int o = 0; o < OCB; ++o) acc[o] = 0.f;

    const float* wbase = wgt + (size_t)(ocb * OCB) * CIN * 9;

#pragma unroll 1
    for (int ic = 0; ic < CIN; ++ic) {
        const float* ip = inb + (size_t)ic * HWp;
        float t[9];
#pragma unroll
        for (int p = 0; p < 9; ++p) t[p] = __ldg(ip + off[p]) * mul[p];
#pragma unroll
        for (int o = 0; o < OCB; ++o) {
            const float* wp = wbase + (size_t)(o * CIN + ic) * 9;
#pragma unroll
            for (int p = 0; p < 9; ++p) acc[o] = fmaf(t[p], wp[p], acc[o]);
        }
    }

    if (bias) {
#pragma unroll
        for (int o = 0; o < OCB; ++o) acc[o] += __ldg(bias + ocb * OCB + o);
    }

    if (EPI == 2) {  // channel softmax (OCB == COUT == 9)
        float m = acc[0];
#pragma unroll
        for (int o = 1; o < OCB; ++o) m = fmaxf(m, acc[o]);
        float s = 0.f;
#pragma unroll
        for (int o = 0; o < OCB; ++o) { acc[o] = __expf(acc[o] - m); s += acc[o]; }
        float inv = 1.f / s;
#pragma unroll
        for (int o = 0; o < OCB; ++o) acc[o] *= inv;
    }

    float alpha = (EPI == 1) ? __ldg(pal) : 0.f;

#pragma unroll
    for (int o = 0; o < OCB; ++o) {
        int oc = out_coff + ocb * OCB + o;
        float v = acc[o];
        if (EPI == 1) v = (v >= 0.f) ? v : alpha * v;
        if (EPI == 3) { v += __ldg(res + ((size_t)b * res_ctot + oc) * HWp + pix); v = fmaxf(v, 0.f); }
        if (EPI == 4) { v += __ldg(res + ((size_t)b * res_ctot + oc) * HWp + pix); }
        out[((size_t)b * out_ctot + oc) * HWp + pix] = v;
    }
}

// data1 = concat([prelu(pixel_shuffle(t_up, 4), a), pan], ch). t_up: [2,64,64,64]
__global__ __launch_bounds__(256) void build_data1_k(const float* __restrict__ t_up,
                                                     const float* __restrict__ pan,
                                                     const float* __restrict__ a_up4,
                                                     float* __restrict__ data1)
{
    int i = blockIdx.x * 256 + threadIdx.x;   // 2*5*65536 total, exact grid
    int px = i & 65535;
    int c  = (i >> 16) % 5;
    int b  = i / (5 * 65536);
    float v;
    if (c == 4) {
        v = pan[b * 65536 + px];
    } else {
        int y = px >> 8, x = px & 255;
        int ch = c * 16 + (y & 3) * 4 + (x & 3);
        v = t_up[((size_t)b * 64 + ch) * 4096 + (y >> 2) * 64 + (x >> 2)];
        float a = __ldg(a_up4);
        v = (v >= 0.f) ? v : a * v;
    }
    data1[i] = v;
}

extern "C" void kernel_launch(void* const* d_in, const int* in_sizes, int n_in,
                              void* d_out, int out_size, void* d_ws, size_t ws_size,
                              hipStream_t stream) {
    const float* ms_up  = (const float*)d_in[0];
    const float* ms_org = (const float*)d_in[1];
    const float* pan    = (const float*)d_in[2];
    const float* w_up4  = (const float*)d_in[3];
    const float* b_up4  = (const float*)d_in[4];
    const float* a_up4  = (const float*)d_in[5];
    const float* w_blk53= (const float*)d_in[6];
    const float* b_blk53= (const float*)d_in[7];
    const float* a_blk53= (const float*)d_in[8];
    const float* w_blk43= (const float*)d_in[9];
    const float* b_blk43= (const float*)d_in[10];
    const float* a_blk43= (const float*)d_in[11];
    const float* w1a=(const float*)d_in[12]; const float* b1a=(const float*)d_in[13];
    const float* w1b=(const float*)d_in[14]; const float* b1b=(const float*)d_in[15];
    const float* w1c=(const float*)d_in[16]; const float* b1c=(const float*)d_in[17];
    const float* aw1=(const float*)d_in[18]; const float* ab1=(const float*)d_in[19];
    const float* fw1=(const float*)d_in[20];
    const float* aw2=(const float*)d_in[21]; const float* ab2=(const float*)d_in[22];
    const float* fw2=(const float*)d_in[23];
    const float* w_blk2=(const float*)d_in[24]; const float* b_blk2=(const float*)d_in[25]; const float* a_blk2=(const float*)d_in[26];
    const float* w2a=(const float*)d_in[27]; const float* b2a=(const float*)d_in[28];
    const float* w2b=(const float*)d_in[29]; const float* b2b=(const float*)d_in[30];
    const float* w2c=(const float*)d_in[31]; const float* b2c=(const float*)d_in[32];
    const float* aw3=(const float*)d_in[33]; const float* ab3=(const float*)d_in[34];
    const float* fw3=(const float*)d_in[35];
    const float* aw4=(const float*)d_in[36]; const float* ab4=(const float*)d_in[37];
    const float* fw4=(const float*)d_in[38];
    const float* w_c6=(const float*)d_in[39]; const float* b_c6=(const float*)d_in[40];

    float* out = (float*)d_out;
    float* ws  = (float*)d_ws;

    // layout (floats): bufA/bufB/bufC = 2*60*65536 each, bufAtt = 2*9*65536
    float* bufA   = ws;
    float* bufB   = ws + 7864320;
    float* bufC   = ws + 15728640;
    float* bufAtt = ws + 23592960;
    // t_up (2*64*4096) and data1 (2*5*65536) live in bufC's region (dead by the
    // time bufC is first written at the aflb1 output).
    float* t_up  = bufC;
    float* data1 = bufC + 524288;

    if (ws_size < (size_t)(23592960 + 1179648) * sizeof(float)) return;

    dim3 blk(256, 1, 1);

    // 1. up-conv: ms_org [2,4,64,64] -> t_up [2,64,64,64]
    conv_k<4,64,16,1,64,64,0,false><<<dim3(1,16,8),blk,0,stream>>>(
        ms_org, w_up4, b_up4, nullptr, nullptr, nullptr, t_up, 64, 0, 0);
    // 2. data1 = [prelu(pixshuf(t_up)), pan]  [2,5,256,256]
    build_data1_k<<<dim3(2560),blk,0,stream>>>(t_up, pan, a_up4, data1);
    // 3/4. out1 (bufA, 60ch) = [prelu(conv(ms_up,w_blk43)), prelu(conv(data1,w_blk53))]
    conv_k<5,30,30,1,256,256,1,false><<<dim3(4,64,2),blk,0,stream>>>(
        data1, w_blk53, b_blk53, nullptr, nullptr, a_blk53, bufA, 60, 30, 0);
    conv_k<4,30,30,1,256,256,1,false><<<dim3(4,64,2),blk,0,stream>>>(
        ms_up, w_blk43, b_blk43, nullptr, nullptr, a_blk43, bufA, 60, 0, 0);

    // ---- rmrs1 (60 ch) ----
    conv_k<60,20,20,1,256,256,0,false><<<dim3(4,64,2),blk,0,stream>>>(
        bufA, w1a, b1a, nullptr, nullptr, nullptr, bufB, 60, 0, 0);
    conv_k<60,20,20,2,256,256,0,false><<<dim3(4,64,2),blk,0,stream>>>(
        bufA, w1b, b1b, nullptr, nullptr, nullptr, bufB, 60, 20, 0);
    conv_k<60,20,20,3,256,256,0,false><<<dim3(4,64,2),blk,0,stream>>>(
        bufA, w1c, b1c, nullptr, nullptr, nullptr, bufB, 60, 40, 0);
    // aflb1: att = softmax(conv(bufB, aw1)); bufC = modconv(bufB, fw1, att)
    conv_k<60,9,9,1,256,256,2,false><<<dim3(4,64,2),blk,0,stream>>>(
        bufB, aw1, ab1, nullptr, nullptr, nullptr, bufAtt, 9, 0, 0);
    conv_k<60,60,30,1,256,256,0,true><<<dim3(4,64,4),blk,0,stream>>>(
        bufB, fw1, nullptr, bufAtt, nullptr, nullptr, bufC, 60, 0, 0);
    // aflb2 + residual relu -> bufB = out2
    conv_k<60,9,9,1,256,256,2,false><<<dim3(4,64,2),blk,0,stream>>>(
        bufC, aw2, ab2, nullptr, nullptr, nullptr, bufAtt, 9, 0, 0);
    conv_k<60,60,30,1,256,256,3,true><<<dim3(4,64,4),blk,0,stream>>>(
        bufC, fw2, nullptr, bufAtt, bufA, nullptr, bufB, 60, 0, 60);

    // 6. out3 = prelu(conv(out2, w_blk2))  -> bufA (30 ch)
    conv_k<60,30,30,1,256,256,1,false><<<dim3(4,64,2),blk,0,stream>>>(
        bufB, w_blk2, b_blk2, nullptr, nullptr, a_blk2, bufA, 30, 0, 0);

    // ---- rmrs2 (30 ch) ----
    conv_k<30,10,10,1,256,256,0,false><<<dim3(4,64,2),blk,0,stream>>>(
        bufA, w2a, b2a, nullptr, nullptr, nullptr, bufC, 30, 0, 0);
    conv_k<30,10,10,2,256,256,0,false><<<dim3(4,64,2),blk,0,stream>>>(
        bufA, w2b, b2b, nullptr, nullptr, nullptr, bufC, 30, 10, 0);
    conv_k<30,10,10,3,256,256,0,false><<<dim3(4,64,2),blk,0,stream>>>(
        bufA, w2c, b2c, nullptr, nullptr, nullptr, bufC, 30, 20, 0);
    conv_k<30,9,9,1,256,256,2,false><<<dim3(4,64,2),blk,0,stream>>>(
        bufC, aw3, ab3, nullptr, nullptr, nullptr, bufAtt, 9, 0, 0);
    conv_k<30,30,30,1,256,256,0,true><<<dim3(4,64,2),blk,0,stream>>>(
        bufC, fw3, nullptr, bufAtt, nullptr, nullptr, bufB, 30, 0, 0);
    conv_k<30,9,9,1,256,256,2,false><<<dim3(4,64,2),blk,0,stream>>>(
        bufB, aw4, ab4, nullptr, nullptr, nullptr, bufAtt, 9, 0, 0);
    conv_k<30,30,30,1,256,256,3,true><<<dim3(4,64,2),blk,0,stream>>>(
        bufB, fw4, nullptr, bufAtt, bufA, nullptr, bufC, 30, 0, 30);

    // 8. out = conv(bufC, w_c6) + ms_up
    conv_k<30,4,4,1,256,256,4,false><<<dim3(4,64,2),blk,0,stream>>>(
        bufC, w_c6, b_c6, nullptr, ms_up, nullptr, out, 4, 0, 4);
}

// Round 2
// 547.107 us; speedup vs baseline: 3.1204x; 3.1204x over previous
//
#include <hip/hip_runtime.h>

typedef __attribute__((ext_vector_type(8))) short short8;
typedef __attribute__((ext_vector_type(4))) float f32x4;

#define HW 65536

__device__ __forceinline__ float bf2f(unsigned short u){
    union { unsigned int i; float f; } x; x.i = ((unsigned int)u) << 16; return x.f;
}
__device__ __forceinline__ unsigned short f2bf(float f){
    union { float f; unsigned int i; } x; x.f = f;
    unsigned int r = x.i + 0x7fffu + ((x.i >> 16) & 1u);
    return (unsigned short)(r >> 16);
}

// ---------------------------------------------------------------------------
// MFMA implicit-GEMM conv: 9 tap-GEMMs, K = CIN(pad KK*32), M = COUT(pad MT*16),
// N = pixels. NHWC bf16 activations. Wave handles 32 pixels (2 N-frags) of one
// image row. EPI: 0 none, 1 prelu, 2 softmax->att(f32 planar), 3 +res relu,
// 5 final (+ms_up f32, NCHW f32 out). ATT: per-tap accumulator scaled by
// att[p,pix] (AFLB modulated conv).
// ---------------------------------------------------------------------------
template<int KK, int MT, int DIL, int EPI, bool ATT>
__global__ __launch_bounds__(256) void mconv(
    const unsigned short* __restrict__ in,      // NHWC bf16, cpad = KK*32
    const unsigned short* __restrict__ wfrag,   // A-frag bf16 [tap][mt][kk][512]
    const float* __restrict__ bias, int cout_real,
    const float* __restrict__ attr,             // [b][9][HW] f32 (ATT)
    float* __restrict__ attw,                   // (EPI==2)
    const unsigned short* __restrict__ res, int res_cpad,  // (EPI==3)
    const float* __restrict__ alphap,           // (EPI==1)
    unsigned short* __restrict__ outb, int out_cpad, int coff, int row_lim,
    const float* __restrict__ msup, float* __restrict__ outf)  // (EPI==5)
{
    constexpr int NF = 2;
    constexpr int CPIN = KK * 32;
    const int lane = threadIdx.x & 63, wv = threadIdx.x >> 6;
    const int col = lane & 15, g = lane >> 4;
    const int y = blockIdx.y, b = blockIdx.z;
    const int x0 = blockIdx.x * 128 + wv * 32;

    const unsigned short* inb = in + (size_t)b * HW * CPIN;

    f32x4 acc[MT][NF];
#pragma unroll
    for (int mt = 0; mt < MT; ++mt)
#pragma unroll
        for (int nf = 0; nf < NF; ++nf) acc[mt][nf] = (f32x4){0.f,0.f,0.f,0.f};

    const short8 kz = {0,0,0,0,0,0,0,0};
    const short8* wp = (const short8*)wfrag;

#pragma unroll
    for (int tap = 0; tap < 9; ++tap) {
        const int dy = tap / 3 - 1, dx = tap % 3 - 1;
        const int yy = y + dy * DIL;
        const bool yok = (unsigned)yy < 256u;

        short8 af[MT][KK];
#pragma unroll
        for (int mt = 0; mt < MT; ++mt)
#pragma unroll
            for (int kk = 0; kk < KK; ++kk)
                af[mt][kk] = wp[((tap * MT + mt) * KK + kk) * 64 + lane];

        f32x4 pacc[MT][NF];
        if (ATT) {
#pragma unroll
            for (int mt = 0; mt < MT; ++mt)
#pragma unroll
                for (int nf = 0; nf < NF; ++nf) pacc[mt][nf] = (f32x4){0.f,0.f,0.f,0.f};
        }

#pragma unroll
        for (int nf = 0; nf < NF; ++nf) {
            const int xx = x0 + nf * 16 + col + dx * DIL;
            const bool ok = yok && ((unsigned)xx < 256u);
            const int pix = ok ? (yy * 256 + xx) : 0;
            const short8* bp = (const short8*)(inb + (size_t)pix * CPIN + g * 8);
#pragma unroll
            for (int kk = 0; kk < KK; ++kk) {
                short8 bf = bp[kk * 4];
                if (!ok) bf = kz;
#pragma unroll
                for (int mt = 0; mt < MT; ++mt) {
                    if (ATT)
                        pacc[mt][nf] = __builtin_amdgcn_mfma_f32_16x16x32_bf16(
                            af[mt][kk], bf, pacc[mt][nf], 0, 0, 0);
                    else
                        acc[mt][nf] = __builtin_amdgcn_mfma_f32_16x16x32_bf16(
                            af[mt][kk], bf, acc[mt][nf], 0, 0, 0);
                }
            }
        }

        if (ATT) {
#pragma unroll
            for (int nf = 0; nf < NF; ++nf) {
                const int pix0 = y * 256 + x0 + nf * 16 + col;
                const float av = attr[((size_t)b * 9 + tap) * HW + pix0];
#pragma unroll
                for (int mt = 0; mt < MT; ++mt)
#pragma unroll
                    for (int r = 0; r < 4; ++r)
                        acc[mt][nf][r] = fmaf(av, pacc[mt][nf][r], acc[mt][nf][r]);
            }
        }
    }

    int pix[NF];
#pragma unroll
    for (int nf = 0; nf < NF; ++nf) pix[nf] = y * 256 + x0 + nf * 16 + col;

    if (EPI == 2) {  // softmax over 9 output channels (MT==1)
#pragma unroll
        for (int nf = 0; nf < NF; ++nf) {
            float v[4]; bool val[4];
            float m = -1e30f;
#pragma unroll
            for (int r = 0; r < 4; ++r) {
                const int row = g * 4 + r;
                val[r] = row < 9;
                v[r] = acc[0][nf][r] + (val[r] ? __ldg(bias + row) : 0.f);
                if (val[r]) m = fmaxf(m, v[r]);
            }
            m = fmaxf(m, __shfl_xor(m, 16));
            m = fmaxf(m, __shfl_xor(m, 32));
            float s = 0.f, e[4];
#pragma unroll
            for (int r = 0; r < 4; ++r) { e[r] = val[r] ? __expf(v[r] - m) : 0.f; s += e[r]; }
            s += __shfl_xor(s, 16);
            s += __shfl_xor(s, 32);
            const float inv = 1.f / s;
#pragma unroll
            for (int r = 0; r < 4; ++r)
                if (val[r]) attw[((size_t)b * 9 + g * 4 + r) * HW + pix[nf]] = e[r] * inv;
        }
        return;
    }

    const float al = (EPI == 1) ? __ldg(alphap) : 0.f;

#pragma unroll
    for (int mt = 0; mt < MT; ++mt)
#pragma unroll
        for (int nf = 0; nf < NF; ++nf)
#pragma unroll
            for (int r = 0; r < 4; ++r) {
                const int row = mt * 16 + g * 4 + r;
                if (row < row_lim) {
                    float v = acc[mt][nf][r];
                    if (bias && row < cout_real) v += __ldg(bias + row);
                    if (EPI == 1) v = (v >= 0.f) ? v : al * v;
                    if (EPI == 3) {
                        v += bf2f(res[((size_t)b * HW + pix[nf]) * res_cpad + coff + row]);
                        v = fmaxf(v, 0.f);
                    }
                    if (EPI == 5) {
                        const size_t oi = ((size_t)b * 4 + row) * HW + pix[nf];
                        outf[oi] = v + msup[oi];
                    } else {
                        outb[((size_t)b * HW + pix[nf]) * out_cpad + coff + row] = f2bf(v);
                    }
                }
            }
}

// ---------------------------------------------------------------------------
// Weight prep: f32 [O][I][3][3] -> bf16 A-fragment layout [tap][mt][kk][512],
// zero-padded; optional K-permutation (out1 layout) and O-permutation (fw2).
// ---------------------------------------------------------------------------
struct PrepDesc { const float* src; int cout, cin, mt, kk, flags, dstoff; };
struct PrepArgs { PrepDesc d[18]; };

__global__ __launch_bounds__(256) void prep_k(PrepArgs pa, unsigned short* __restrict__ wb)
{
    PrepDesc d = pa.d[blockIdx.x];
    const int n = 9 * d.mt * d.kk * 512;
    for (int e = threadIdx.x; e < n; e += 256) {
        const int j = e & 7;
        const int lane = (e >> 3) & 63;
        const int i512 = e >> 9;
        const int kk = i512 % d.kk;
        const int mt = (i512 / d.kk) % d.mt;
        const int tap = i512 / (d.kk * d.mt);
        const int rpos = mt * 16 + (lane & 15);
        const int kpos = kk * 32 + (lane >> 4) * 8 + j;
        int o = rpos, ic = kpos;
        bool ok = true;
        if (d.flags & 2) {  // output-row permutation (fw2)
            if (rpos < 30) o = rpos;
            else if (rpos >= 32 && rpos < 62) o = rpos - 2;
            else ok = false;
        }
        if (d.flags & 1) {  // k permutation (consumers of out1/out2 layout)
            if (kpos < 30) ic = kpos;
            else if (kpos >= 32 && kpos < 62) ic = kpos - 2;
            else ok = false;
        }
        float v = 0.f;
        if (ok && o < d.cout && ic < d.cin) v = d.src[(o * d.cin + ic) * 9 + tap];
        wb[d.dstoff + e] = f2bf(v);
    }
}

// ---------------------------------------------------------------------------
// up-conv (ms_org 4->64 @64x64, f32 NCHW) — small, VALU direct conv.
// ---------------------------------------------------------------------------
template<int CIN, int COUT, int OCB, int H, int W>
__launch_bounds__(256)
__global__ void upconv_k(const float* __restrict__ in, const float* __restrict__ wgt,
                         const float* __restrict__ bias, float* __restrict__ out)
{
    constexpr int HWp = H * W;
    constexpr int NOCB = COUT / OCB;
    const int tx = threadIdx.x;
    const int lx = tx & 63, ly = tx >> 6;
    const int gx = blockIdx.x * 64 + lx;
    const int gy = blockIdx.y * 4 + ly;
    const int b = blockIdx.z / NOCB;
    const int ocb = blockIdx.z % NOCB;
    const int pixp = gy * W + gx;
    const float* inb = in + (size_t)b * CIN * HWp;

    int off[9]; float mul[9];
#pragma unroll
    for (int dy = 0; dy < 3; ++dy)
#pragma unroll
        for (int dx = 0; dx < 3; ++dx) {
            int p = dy * 3 + dx;
            int yy = gy + dy - 1, xx = gx + dx - 1;
            bool okp = ((unsigned)yy < (unsigned)H) && ((unsigned)xx < (unsigned)W);
            off[p] = okp ? (yy * W + xx) : 0;
            mul[p] = okp ? 1.f : 0.f;
        }
    float acc[OCB];
#pragma unroll
    for (int o = 0; o < OCB; ++o) acc[o] = 0.f;
    const float* wbase = wgt + (size_t)(ocb * OCB) * CIN * 9;
#pragma unroll
    for (int ic = 0; ic < CIN; ++ic) {
        const float* ip = inb + (size_t)ic * HWp;
        float t[9];
#pragma unroll
        for (int p = 0; p < 9; ++p) t[p] = __ldg(ip + off[p]) * mul[p];
#pragma unroll
        for (int o = 0; o < OCB; ++o) {
            const float* wq = wbase + (size_t)(o * CIN + ic) * 9;
#pragma unroll
            for (int p = 0; p < 9; ++p) acc[o] = fmaf(t[p], wq[p], acc[o]);
        }
    }
#pragma unroll
    for (int o = 0; o < OCB; ++o)
        out[((size_t)b * COUT + ocb * OCB + o) * HWp + pixp] = acc[o] + __ldg(bias + ocb * OCB + o);
}

// ---------------------------------------------------------------------------
// Build data1 (prelu(pixshuf(t_up))||pan, NHWC bf16 pad32) and ms_up NHWC
// bf16 pad32.  blockIdx.y: 0 -> data1, 1 -> msb.
// ---------------------------------------------------------------------------
__global__ __launch_bounds__(256) void build_inputs(
    const float* __restrict__ tup, const float* __restrict__ pan,
    const float* __restrict__ aup, const float* __restrict__ msup,
    unsigned short* __restrict__ data1, unsigned short* __restrict__ msb)
{
    const int i = blockIdx.x * 256 + threadIdx.x;   // 0..131071 (pixel id incl. batch)
    const int b = i >> 16, pixp = i & 65535;
    const int y = pixp >> 8, x = pixp & 255;
    unsigned short o[32];
#pragma unroll
    for (int c = 0; c < 32; ++c) o[c] = 0;
    unsigned short* dst;
    if (blockIdx.y == 0) {
        const float a = __ldg(aup);
#pragma unroll
        for (int c = 0; c < 4; ++c) {
            const int ch = c * 16 + (y & 3) * 4 + (x & 3);
            float v = tup[(((size_t)b * 64 + ch) << 12) + ((y >> 2) << 6) + (x >> 2)];
            v = (v >= 0.f) ? v : a * v;
            o[c] = f2bf(v);
        }
        o[4] = f2bf(pan[((size_t)b << 16) + pixp]);
        dst = data1;
    } else {
#pragma unroll
        for (int c = 0; c < 4; ++c)
            o[c] = f2bf(msup[(((size_t)b * 4 + c) << 16) + pixp]);
        dst = msb;
    }
    short8* dp = (short8*)(dst + (size_t)i * 32);
#pragma unroll
    for (int q = 0; q < 4; ++q) {
        short8 s;
#pragma unroll
        for (int r = 0; r < 8; ++r) s[r] = (short)o[q * 8 + r];
        dp[q] = s;
    }
}

// ---------------------------------------------------------------------------
extern "C" void kernel_launch(void* const* d_in, const int* in_sizes, int n_in,
                              void* d_out, int out_size, void* d_ws, size_t ws_size,
                              hipStream_t stream) {
    const float* ms_up  = (const float*)d_in[0];
    const float* ms_org = (const float*)d_in[1];
    const float* pan    = (const float*)d_in[2];
    const float* w_up4  = (const float*)d_in[3];
    const float* b_up4  = (const float*)d_in[4];
    const float* a_up4  = (const float*)d_in[5];
    const float* w_blk53= (const float*)d_in[6];
    const float* b_blk53= (const float*)d_in[7];
    const float* a_blk53= (const float*)d_in[8];
    const float* w_blk43= (const float*)d_in[9];
    const float* b_blk43= (const float*)d_in[10];
    const float* a_blk43= (const float*)d_in[11];
    const float* w1a=(const float*)d_in[12]; const float* b1a=(const float*)d_in[13];
    const float* w1b=(const float*)d_in[14]; const float* b1b=(const float*)d_in[15];
    const float* w1c=(const float*)d_in[16]; const float* b1c=(const float*)d_in[17];
    const float* aw1=(const float*)d_in[18]; const float* ab1=(const float*)d_in[19];
    const float* fw1=(const float*)d_in[20];
    const float* aw2=(const float*)d_in[21]; const float* ab2=(const float*)d_in[22];
    const float* fw2=(const float*)d_in[23];
    const float* w_blk2=(const float*)d_in[24]; const float* b_blk2=(const float*)d_in[25]; const float* a_blk2=(const float*)d_in[26];
    const float* w2a=(const float*)d_in[27]; const float* b2a=(const float*)d_in[28];
    const float* w2b=(const float*)d_in[29]; const float* b2b=(const float*)d_in[30];
    const float* w2c=(const float*)d_in[31]; const float* b2c=(const float*)d_in[32];
    const float* aw3=(const float*)d_in[33]; const float* ab3=(const float*)d_in[34];
    const float* fw3=(const float*)d_in[35];
    const float* aw4=(const float*)d_in[36]; const float* ab4=(const float*)d_in[37];
    const float* fw4=(const float*)d_in[38];
    const float* w_c6=(const float*)d_in[39]; const float* b_c6=(const float*)d_in[40];

    float* out = (float*)d_out;
    char* ws = (char*)d_ws;

    // ---- workspace layout (bytes) ----
    const size_t BIG = (size_t)2 * HW * 64 * 2;   // 16.78 MB (NHWC pad64 bf16)
    const size_t HALF = BIG / 2;                  // pad32
    unsigned short* bufA = (unsigned short*)(ws);                 // out1 / later bufF
    unsigned short* bufB = (unsigned short*)(ws + BIG);           // rmrs1 mid / out2 / later bufE
    unsigned short* bufC = (unsigned short*)(ws + 2 * BIG);       // aflb1 out / later bufD
    unsigned short* data1 = bufC;                                  // dead before bufC written
    float*          t_up  = (float*)(ws + 2 * BIG + HALF);         // dead before bufC written
    unsigned short* msb   = bufB;                                  // dead before bufB written
    unsigned short* bufD = bufC;   // pad32, written at blk2 (bufC dead)
    unsigned short* bufE = bufB;   // pad32, written at w2a (bufB dead)
    unsigned short* bufF = bufA;   // pad32, written at fw3 (out1 dead)
    float* attb = (float*)(ws + 3 * BIG);                          // [2][9][HW] f32
    unsigned short* wb = (unsigned short*)(ws + 3 * BIG + (size_t)2 * 9 * HW * 4);

    if (ws_size < 3 * BIG + (size_t)2 * 9 * HW * 4 + 524288) return;

    // ---- weight prep descriptors ----
    PrepArgs pa;
    int off = 0, li = 0;
    auto add = [&](const float* s, int cout, int cin, int mt, int kk, int flags) {
        pa.d[li].src = s; pa.d[li].cout = cout; pa.d[li].cin = cin;
        pa.d[li].mt = mt; pa.d[li].kk = kk; pa.d[li].flags = flags; pa.d[li].dstoff = off;
        int ret = off; off += 9 * mt * kk * 512; ++li; return ret;
    };
    const int o_blk43 = add(w_blk43, 30, 4, 2, 1, 0);
    const int o_blk53 = add(w_blk53, 30, 5, 2, 1, 0);
    const int o_w1a   = add(w1a, 20, 60, 2, 2, 1);
    const int o_w1b   = add(w1b, 20, 60, 2, 2, 1);
    const int o_w1c   = add(w1c, 20, 60, 2, 2, 1);
    const int o_aw1   = add(aw1,  9, 60, 1, 2, 1);
    const int o_fw1   = add(fw1, 60, 60, 4, 2, 0);
    const int o_aw2   = add(aw2,  9, 60, 1, 2, 0);
    const int o_fw2   = add(fw2, 60, 60, 4, 2, 2);   // output rows permuted
    const int o_blk2  = add(w_blk2, 30, 60, 2, 2, 1);
    const int o_w2a   = add(w2a, 10, 30, 1, 1, 0);
    const int o_w2b   = add(w2b, 10, 30, 1, 1, 0);
    const int o_w2c   = add(w2c, 10, 30, 1, 1, 0);
    const int o_aw3   = add(aw3,  9, 30, 1, 1, 0);
    const int o_fw3   = add(fw3, 30, 30, 2, 1, 0);
    const int o_aw4   = add(aw4,  9, 30, 1, 1, 0);
    const int o_fw4   = add(fw4, 30, 30, 2, 1, 0);
    const int o_c6    = add(w_c6,  4, 30, 1, 1, 0);

    prep_k<<<dim3(18), 256, 0, stream>>>(pa, wb);

    // ---- front end ----
    upconv_k<4, 64, 16, 64, 64><<<dim3(1, 16, 8), 256, 0, stream>>>(ms_org, w_up4, b_up4, t_up);
    build_inputs<<<dim3(512, 2), 256, 0, stream>>>(t_up, pan, a_up4, ms_up, data1, msb);

    const dim3 G(2, 256, 2), B256(256);

    // out1 (bufA, pad64): blk43 -> ch 0..29 (+30,31 zero), blk53 -> ch 32..61 (+62,63 zero)
    mconv<1,2,1,1,false><<<G,B256,0,stream>>>(msb,   wb+o_blk43, b_blk43, 30, nullptr,nullptr, nullptr,0, a_blk43, bufA,64, 0,32, nullptr,nullptr);
    mconv<1,2,1,1,false><<<G,B256,0,stream>>>(data1, wb+o_blk53, b_blk53, 30, nullptr,nullptr, nullptr,0, a_blk53, bufA,64,32,32, nullptr,nullptr);

    // ---- rmrs1 (60 ch) ----
    mconv<2,2,1,0,false><<<G,B256,0,stream>>>(bufA, wb+o_w1a, b1a, 20, nullptr,nullptr, nullptr,0, nullptr, bufB,64, 0,20, nullptr,nullptr);
    mconv<2,2,2,0,false><<<G,B256,0,stream>>>(bufA, wb+o_w1b, b1b, 20, nullptr,nullptr, nullptr,0, nullptr, bufB,64,20,20, nullptr,nullptr);
    mconv<2,2,3,0,false><<<G,B256,0,stream>>>(bufA, wb+o_w1c, b1c, 20, nullptr,nullptr, nullptr,0, nullptr, bufB,64,40,24, nullptr,nullptr);
    mconv<2,1,1,2,false><<<G,B256,0,stream>>>(bufB, wb+o_aw1, ab1,  9, nullptr,attb,    nullptr,0, nullptr, nullptr,0,0,0, nullptr,nullptr);
    mconv<2,4,1,0,true ><<<G,B256,0,stream>>>(bufB, wb+o_fw1, nullptr,60, attb,nullptr, nullptr,0, nullptr, bufC,64, 0,64, nullptr,nullptr);
    mconv<2,1,1,2,false><<<G,B256,0,stream>>>(bufC, wb+o_aw2, ab2,  9, nullptr,attb,    nullptr,0, nullptr, nullptr,0,0,0, nullptr,nullptr);
    mconv<2,4,1,3,true ><<<G,B256,0,stream>>>(bufC, wb+o_fw2, nullptr,60, attb,nullptr, bufA,64,  nullptr, bufB,64, 0,64, nullptr,nullptr);

    // blk2: out2 -> 30ch (bufD pad32)
    mconv<2,2,1,1,false><<<G,B256,0,stream>>>(bufB, wb+o_blk2, b_blk2, 30, nullptr,nullptr, nullptr,0, a_blk2, bufD,32, 0,32, nullptr,nullptr);

    // ---- rmrs2 (30 ch) ----
    mconv<1,1,1,0,false><<<G,B256,0,stream>>>(bufD, wb+o_w2a, b2a, 10, nullptr,nullptr, nullptr,0, nullptr, bufE,32, 0,10, nullptr,nullptr);
    mconv<1,1,2,0,false><<<G,B256,0,stream>>>(bufD, wb+o_w2b, b2b, 10, nullptr,nullptr, nullptr,0, nullptr, bufE,32,10,10, nullptr,nullptr);
    mconv<1,1,3,0,false><<<G,B256,0,stream>>>(bufD, wb+o_w2c, b2c, 10, nullptr,nullptr, nullptr,0, nullptr, bufE,32,20,12, nullptr,nullptr);
    mconv<1,1,1,2,false><<<G,B256,0,stream>>>(bufE, wb+o_aw3, ab3,  9, nullptr,attb,    nullptr,0, nullptr, nullptr,0,0,0, nullptr,nullptr);
    mconv<1,2,1,0,true ><<<G,B256,0,stream>>>(bufE, wb+o_fw3, nullptr,30, attb,nullptr, nullptr,0, nullptr, bufF,32, 0,32, nullptr,nullptr);
    mconv<1,1,1,2,false><<<G,B256,0,stream>>>(bufF, wb+o_aw4, ab4,  9, nullptr,attb,    nullptr,0, nullptr, nullptr,0,0,0, nullptr,nullptr);
    mconv<1,2,1,3,true ><<<G,B256,0,stream>>>(bufF, wb+o_fw4, nullptr,30, attb,nullptr, bufD,32,  nullptr, bufE,32, 0,32, nullptr,nullptr);

    // final: conv 30->4 + ms_up (f32 NCHW out)
    mconv<1,1,1,5,false><<<G,B256,0,stream>>>(bufE, wb+o_c6, b_c6, 4, nullptr,nullptr, nullptr,0, nullptr, nullptr,0,0,4, ms_up, out);
}

// Round 3
// 512.098 us; speedup vs baseline: 3.3338x; 1.0684x over previous
//
#include <hip/hip_runtime.h>

typedef __attribute__((ext_vector_type(8))) short short8;
typedef __attribute__((ext_vector_type(4))) float f32x4;

#define HW 65536

__device__ __forceinline__ float bf2f(unsigned short u){
    union { unsigned int i; float f; } x; x.i = ((unsigned int)u) << 16; return x.f;
}
__device__ __forceinline__ unsigned short f2bf(float f){
    union { float f; unsigned int i; } x; x.f = f;
    unsigned int r = x.i + 0x7fffu + ((x.i >> 16) & 1u);
    return (unsigned short)(r >> 16);
}

// ---------------------------------------------------------------------------
// Plain MFMA implicit-GEMM 3x3 conv. NHWC bf16, cpad=KK*32. NF=2 (wave=32px).
// Grid: x in [0,512): xcd=x&7 owns rows [xcd*32, xcd*32+32); z = batch.
// EPI: 0 none, 1 prelu, 5 final (+ms_up, f32 NCHW out).
// ---------------------------------------------------------------------------
template<int KK, int MT, int DIL, int EPI>
__global__ __launch_bounds__(256, 4) void conv_mf(
    const unsigned short* __restrict__ in,
    const unsigned short* __restrict__ wfrag,   // [tap][MT][KK][512] bf16
    const float* __restrict__ bias, int cout_real,
    const float* __restrict__ alphap,
    unsigned short* __restrict__ outb, int out_cpad, int coff, int row_lim,
    const float* __restrict__ msup, float* __restrict__ outf)
{
    constexpr int NF = 2;
    constexpr int CPIN = KK * 32;
    const int lane = threadIdx.x & 63, wv = threadIdx.x >> 6;
    const int col = lane & 15, g = lane >> 4;
    const int bx = blockIdx.x;
    const int xcd = bx & 7, q = bx >> 3;          // q in [0,64)
    const int y = xcd * 32 + (q & 31);
    const int xh = q >> 5;                        // [0,2)
    const int b = blockIdx.z;
    const int x0 = xh * 128 + wv * 32;

    const unsigned short* inb = in + (size_t)b * HW * CPIN;
    const short8 kz = {0,0,0,0,0,0,0,0};
    const short8* wp = (const short8*)wfrag;

    f32x4 acc[MT][NF];
#pragma unroll
    for (int mt = 0; mt < MT; ++mt)
#pragma unroll
        for (int nf = 0; nf < NF; ++nf) acc[mt][nf] = (f32x4){0.f,0.f,0.f,0.f};

#pragma unroll
    for (int tap = 0; tap < 9; ++tap) {
        const int dy = tap / 3 - 1, dx = tap % 3 - 1;
        const int yy = y + dy * DIL;
        const bool yok = (unsigned)yy < 256u;

        short8 af[MT][KK];
#pragma unroll
        for (int mt = 0; mt < MT; ++mt)
#pragma unroll
            for (int kk = 0; kk < KK; ++kk)
                af[mt][kk] = wp[((tap * MT + mt) * KK + kk) * 64 + lane];

#pragma unroll
        for (int nf = 0; nf < NF; ++nf) {
            const int xx = x0 + nf * 16 + col + dx * DIL;
            const bool ok = yok && ((unsigned)xx < 256u);
            const int pix = ok ? (yy * 256 + xx) : 0;
            const short8* bp = (const short8*)(inb + (size_t)pix * CPIN + g * 8);
#pragma unroll
            for (int kk = 0; kk < KK; ++kk) {
                short8 bf = bp[kk * 4];
                if (!ok) bf = kz;
#pragma unroll
                for (int mt = 0; mt < MT; ++mt)
                    acc[mt][nf] = __builtin_amdgcn_mfma_f32_16x16x32_bf16(
                        af[mt][kk], bf, acc[mt][nf], 0, 0, 0);
            }
        }
    }

    const float al = (EPI == 1) ? __ldg(alphap) : 0.f;

#pragma unroll
    for (int mt = 0; mt < MT; ++mt)
#pragma unroll
        for (int nf = 0; nf < NF; ++nf) {
            const int pix = y * 256 + x0 + nf * 16 + col;
#pragma unroll
            for (int r = 0; r < 4; ++r) {
                const int row = mt * 16 + g * 4 + r;
                if (row < row_lim) {
                    float v = acc[mt][nf][r];
                    if (bias && row < cout_real) v += __ldg(bias + row);
                    if (EPI == 1) v = (v >= 0.f) ? v : al * v;
                    if (EPI == 5) {
                        const size_t oi = ((size_t)b * 4 + row) * HW + pix;
                        outf[oi] = v + msup[oi];
                    } else {
                        outb[((size_t)b * HW + pix) * out_cpad + coff + row] = f2bf(v);
                    }
                }
            }
        }
}

// ---------------------------------------------------------------------------
// Fused AFLB: att = softmax(conv(in, aw)+ab) computed in-register (pass 1),
// then modulated conv out = sum_p att_p * (fw_p . in_p) (pass 2).
// z = batch*2 + mt_half (each half computes att redundantly).
// EPI: 0 none, 3 +res relu.
// ---------------------------------------------------------------------------
template<int KK, int MT, int MT_TOT, int EPI>
__global__ __launch_bounds__(256, (KK >= 2 ? 3 : 4)) void aflb_k(
    const unsigned short* __restrict__ in,
    const unsigned short* __restrict__ awf,   // [tap][KK][512]
    const float* __restrict__ ab,             // [9]
    const unsigned short* __restrict__ fwf,   // [tap][MT_TOT][KK][512]
    const unsigned short* __restrict__ res, int res_cpad,
    unsigned short* __restrict__ outb, int out_cpad)
{
    constexpr int NF = 2;
    constexpr int CPIN = KK * 32;
    const int lane = threadIdx.x & 63, wv = threadIdx.x >> 6;
    const int col = lane & 15, g = lane >> 4;
    const int bx = blockIdx.x;
    const int xcd = bx & 7, q = bx >> 3;
    const int y = xcd * 32 + (q & 31);
    const int xh = q >> 5;
    const int b = blockIdx.z >> 1, half = blockIdx.z & 1;
    const int mt_off = half * MT;
    const int x0 = xh * 128 + wv * 32;

    const unsigned short* inb = in + (size_t)b * HW * CPIN;
    const short8 kz = {0,0,0,0,0,0,0,0};
    const short8* awp = (const short8*)awf;
    const short8* fwp = (const short8*)fwf;

    // ---- pass 1: attention scores (M=16, rows 0..8 valid) ----
    f32x4 aacc[NF];
#pragma unroll
    for (int nf = 0; nf < NF; ++nf) aacc[nf] = (f32x4){0.f,0.f,0.f,0.f};

#pragma unroll
    for (int tap = 0; tap < 9; ++tap) {
        const int dy = tap / 3 - 1, dx = tap % 3 - 1;
        const int yy = y + dy;
        const bool yok = (unsigned)yy < 256u;
        short8 afa[KK];
#pragma unroll
        for (int kk = 0; kk < KK; ++kk)
            afa[kk] = awp[(tap * KK + kk) * 64 + lane];
#pragma unroll
        for (int nf = 0; nf < NF; ++nf) {
            const int xx = x0 + nf * 16 + col + dx;
            const bool ok = yok && ((unsigned)xx < 256u);
            const int pix = ok ? (yy * 256 + xx) : 0;
            const short8* bp = (const short8*)(inb + (size_t)pix * CPIN + g * 8);
#pragma unroll
            for (int kk = 0; kk < KK; ++kk) {
                short8 bf = bp[kk * 4];
                if (!ok) bf = kz;
                aacc[nf] = __builtin_amdgcn_mfma_f32_16x16x32_bf16(afa[kk], bf, aacc[nf], 0, 0, 0);
            }
        }
    }

    // ---- softmax over rows (channel axis), per pixel column ----
    float sm[NF][4];
#pragma unroll
    for (int nf = 0; nf < NF; ++nf) {
        float v[4];
        float m = -1e30f;
#pragma unroll
        for (int r = 0; r < 4; ++r) {
            const int row = g * 4 + r;
            v[r] = (row < 9) ? (aacc[nf][r] + __ldg(ab + row)) : -1e30f;
            m = fmaxf(m, v[r]);
        }
        m = fmaxf(m, __shfl_xor(m, 16));
        m = fmaxf(m, __shfl_xor(m, 32));
        float s = 0.f;
#pragma unroll
        for (int r = 0; r < 4; ++r) { sm[nf][r] = __expf(v[r] - m); s += sm[nf][r]; }
        s += __shfl_xor(s, 16);
        s += __shfl_xor(s, 32);
        const float inv = 1.f / s;
#pragma unroll
        for (int r = 0; r < 4; ++r) sm[nf][r] *= inv;
    }

    // ---- pass 2: modulated conv ----
    f32x4 acc[MT][NF];
#pragma unroll
    for (int mt = 0; mt < MT; ++mt)
#pragma unroll
        for (int nf = 0; nf < NF; ++nf) acc[mt][nf] = (f32x4){0.f,0.f,0.f,0.f};

#pragma unroll
    for (int tap = 0; tap < 9; ++tap) {
        const int dy = tap / 3 - 1, dx = tap % 3 - 1;
        const int yy = y + dy;
        const bool yok = (unsigned)yy < 256u;

        float av[NF];
#pragma unroll
        for (int nf = 0; nf < NF; ++nf)
            av[nf] = __shfl(sm[nf][tap & 3], (tap >> 2) * 16 + col);

        short8 af[MT][KK];
#pragma unroll
        for (int mt = 0; mt < MT; ++mt)
#pragma unroll
            for (int kk = 0; kk < KK; ++kk)
                af[mt][kk] = fwp[((tap * MT_TOT + mt_off + mt) * KK + kk) * 64 + lane];

#pragma unroll
        for (int nf = 0; nf < NF; ++nf) {
            const int xx = x0 + nf * 16 + col + dx;
            const bool ok = yok && ((unsigned)xx < 256u);
            const int pix = ok ? (yy * 256 + xx) : 0;
            const short8* bp = (const short8*)(inb + (size_t)pix * CPIN + g * 8);
            f32x4 pacc[MT];
#pragma unroll
            for (int mt = 0; mt < MT; ++mt) pacc[mt] = (f32x4){0.f,0.f,0.f,0.f};
#pragma unroll
            for (int kk = 0; kk < KK; ++kk) {
                short8 bf = bp[kk * 4];
                if (!ok) bf = kz;
#pragma unroll
                for (int mt = 0; mt < MT; ++mt)
                    pacc[mt] = __builtin_amdgcn_mfma_f32_16x16x32_bf16(af[mt][kk], bf, pacc[mt], 0, 0, 0);
            }
#pragma unroll
            for (int mt = 0; mt < MT; ++mt)
#pragma unroll
                for (int r = 0; r < 4; ++r)
                    acc[mt][nf][r] = fmaf(av[nf], pacc[mt][r], acc[mt][nf][r]);
        }
    }

    // ---- epilogue ----
#pragma unroll
    for (int mt = 0; mt < MT; ++mt)
#pragma unroll
        for (int nf = 0; nf < NF; ++nf) {
            const int pix = y * 256 + x0 + nf * 16 + col;
#pragma unroll
            for (int r = 0; r < 4; ++r) {
                const int row = mt_off * 16 + mt * 16 + g * 4 + r;
                float v = acc[mt][nf][r];
                if (EPI == 3) {
                    v += bf2f(res[((size_t)b * HW + pix) * res_cpad + row]);
                    v = fmaxf(v, 0.f);
                }
                outb[((size_t)b * HW + pix) * out_cpad + row] = f2bf(v);
            }
        }
}

// ---------------------------------------------------------------------------
// Weight prep: f32 [O][I][3][3] -> bf16 A-fragment layout [tap][mt][kk][512].
// ---------------------------------------------------------------------------
struct PrepDesc { const float* src; int cout, cin, mt, kk, flags, dstoff; };
struct PrepArgs { PrepDesc d[18]; };

__global__ __launch_bounds__(256) void prep_k(PrepArgs pa, unsigned short* __restrict__ wb)
{
    PrepDesc d = pa.d[blockIdx.x];
    const int n = 9 * d.mt * d.kk * 512;
    for (int e = threadIdx.x; e < n; e += 256) {
        const int j = e & 7;
        const int lane = (e >> 3) & 63;
        const int i512 = e >> 9;
        const int kk = i512 % d.kk;
        const int mt = (i512 / d.kk) % d.mt;
        const int tap = i512 / (d.kk * d.mt);
        const int rpos = mt * 16 + (lane & 15);
        const int kpos = kk * 32 + (lane >> 4) * 8 + j;
        int o = rpos, ic = kpos;
        bool ok = true;
        if (d.flags & 2) {  // output-row permutation (fw2)
            if (rpos < 30) o = rpos;
            else if (rpos >= 32 && rpos < 62) o = rpos - 2;
            else ok = false;
        }
        if (d.flags & 1) {  // k permutation (consumers of out1/out2 layout)
            if (kpos < 30) ic = kpos;
            else if (kpos >= 32 && kpos < 62) ic = kpos - 2;
            else ok = false;
        }
        float v = 0.f;
        if (ok && o < d.cout && ic < d.cin) v = d.src[(o * d.cin + ic) * 9 + tap];
        wb[d.dstoff + e] = f2bf(v);
    }
}

// ---------------------------------------------------------------------------
// up-conv (ms_org 4->64 @64x64, f32 NCHW) — small, VALU direct conv.
// ---------------------------------------------------------------------------
template<int CIN, int COUT, int OCB, int H, int W>
__launch_bounds__(256)
__global__ void upconv_k(const float* __restrict__ in, const float* __restrict__ wgt,
                         const float* __restrict__ bias, float* __restrict__ out)
{
    constexpr int HWp = H * W;
    constexpr int NOCB = COUT / OCB;
    const int tx = threadIdx.x;
    const int lx = tx & 63, ly = tx >> 6;
    const int gx = blockIdx.x * 64 + lx;
    const int gy = blockIdx.y * 4 + ly;
    const int b = blockIdx.z / NOCB;
    const int ocb = blockIdx.z % NOCB;
    const int pixp = gy * W + gx;
    const float* inb = in + (size_t)b * CIN * HWp;

    int off[9]; float mul[9];
#pragma unroll
    for (int dy = 0; dy < 3; ++dy)
#pragma unroll
        for (int dx = 0; dx < 3; ++dx) {
            int p = dy * 3 + dx;
            int yy = gy + dy - 1, xx = gx + dx - 1;
            bool okp = ((unsigned)yy < (unsigned)H) && ((unsigned)xx < (unsigned)W);
            off[p] = okp ? (yy * W + xx) : 0;
            mul[p] = okp ? 1.f : 0.f;
        }
    float acc[OCB];
#pragma unroll
    for (int o = 0; o < OCB; ++o) acc[o] = 0.f;
    const float* wbase = wgt + (size_t)(ocb * OCB) * CIN * 9;
#pragma unroll
    for (int ic = 0; ic < CIN; ++ic) {
        const float* ip = inb + (size_t)ic * HWp;
        float t[9];
#pragma unroll
        for (int p = 0; p < 9; ++p) t[p] = __ldg(ip + off[p]) * mul[p];
#pragma unroll
        for (int o = 0; o < OCB; ++o) {
            const float* wq = wbase + (size_t)(o * CIN + ic) * 9;
#pragma unroll
            for (int p = 0; p < 9; ++p) acc[o] = fmaf(t[p], wq[p], acc[o]);
        }
    }
#pragma unroll
    for (int o = 0; o < OCB; ++o)
        out[((size_t)b * COUT + ocb * OCB + o) * HWp + pixp] = acc[o] + __ldg(bias + ocb * OCB + o);
}

// ---------------------------------------------------------------------------
// Build data1 (prelu(pixshuf(t_up))||pan, NHWC bf16 pad32) and ms_up NHWC
// bf16 pad32.  blockIdx.y: 0 -> data1, 1 -> msb.
// ---------------------------------------------------------------------------
__global__ __launch_bounds__(256) void build_inputs(
    const float* __restrict__ tup, const float* __restrict__ pan,
    const float* __restrict__ aup, const float* __restrict__ msup,
    unsigned short* __restrict__ data1, unsigned short* __restrict__ msb)
{
    const int i = blockIdx.x * 256 + threadIdx.x;
    const int b = i >> 16, pixp = i & 65535;
    const int y = pixp >> 8, x = pixp & 255;
    unsigned short o[32];
#pragma unroll
    for (int c = 0; c < 32; ++c) o[c] = 0;
    unsigned short* dst;
    if (blockIdx.y == 0) {
        const float a = __ldg(aup);
#pragma unroll
        for (int c = 0; c < 4; ++c) {
            const int ch = c * 16 + (y & 3) * 4 + (x & 3);
            float v = tup[(((size_t)b * 64 + ch) << 12) + ((y >> 2) << 6) + (x >> 2)];
            v = (v >= 0.f) ? v : a * v;
            o[c] = f2bf(v);
        }
        o[4] = f2bf(pan[((size_t)b << 16) + pixp]);
        dst = data1;
    } else {
#pragma unroll
        for (int c = 0; c < 4; ++c)
            o[c] = f2bf(msup[(((size_t)b * 4 + c) << 16) + pixp]);
        dst = msb;
    }
    short8* dp = (short8*)(dst + (size_t)i * 32);
#pragma unroll
    for (int q = 0; q < 4; ++q) {
        short8 s;
#pragma unroll
        for (int r = 0; r < 8; ++r) s[r] = (short)o[q * 8 + r];
        dp[q] = s;
    }
}

// ---------------------------------------------------------------------------
extern "C" void kernel_launch(void* const* d_in, const int* in_sizes, int n_in,
                              void* d_out, int out_size, void* d_ws, size_t ws_size,
                              hipStream_t stream) {
    const float* ms_up  = (const float*)d_in[0];
    const float* ms_org = (const float*)d_in[1];
    const float* pan    = (const float*)d_in[2];
    const float* w_up4  = (const float*)d_in[3];
    const float* b_up4  = (const float*)d_in[4];
    const float* a_up4  = (const float*)d_in[5];
    const float* w_blk53= (const float*)d_in[6];
    const float* b_blk53= (const float*)d_in[7];
    const float* a_blk53= (const float*)d_in[8];
    const float* w_blk43= (const float*)d_in[9];
    const float* b_blk43= (const float*)d_in[10];
    const float* a_blk43= (const float*)d_in[11];
    const float* w1a=(const float*)d_in[12]; const float* b1a=(const float*)d_in[13];
    const float* w1b=(const float*)d_in[14]; const float* b1b=(const float*)d_in[15];
    const float* w1c=(const float*)d_in[16]; const float* b1c=(const float*)d_in[17];
    const float* aw1=(const float*)d_in[18]; const float* ab1=(const float*)d_in[19];
    const float* fw1=(const float*)d_in[20];
    const float* aw2=(const float*)d_in[21]; const float* ab2=(const float*)d_in[22];
    const float* fw2=(const float*)d_in[23];
    const float* w_blk2=(const float*)d_in[24]; const float* b_blk2=(const float*)d_in[25]; const float* a_blk2=(const float*)d_in[26];
    const float* w2a=(const float*)d_in[27]; const float* b2a=(const float*)d_in[28];
    const float* w2b=(const float*)d_in[29]; const float* b2b=(const float*)d_in[30];
    const float* w2c=(const float*)d_in[31]; const float* b2c=(const float*)d_in[32];
    const float* aw3=(const float*)d_in[33]; const float* ab3=(const float*)d_in[34];
    const float* fw3=(const float*)d_in[35];
    const float* aw4=(const float*)d_in[36]; const float* ab4=(const float*)d_in[37];
    const float* fw4=(const float*)d_in[38];
    const float* w_c6=(const float*)d_in[39]; const float* b_c6=(const float*)d_in[40];

    float* out = (float*)d_out;
    char* ws = (char*)d_ws;

    // ---- workspace layout (bytes) ----
    const size_t BIG = (size_t)2 * HW * 64 * 2;   // 16.78 MB (NHWC pad64 bf16)
    const size_t HALF = BIG / 2;                  // pad32
    unsigned short* bufA = (unsigned short*)(ws);                 // out1 / later bufF
    unsigned short* bufB = (unsigned short*)(ws + BIG);           // rmrs1 mid / out2 / later bufE
    unsigned short* bufC = (unsigned short*)(ws + 2 * BIG);       // aflb1 out / later bufD
    unsigned short* data1 = bufC;                                  // dead before bufC written
    float*          t_up  = (float*)(ws + 2 * BIG + HALF);         // dead before bufC written
    unsigned short* msb   = bufB;                                  // dead before bufB written
    unsigned short* bufD = bufC;
    unsigned short* bufE = bufB;
    unsigned short* bufF = bufA;
    unsigned short* wb = (unsigned short*)(ws + 3 * BIG);

    if (ws_size < 3 * BIG + 1000000) return;

    // ---- weight prep descriptors ----
    PrepArgs pa;
    int off = 0, li = 0;
    auto add = [&](const float* s, int cout, int cin, int mt, int kk, int flags) {
        pa.d[li].src = s; pa.d[li].cout = cout; pa.d[li].cin = cin;
        pa.d[li].mt = mt; pa.d[li].kk = kk; pa.d[li].flags = flags; pa.d[li].dstoff = off;
        int ret = off; off += 9 * mt * kk * 512; ++li; return ret;
    };
    const int o_blk43 = add(w_blk43, 30, 4, 2, 1, 0);
    const int o_blk53 = add(w_blk53, 30, 5, 2, 1, 0);
    const int o_w1a   = add(w1a, 20, 60, 2, 2, 1);
    const int o_w1b   = add(w1b, 20, 60, 2, 2, 1);
    const int o_w1c   = add(w1c, 20, 60, 2, 2, 1);
    const int o_aw1   = add(aw1,  9, 60, 1, 2, 1);
    const int o_fw1   = add(fw1, 60, 60, 4, 2, 0);
    const int o_aw2   = add(aw2,  9, 60, 1, 2, 0);
    const int o_fw2   = add(fw2, 60, 60, 4, 2, 2);   // output rows permuted
    const int o_blk2  = add(w_blk2, 30, 60, 2, 2, 1);
    const int o_w2a   = add(w2a, 10, 30, 1, 1, 0);
    const int o_w2b   = add(w2b, 10, 30, 1, 1, 0);
    const int o_w2c   = add(w2c, 10, 30, 1, 1, 0);
    const int o_aw3   = add(aw3,  9, 30, 1, 1, 0);
    const int o_fw3   = add(fw3, 30, 30, 2, 1, 0);
    const int o_aw4   = add(aw4,  9, 30, 1, 1, 0);
    const int o_fw4   = add(fw4, 30, 30, 2, 1, 0);
    const int o_c6    = add(w_c6,  4, 30, 1, 1, 0);

    prep_k<<<dim3(18), 256, 0, stream>>>(pa, wb);

    // ---- front end ----
    upconv_k<4, 64, 16, 64, 64><<<dim3(1, 16, 8), 256, 0, stream>>>(ms_org, w_up4, b_up4, t_up);
    build_inputs<<<dim3(512, 2), 256, 0, stream>>>(t_up, pan, a_up4, ms_up, data1, msb);

    const dim3 G(512, 1, 2), GA60(512, 1, 4), GA30(512, 1, 4), B256(256);

    // out1 (bufA, pad64): blk43 -> ch 0..31, blk53 -> ch 32..63
    conv_mf<1,2,1,1><<<G,B256,0,stream>>>(msb,   wb+o_blk43, b_blk43, 30, a_blk43, bufA,64, 0,32, nullptr,nullptr);
    conv_mf<1,2,1,1><<<G,B256,0,stream>>>(data1, wb+o_blk53, b_blk53, 30, a_blk53, bufA,64,32,32, nullptr,nullptr);

    // ---- rmrs1 (60 ch) ----
    conv_mf<2,2,1,0><<<G,B256,0,stream>>>(bufA, wb+o_w1a, b1a, 20, nullptr, bufB,64, 0,20, nullptr,nullptr);
    conv_mf<2,2,2,0><<<G,B256,0,stream>>>(bufA, wb+o_w1b, b1b, 20, nullptr, bufB,64,20,20, nullptr,nullptr);
    conv_mf<2,2,3,0><<<G,B256,0,stream>>>(bufA, wb+o_w1c, b1c, 20, nullptr, bufB,64,40,24, nullptr,nullptr);
    // fused aflb1: att(aw1) + modconv(fw1) -> bufC
    aflb_k<2,2,4,0><<<GA60,B256,0,stream>>>(bufB, wb+o_aw1, ab1, wb+o_fw1, nullptr,0, bufC,64);
    // fused aflb2 + residual relu -> bufB = out2
    aflb_k<2,2,4,3><<<GA60,B256,0,stream>>>(bufC, wb+o_aw2, ab2, wb+o_fw2, bufA,64, bufB,64);

    // blk2: out2 -> 30ch (bufD pad32)
    conv_mf<2,2,1,1><<<G,B256,0,stream>>>(bufB, wb+o_blk2, b_blk2, 30, a_blk2, bufD,32, 0,32, nullptr,nullptr);

    // ---- rmrs2 (30 ch) ----
    conv_mf<1,1,1,0><<<G,B256,0,stream>>>(bufD, wb+o_w2a, b2a, 10, nullptr, bufE,32, 0,10, nullptr,nullptr);
    conv_mf<1,1,2,0><<<G,B256,0,stream>>>(bufD, wb+o_w2b, b2b, 10, nullptr, bufE,32,10,10, nullptr,nullptr);
    conv_mf<1,1,3,0><<<G,B256,0,stream>>>(bufD, wb+o_w2c, b2c, 10, nullptr, bufE,32,20,12, nullptr,nullptr);
    aflb_k<1,1,2,0><<<GA30,B256,0,stream>>>(bufE, wb+o_aw3, ab3, wb+o_fw3, nullptr,0, bufF,32);
    aflb_k<1,1,2,3><<<GA30,B256,0,stream>>>(bufF, wb+o_aw4, ab4, wb+o_fw4, bufD,32, bufE,32);

    // final: conv 30->4 + ms_up (f32 NCHW out)
    conv_mf<1,1,1,5><<<G,B256,0,stream>>>(bufE, wb+o_c6, b_c6, 4, nullptr, nullptr,0,0,4, ms_up, out);
}

// Round 4
// 415.978 us; speedup vs baseline: 4.1041x; 1.2311x over previous
//
#include <hip/hip_runtime.h>

typedef __attribute__((ext_vector_type(8))) short short8;
typedef __attribute__((ext_vector_type(4))) float f32x4;
typedef __attribute__((ext_vector_type(4))) int i32x4;

#define HW 65536

__device__ __forceinline__ float bf2f(unsigned short u){
    union { unsigned int i; float f; } x; x.i = ((unsigned int)u) << 16; return x.f;
}
__device__ __forceinline__ unsigned short f2bf(float f){
    union { float f; unsigned int i; } x; x.f = f;
    unsigned int r = x.i + 0x7fffu + ((x.i >> 16) & 1u);
    return (unsigned short)(r >> 16);
}
__device__ __forceinline__ unsigned int pack2(float a, float b){
    return (unsigned int)f2bf(a) | ((unsigned int)f2bf(b) << 16);
}
__device__ __forceinline__ i32x4 addrelu4(i32x4 a, i32x4 b){
    i32x4 o;
#pragma unroll
    for (int k = 0; k < 4; ++k) {
        unsigned int ua = (unsigned int)a[k], ub = (unsigned int)b[k];
        float x0 = bf2f((unsigned short)(ua & 0xffff)) + bf2f((unsigned short)(ub & 0xffff));
        float x1 = bf2f((unsigned short)(ua >> 16))    + bf2f((unsigned short)(ub >> 16));
        o[k] = (int)(((unsigned int)f2bf(fmaxf(x0, 0.f))) |
                     ((unsigned int)f2bf(fmaxf(x1, 0.f)) << 16));
    }
    return o;
}

// Coalesced write-back of a wave's LDS tile (PXW pixels x R rows bf16, XOR-swizzled).
// RES: fuse +residual,relu (res has same cpad/coff layout as out).
template<int PXW, int R, int RES>
__device__ __forceinline__ void wave_store(unsigned int* tl, int lane,
    unsigned short* __restrict__ outb, const unsigned short* __restrict__ res,
    size_t gbase, int cpad)
{
    constexpr int SDW = R / 2, SWM = R / 8 - 1, CPP = R / 8;
    constexpr int IT = (PXW * CPP) / 64;
    constexpr int LC = (CPP == 8) ? 3 : 2;
#pragma unroll
    for (int it = 0; it < IT; ++it) {
        const int idx = it * 64 + lane;
        const int px = idx >> LC, c = idx & (CPP - 1);
        i32x4 v = *(i32x4*)(tl + px * SDW + ((4 * c) ^ ((px & SWM) << 2)));
        const size_t go = gbase + (size_t)px * cpad + c * 8;
        if (RES) v = addrelu4(v, *(const i32x4*)(res + go));
        *(i32x4*)(outb + go) = v;
    }
}

// ---------------------------------------------------------------------------
// Plain MFMA implicit-GEMM 3x3 conv, NHWC bf16 (cpad=KK*32), LDS epilogue.
// Grid.x = 256*(64/PXW)/... : xcd=bid&7 owns rows [xcd*32, xcd*32+32).
// ---------------------------------------------------------------------------
template<int KK, int MT, int DIL, int NF, int PRELU>
__global__ __launch_bounds__(256, 4) void conv_nf(
    const unsigned short* __restrict__ in,
    const unsigned short* __restrict__ wfrag,
    const float* __restrict__ bias, int rl,
    const float* __restrict__ alphap,
    unsigned short* __restrict__ outb, int cpad, int coff)
{
    constexpr int CPIN = KK * 32;
    constexpr int R = MT * 16, SDW = R / 2, SWM = R / 8 - 1;
    constexpr int PXW = NF * 16;
    __shared__ unsigned int lds[4][PXW * SDW];
    const int lane = threadIdx.x & 63, wv = threadIdx.x >> 6;
    const int col = lane & 15, g = lane >> 4;
    const int bx = blockIdx.x;
    const int xcd = bx & 7, t = bx >> 3;
    const int y = xcd * 32 + (t & 31);
    const int xh = t >> 5;
    const int b = blockIdx.z;
    const int x0 = xh * (4 * PXW) + wv * PXW;

    const unsigned short* inb = in + (size_t)b * HW * CPIN;
    const short8 kz = {0,0,0,0,0,0,0,0};
    const short8* wp = (const short8*)wfrag;

    f32x4 acc[MT][NF];
#pragma unroll
    for (int mt = 0; mt < MT; ++mt)
#pragma unroll
        for (int nf = 0; nf < NF; ++nf) acc[mt][nf] = (f32x4){0.f,0.f,0.f,0.f};

#pragma unroll
    for (int tap = 0; tap < 9; ++tap) {
        const int dy = tap / 3 - 1, dx = tap % 3 - 1;
        const int yy = y + dy * DIL;
        const bool yok = (unsigned)yy < 256u;
        short8 af[MT][KK];
#pragma unroll
        for (int mt = 0; mt < MT; ++mt)
#pragma unroll
            for (int kk = 0; kk < KK; ++kk)
                af[mt][kk] = wp[((tap * MT + mt) * KK + kk) * 64 + lane];
#pragma unroll
        for (int nf = 0; nf < NF; ++nf) {
            const int xx = x0 + nf * 16 + col + dx * DIL;
            const bool ok = yok && ((unsigned)xx < 256u);
            const int pix = ok ? (yy * 256 + xx) : 0;
            const short8* bp = (const short8*)(inb + (size_t)pix * CPIN + g * 8);
#pragma unroll
            for (int kk = 0; kk < KK; ++kk) {
                short8 bf = bp[kk * 4];
                if (!ok) bf = kz;
#pragma unroll
                for (int mt = 0; mt < MT; ++mt)
                    acc[mt][nf] = __builtin_amdgcn_mfma_f32_16x16x32_bf16(
                        af[mt][kk], bf, acc[mt][nf], 0, 0, 0);
            }
        }
    }

    const float al = PRELU ? __ldg(alphap) : 0.f;
    unsigned int* tl = lds[wv];
#pragma unroll
    for (int mt = 0; mt < MT; ++mt)
#pragma unroll
        for (int nf = 0; nf < NF; ++nf)
#pragma unroll
            for (int e = 0; e < 2; ++e) {
                const int rb = mt * 16 + g * 4 + e * 2;
                float v0 = acc[mt][nf][e * 2], v1 = acc[mt][nf][e * 2 + 1];
                v0 += (rb     < rl) ? __ldg(bias + rb)     : 0.f;
                v1 += (rb + 1 < rl) ? __ldg(bias + rb + 1) : 0.f;
                if (PRELU) { v0 = v0 >= 0.f ? v0 : al * v0; v1 = v1 >= 0.f ? v1 : al * v1; }
                if (rb     >= rl) v0 = 0.f;
                if (rb + 1 >= rl) v1 = 0.f;
                const int px = nf * 16 + col;
                tl[px * SDW + ((rb >> 1) ^ ((px & SWM) << 2))] = pack2(v0, v1);
            }
    const size_t gbase = ((size_t)b * HW + y * 256 + x0) * cpad + coff;
    wave_store<PXW, R, 0>(tl, lane, outb, nullptr, gbase, cpad);
}

// ---------------------------------------------------------------------------
// Trident: three dilated convs (dil=1,2,3) sharing one input, outputs packed
// at rows which*MR in one cpad=KK*32 buffer. Rows 3*MR..R zeroed.
// ---------------------------------------------------------------------------
template<int KK, int MR, int MT, int NF>
__global__ __launch_bounds__(256, 4) void trident_k(
    const unsigned short* __restrict__ in,
    const unsigned short* __restrict__ wf0, const unsigned short* __restrict__ wf1,
    const unsigned short* __restrict__ wf2,
    const float* __restrict__ b0, const float* __restrict__ b1, const float* __restrict__ b2,
    unsigned short* __restrict__ outb)
{
    constexpr int CPIN = KK * 32, CPAD = KK * 32, R = CPAD;
    constexpr int SDW = R / 2, SWM = R / 8 - 1, PXW = NF * 16;
    __shared__ unsigned int lds[4][PXW * SDW];
    const int lane = threadIdx.x & 63, wv = threadIdx.x >> 6;
    const int col = lane & 15, g = lane >> 4;
    const int bx = blockIdx.x;
    const int xcd = bx & 7, t = bx >> 3;
    const int y = xcd * 32 + (t & 31);
    const int xh = t >> 5;
    const int b = blockIdx.z;
    const int x0 = xh * (4 * PXW) + wv * PXW;

    const unsigned short* inb = in + (size_t)b * HW * CPIN;
    const short8 kz = {0,0,0,0,0,0,0,0};
    const unsigned short* wfs[3] = {wf0, wf1, wf2};
    const float* bss[3] = {b0, b1, b2};
    unsigned int* tl = lds[wv];

    constexpr int ZD = (R - 3 * MR) / 2;   // pad dwords per px
    for (int i = lane; i < PXW * ZD; i += 64) {
        const int px = i / ZD, d = 3 * MR / 2 + i % ZD;
        tl[px * SDW + (d ^ ((px & SWM) << 2))] = 0;
    }

#pragma unroll
    for (int which = 0; which < 3; ++which) {
        const int dil = which + 1;
        const short8* wp = (const short8*)wfs[which];
        const float* bs = bss[which];
        f32x4 acc[MT][NF];
#pragma unroll
        for (int mt = 0; mt < MT; ++mt)
#pragma unroll
            for (int nf = 0; nf < NF; ++nf) acc[mt][nf] = (f32x4){0.f,0.f,0.f,0.f};
#pragma unroll
        for (int tap = 0; tap < 9; ++tap) {
            const int dy = tap / 3 - 1, dx = tap % 3 - 1;
            const int yy = y + dy * dil;
            const bool yok = (unsigned)yy < 256u;
            short8 af[MT][KK];
#pragma unroll
            for (int mt = 0; mt < MT; ++mt)
#pragma unroll
                for (int kk = 0; kk < KK; ++kk)
                    af[mt][kk] = wp[((tap * MT + mt) * KK + kk) * 64 + lane];
#pragma unroll
            for (int nf = 0; nf < NF; ++nf) {
                const int xx = x0 + nf * 16 + col + dx * dil;
                const bool ok = yok && ((unsigned)xx < 256u);
                const int pix = ok ? (yy * 256 + xx) : 0;
                const short8* bp = (const short8*)(inb + (size_t)pix * CPIN + g * 8);
#pragma unroll
                for (int kk = 0; kk < KK; ++kk) {
                    short8 bf = bp[kk * 4];
                    if (!ok) bf = kz;
#pragma unroll
                    for (int mt = 0; mt < MT; ++mt)
                        acc[mt][nf] = __builtin_amdgcn_mfma_f32_16x16x32_bf16(
                            af[mt][kk], bf, acc[mt][nf], 0, 0, 0);
                }
            }
        }
#pragma unroll
        for (int mt = 0; mt < MT; ++mt)
#pragma unroll
            for (int nf = 0; nf < NF; ++nf)
#pragma unroll
                for (int e = 0; e < 2; ++e) {
                    const int rb = mt * 16 + g * 4 + e * 2;
                    if (rb < MR) {
                        float v0 = acc[mt][nf][e * 2]     + __ldg(bs + rb);
                        float v1 = acc[mt][nf][e * 2 + 1] + ((rb + 1 < MR) ? __ldg(bs + rb + 1) : 0.f);
                        const int px = nf * 16 + col;
                        const int d = (which * MR + rb) >> 1;
                        tl[px * SDW + (d ^ ((px & SWM) << 2))] = pack2(v0, v1);
                    }
                }
    }
    const size_t gbase = ((size_t)b * HW + y * 256 + x0) * CPAD;
    wave_store<PXW, R, 0>(tl, lane, outb, nullptr, gbase, CPAD);
}

// ---------------------------------------------------------------------------
// Fused AFLB: in-register att conv + softmax + modulated conv, LDS epilogue.
// NHALF: output-M halves (att computed redundantly per half). RES: +res,relu.
// ---------------------------------------------------------------------------
template<int KK, int MT, int NHALF, int RES, int NF>
__global__ __launch_bounds__(256, 4) void aflb_nf(
    const unsigned short* __restrict__ in,
    const unsigned short* __restrict__ awf, const float* __restrict__ ab,
    const unsigned short* __restrict__ fwf,
    const unsigned short* __restrict__ res,
    unsigned short* __restrict__ outb)
{
    constexpr int CPIN = KK * 32;
    constexpr int R = MT * 16, SDW = R / 2, SWM = R / 8 - 1, PXW = NF * 16;
    constexpr int CPAD = MT * 16 * NHALF;
    constexpr int MT_TOT = MT * NHALF;
    __shared__ unsigned int lds[4][PXW * SDW];
    const int lane = threadIdx.x & 63, wv = threadIdx.x >> 6;
    const int col = lane & 15, g = lane >> 4;
    const int bx = blockIdx.x;
    const int xcd = bx & 7, t = bx >> 3;
    const int y = xcd * 32 + (t & 31);
    const int xh = t >> 5;
    const int b = (NHALF == 2) ? (blockIdx.z >> 1) : blockIdx.z;
    const int half = (NHALF == 2) ? (blockIdx.z & 1) : 0;
    const int x0 = xh * (4 * PXW) + wv * PXW;
    const int coff = half * R;

    const unsigned short* inb = in + (size_t)b * HW * CPIN;
    const short8 kz = {0,0,0,0,0,0,0,0};
    const short8* awp = (const short8*)awf;
    const short8* fwp = (const short8*)fwf;

    // ---- pass 1: attention scores ----
    f32x4 aacc[NF];
#pragma unroll
    for (int nf = 0; nf < NF; ++nf) aacc[nf] = (f32x4){0.f,0.f,0.f,0.f};
#pragma unroll
    for (int tap = 0; tap < 9; ++tap) {
        const int dy = tap / 3 - 1, dx = tap % 3 - 1;
        const int yy = y + dy;
        const bool yok = (unsigned)yy < 256u;
        short8 afa[KK];
#pragma unroll
        for (int kk = 0; kk < KK; ++kk)
            afa[kk] = awp[(tap * KK + kk) * 64 + lane];
#pragma unroll
        for (int nf = 0; nf < NF; ++nf) {
            const int xx = x0 + nf * 16 + col + dx;
            const bool ok = yok && ((unsigned)xx < 256u);
            const int pix = ok ? (yy * 256 + xx) : 0;
            const short8* bp = (const short8*)(inb + (size_t)pix * CPIN + g * 8);
#pragma unroll
            for (int kk = 0; kk < KK; ++kk) {
                short8 bf = bp[kk * 4];
                if (!ok) bf = kz;
                aacc[nf] = __builtin_amdgcn_mfma_f32_16x16x32_bf16(afa[kk], bf, aacc[nf], 0, 0, 0);
            }
        }
    }
    // ---- softmax over 9 channels ----
    float sm[NF][4];
#pragma unroll
    for (int nf = 0; nf < NF; ++nf) {
        float v[4];
        float m = -1e30f;
#pragma unroll
        for (int r = 0; r < 4; ++r) {
            const int row = g * 4 + r;
            v[r] = (row < 9) ? (aacc[nf][r] + __ldg(ab + row)) : -1e30f;
            m = fmaxf(m, v[r]);
        }
        m = fmaxf(m, __shfl_xor(m, 16));
        m = fmaxf(m, __shfl_xor(m, 32));
        float s = 0.f;
#pragma unroll
        for (int r = 0; r < 4; ++r) { sm[nf][r] = __expf(v[r] - m); s += sm[nf][r]; }
        s += __shfl_xor(s, 16);
        s += __shfl_xor(s, 32);
        const float inv = 1.f / s;
#pragma unroll
        for (int r = 0; r < 4; ++r) sm[nf][r] *= inv;
    }
    // ---- pass 2: modulated conv ----
    f32x4 acc[MT][NF];
#pragma unroll
    for (int mt = 0; mt < MT; ++mt)
#pragma unroll
        for (int nf = 0; nf < NF; ++nf) acc[mt][nf] = (f32x4){0.f,0.f,0.f,0.f};
#pragma unroll
    for (int tap = 0; tap < 9; ++tap) {
        const int dy = tap / 3 - 1, dx = tap % 3 - 1;
        const int yy = y + dy;
        const bool yok = (unsigned)yy < 256u;
        float av[NF];
#pragma unroll
        for (int nf = 0; nf < NF; ++nf)
            av[nf] = __shfl(sm[nf][tap & 3], (tap >> 2) * 16 + col);
        short8 af[MT][KK];
#pragma unroll
        for (int mt = 0; mt < MT; ++mt)
#pragma unroll
            for (int kk = 0; kk < KK; ++kk)
                af[mt][kk] = fwp[((tap * MT_TOT + half * MT + mt) * KK + kk) * 64 + lane];
#pragma unroll
        for (int nf = 0; nf < NF; ++nf) {
            const int xx = x0 + nf * 16 + col + dx;
            const bool ok = yok && ((unsigned)xx < 256u);
            const int pix = ok ? (yy * 256 + xx) : 0;
            const short8* bp = (const short8*)(inb + (size_t)pix * CPIN + g * 8);
            f32x4 pacc[MT];
#pragma unroll
            for (int mt = 0; mt < MT; ++mt) pacc[mt] = (f32x4){0.f,0.f,0.f,0.f};
#pragma unroll
            for (int kk = 0; kk < KK; ++kk) {
                short8 bf = bp[kk * 4];
                if (!ok) bf = kz;
#pragma unroll
                for (int mt = 0; mt < MT; ++mt)
                    pacc[mt] = __builtin_amdgcn_mfma_f32_16x16x32_bf16(af[mt][kk], bf, pacc[mt], 0, 0, 0);
            }
#pragma unroll
            for (int mt = 0; mt < MT; ++mt)
#pragma unroll
                for (int r = 0; r < 4; ++r)
                    acc[mt][nf][r] = fmaf(av[nf], pacc[mt][r], acc[mt][nf][r]);
        }
    }
    // ---- epilogue via LDS (weights zero-padded => pad rows are exact zeros) ----
    unsigned int* tl = lds[wv];
#pragma unroll
    for (int mt = 0; mt < MT; ++mt)
#pragma unroll
        for (int nf = 0; nf < NF; ++nf)
#pragma unroll
            for (int e = 0; e < 2; ++e) {
                const int rb = mt * 16 + g * 4 + e * 2;
                const int px = nf * 16 + col;
                tl[px * SDW + ((rb >> 1) ^ ((px & SWM) << 2))] =
                    pack2(acc[mt][nf][e * 2], acc[mt][nf][e * 2 + 1]);
            }
    const size_t gbase = ((size_t)b * HW + y * 256 + x0) * CPAD + coff;
    wave_store<PXW, R, RES>(tl, lane, outb, res, gbase, CPAD);
}

// ---------------------------------------------------------------------------
// Final conv 30->4 + ms_up, f32 NCHW output.
// ---------------------------------------------------------------------------
__global__ __launch_bounds__(256, 4) void final_k(
    const unsigned short* __restrict__ in,
    const unsigned short* __restrict__ wfrag,
    const float* __restrict__ bias,
    const float* __restrict__ msup, float* __restrict__ outf)
{
    constexpr int CPIN = 32, NF = 2;
    const int lane = threadIdx.x & 63, wv = threadIdx.x >> 6;
    const int col = lane & 15, g = lane >> 4;
    const int bx = blockIdx.x;
    const int xcd = bx & 7, t = bx >> 3;
    const int y = xcd * 32 + (t & 31);
    const int xh = t >> 5;
    const int b = blockIdx.z;
    const int x0 = xh * 128 + wv * 32;

    const unsigned short* inb = in + (size_t)b * HW * CPIN;
    const short8 kz = {0,0,0,0,0,0,0,0};
    const short8* wp = (const short8*)wfrag;

    f32x4 acc[NF];
#pragma unroll
    for (int nf = 0; nf < NF; ++nf) acc[nf] = (f32x4){0.f,0.f,0.f,0.f};
#pragma unroll
    for (int tap = 0; tap < 9; ++tap) {
        const int dy = tap / 3 - 1, dx = tap % 3 - 1;
        const int yy = y + dy;
        const bool yok = (unsigned)yy < 256u;
        const short8 af = wp[tap * 64 + lane];
#pragma unroll
        for (int nf = 0; nf < NF; ++nf) {
            const int xx = x0 + nf * 16 + col + dx;
            const bool ok = yok && ((unsigned)xx < 256u);
            const int pix = ok ? (yy * 256 + xx) : 0;
            short8 bf = *(const short8*)(inb + (size_t)pix * CPIN + g * 8);
            if (!ok) bf = kz;
            acc[nf] = __builtin_amdgcn_mfma_f32_16x16x32_bf16(af, bf, acc[nf], 0, 0, 0);
        }
    }
#pragma unroll
    for (int nf = 0; nf < NF; ++nf) {
        const int pix = y * 256 + x0 + nf * 16 + col;
        if (g == 0) {
#pragma unroll
            for (int r = 0; r < 4; ++r) {
                const size_t oi = ((size_t)b * 4 + r) * HW + pix;
                outf[oi] = acc[nf][r] + __ldg(bias + r) + msup[oi];
            }
        }
    }
}

// ---------------------------------------------------------------------------
// Weight prep: f32 [O][I][3][3] -> bf16 A-fragment layout [tap][mt][kk][512].
// ---------------------------------------------------------------------------
struct PrepDesc { const float* src; int cout, cin, mt, kk, flags, dstoff; };
struct PrepArgs { PrepDesc d[18]; };

__global__ __launch_bounds__(256) void prep_k(PrepArgs pa, unsigned short* __restrict__ wb)
{
    PrepDesc d = pa.d[blockIdx.x];
    const int n = 9 * d.mt * d.kk * 512;
    for (int e = threadIdx.x; e < n; e += 256) {
        const int j = e & 7;
        const int lane = (e >> 3) & 63;
        const int i512 = e >> 9;
        const int kk = i512 % d.kk;
        const int mt = (i512 / d.kk) % d.mt;
        const int tap = i512 / (d.kk * d.mt);
        const int rpos = mt * 16 + (lane & 15);
        const int kpos = kk * 32 + (lane >> 4) * 8 + j;
        int o = rpos, ic = kpos;
        bool ok = true;
        if (d.flags & 2) {  // output-row permutation (split-60 layout)
            if (rpos < 30) o = rpos;
            else if (rpos >= 32 && rpos < 62) o = rpos - 2;
            else ok = false;
        }
        if (d.flags & 1) {  // k permutation (consumers of split-60 layout)
            if (kpos < 30) ic = kpos;
            else if (kpos >= 32 && kpos < 62) ic = kpos - 2;
            else ok = false;
        }
        float v = 0.f;
        if (ok && o < d.cout && ic < d.cin) v = d.src[(o * d.cin + ic) * 9 + tap];
        wb[d.dstoff + e] = f2bf(v);
    }
}

// ---------------------------------------------------------------------------
// up-conv (ms_org 4->64 @64x64, f32 NCHW) — small, VALU direct conv.
// ---------------------------------------------------------------------------
template<int CIN, int COUT, int OCB, int H, int W>
__launch_bounds__(256)
__global__ void upconv_k(const float* __restrict__ in, const float* __restrict__ wgt,
                         const float* __restrict__ bias, float* __restrict__ out)
{
    constexpr int HWp = H * W;
    constexpr int NOCB = COUT / OCB;
    const int tx = threadIdx.x;
    const int lx = tx & 63, ly = tx >> 6;
    const int gx = blockIdx.x * 64 + lx;
    const int gy = blockIdx.y * 4 + ly;
    const int b = blockIdx.z / NOCB;
    const int ocb = blockIdx.z % NOCB;
    const int pixp = gy * W + gx;
    const float* inb = in + (size_t)b * CIN * HWp;

    int off[9]; float mul[9];
#pragma unroll
    for (int dy = 0; dy < 3; ++dy)
#pragma unroll
        for (int dx = 0; dx < 3; ++dx) {
            int p = dy * 3 + dx;
            int yy = gy + dy - 1, xx = gx + dx - 1;
            bool okp = ((unsigned)yy < (unsigned)H) && ((unsigned)xx < (unsigned)W);
            off[p] = okp ? (yy * W + xx) : 0;
            mul[p] = okp ? 1.f : 0.f;
        }
    float acc[OCB];
#pragma unroll
    for (int o = 0; o < OCB; ++o) acc[o] = 0.f;
    const float* wbase = wgt + (size_t)(ocb * OCB) * CIN * 9;
#pragma unroll
    for (int ic = 0; ic < CIN; ++ic) {
        const float* ip = inb + (size_t)ic * HWp;
        float tv[9];
#pragma unroll
        for (int p = 0; p < 9; ++p) tv[p] = __ldg(ip + off[p]) * mul[p];
#pragma unroll
        for (int o = 0; o < OCB; ++o) {
            const float* wq = wbase + (size_t)(o * CIN + ic) * 9;
#pragma unroll
            for (int p = 0; p < 9; ++p) acc[o] = fmaf(tv[p], wq[p], acc[o]);
        }
    }
#pragma unroll
    for (int o = 0; o < OCB; ++o)
        out[((size_t)b * COUT + ocb * OCB + o) * HWp + pixp] = acc[o] + __ldg(bias + ocb * OCB + o);
}

// ---------------------------------------------------------------------------
// Build data1 (prelu(pixshuf(t_up))||pan) and ms_up as NHWC bf16 pad32.
// ---------------------------------------------------------------------------
__global__ __launch_bounds__(256) void build_inputs(
    const float* __restrict__ tup, const float* __restrict__ pan,
    const float* __restrict__ aup, const float* __restrict__ msup,
    unsigned short* __restrict__ data1, unsigned short* __restrict__ msb)
{
    const int i = blockIdx.x * 256 + threadIdx.x;
    const int b = i >> 16, pixp = i & 65535;
    const int y = pixp >> 8, x = pixp & 255;
    unsigned short o[32];
#pragma unroll
    for (int c = 0; c < 32; ++c) o[c] = 0;
    unsigned short* dst;
    if (blockIdx.y == 0) {
        const float a = __ldg(aup);
#pragma unroll
        for (int c = 0; c < 4; ++c) {
            const int ch = c * 16 + (y & 3) * 4 + (x & 3);
            float v = tup[(((size_t)b * 64 + ch) << 12) + ((y >> 2) << 6) + (x >> 2)];
            v = (v >= 0.f) ? v : a * v;
            o[c] = f2bf(v);
        }
        o[4] = f2bf(pan[((size_t)b << 16) + pixp]);
        dst = data1;
    } else {
#pragma unroll
        for (int c = 0; c < 4; ++c)
            o[c] = f2bf(msup[(((size_t)b * 4 + c) << 16) + pixp]);
        dst = msb;
    }
    short8* dp = (short8*)(dst + (size_t)i * 32);
#pragma unroll
    for (int q = 0; q < 4; ++q) {
        short8 s;
#pragma unroll
        for (int r = 0; r < 8; ++r) s[r] = (short)o[q * 8 + r];
        dp[q] = s;
    }
}

// ---------------------------------------------------------------------------
extern "C" void kernel_launch(void* const* d_in, const int* in_sizes, int n_in,
                              void* d_out, int out_size, void* d_ws, size_t ws_size,
                              hipStream_t stream) {
    const float* ms_up  = (const float*)d_in[0];
    const float* ms_org = (const float*)d_in[1];
    const float* pan    = (const float*)d_in[2];
    const float* w_up4  = (const float*)d_in[3];
    const float* b_up4  = (const float*)d_in[4];
    const float* a_up4  = (const float*)d_in[5];
    const float* w_blk53= (const float*)d_in[6];
    const float* b_blk53= (const float*)d_in[7];
    const float* a_blk53= (const float*)d_in[8];
    const float* w_blk43= (const float*)d_in[9];
    const float* b_blk43= (const float*)d_in[10];
    const float* a_blk43= (const float*)d_in[11];
    const float* w1a=(const float*)d_in[12]; const float* b1a=(const float*)d_in[13];
    const float* w1b=(const float*)d_in[14]; const float* b1b=(const float*)d_in[15];
    const float* w1c=(const float*)d_in[16]; const float* b1c=(const float*)d_in[17];
    const float* aw1=(const float*)d_in[18]; const float* ab1=(const float*)d_in[19];
    const float* fw1=(const float*)d_in[20];
    const float* aw2=(const float*)d_in[21]; const float* ab2=(const float*)d_in[22];
    const float* fw2=(const float*)d_in[23];
    const float* w_blk2=(const float*)d_in[24]; const float* b_blk2=(const float*)d_in[25]; const float* a_blk2=(const float*)d_in[26];
    const float* w2a=(const float*)d_in[27]; const float* b2a=(const float*)d_in[28];
    const float* w2b=(const float*)d_in[29]; const float* b2b=(const float*)d_in[30];
    const float* w2c=(const float*)d_in[31]; const float* b2c=(const float*)d_in[32];
    const float* aw3=(const float*)d_in[33]; const float* ab3=(const float*)d_in[34];
    const float* fw3=(const float*)d_in[35];
    const float* aw4=(const float*)d_in[36]; const float* ab4=(const float*)d_in[37];
    const float* fw4=(const float*)d_in[38];
    const float* w_c6=(const float*)d_in[39]; const float* b_c6=(const float*)d_in[40];

    float* out = (float*)d_out;
    char* ws = (char*)d_ws;

    // ---- workspace layout (bytes) ----
    const size_t BIG = (size_t)2 * HW * 64 * 2;   // 16.78 MB (NHWC pad64 bf16)
    const size_t HALF = BIG / 2;                  // pad32
    unsigned short* bufA = (unsigned short*)(ws);
    unsigned short* bufB = (unsigned short*)(ws + BIG);
    unsigned short* bufC = (unsigned short*)(ws + 2 * BIG);
    unsigned short* data1 = bufC;                  // dead before bufC written
    float*          t_up  = (float*)(ws + 2 * BIG + HALF);
    unsigned short* msb   = bufB;                  // dead before bufB written
    unsigned short* bufD = bufC;
    unsigned short* bufE = bufB;
    unsigned short* bufF = bufA;
    unsigned short* wb = (unsigned short*)(ws + 3 * BIG);

    if (ws_size < 3 * BIG + 1000000) return;

    // ---- weight prep descriptors ----
    PrepArgs pa;
    int off = 0, li = 0;
    auto add = [&](const float* s, int cout, int cin, int mt, int kk, int flags) {
        pa.d[li].src = s; pa.d[li].cout = cout; pa.d[li].cin = cin;
        pa.d[li].mt = mt; pa.d[li].kk = kk; pa.d[li].flags = flags; pa.d[li].dstoff = off;
        int ret = off; off += 9 * mt * kk * 512; ++li; return ret;
    };
    const int o_blk43 = add(w_blk43, 30, 4, 2, 1, 0);
    const int o_blk53 = add(w_blk53, 30, 5, 2, 1, 0);
    const int o_w1a   = add(w1a, 20, 60, 2, 2, 1);
    const int o_w1b   = add(w1b, 20, 60, 2, 2, 1);
    const int o_w1c   = add(w1c, 20, 60, 2, 2, 1);
    const int o_aw1   = add(aw1,  9, 60, 1, 2, 0);   // bufB is straight (fixed)
    const int o_fw1   = add(fw1, 60, 60, 4, 2, 0);
    const int o_aw2   = add(aw2,  9, 60, 1, 2, 0);
    const int o_fw2   = add(fw2, 60, 60, 4, 2, 2);   // output rows split-60
    const int o_blk2  = add(w_blk2, 30, 60, 2, 2, 1);
    const int o_w2a   = add(w2a, 10, 30, 1, 1, 0);
    const int o_w2b   = add(w2b, 10, 30, 1, 1, 0);
    const int o_w2c   = add(w2c, 10, 30, 1, 1, 0);
    const int o_aw3   = add(aw3,  9, 30, 1, 1, 0);
    const int o_fw3   = add(fw3, 30, 30, 2, 1, 0);
    const int o_aw4   = add(aw4,  9, 30, 1, 1, 0);
    const int o_fw4   = add(fw4, 30, 30, 2, 1, 0);
    const int o_c6    = add(w_c6,  4, 30, 1, 1, 0);

    prep_k<<<dim3(18), 256, 0, stream>>>(pa, wb);

    // ---- front end ----
    upconv_k<4, 64, 16, 64, 64><<<dim3(1, 16, 8), 256, 0, stream>>>(ms_org, w_up4, b_up4, t_up);
    build_inputs<<<dim3(512, 2), 256, 0, stream>>>(t_up, pan, a_up4, ms_up, data1, msb);

    const dim3 B256(256);
    const dim3 G2(512, 1, 2);    // NF=2 kernels, z=batch
    const dim3 G4(256, 1, 4);    // NF=4 aflb60, z=batch*2+half

    // out1 (bufA, pad64, split-60): blk43 -> rows 0..29, blk53 -> rows 32..61
    conv_nf<1,2,1,2,1><<<G2,B256,0,stream>>>(msb,   wb+o_blk43, b_blk43, 30, a_blk43, bufA, 64, 0);
    conv_nf<1,2,1,2,1><<<G2,B256,0,stream>>>(data1, wb+o_blk53, b_blk53, 30, a_blk53, bufA, 64, 32);

    // ---- rmrs1 (60 ch) ----
    trident_k<2,20,2,2><<<G2,B256,0,stream>>>(bufA, wb+o_w1a, wb+o_w1b, wb+o_w1c, b1a, b1b, b1c, bufB);
    aflb_nf<2,2,2,0,4><<<G4,B256,0,stream>>>(bufB, wb+o_aw1, ab1, wb+o_fw1, nullptr, bufC);
    aflb_nf<2,2,2,1,4><<<G4,B256,0,stream>>>(bufC, wb+o_aw2, ab2, wb+o_fw2, bufA,   bufB);

    // blk2: out2 -> 30ch (bufD pad32)
    conv_nf<2,2,1,2,1><<<G2,B256,0,stream>>>(bufB, wb+o_blk2, b_blk2, 30, a_blk2, bufD, 32, 0);

    // ---- rmrs2 (30 ch) ----
    trident_k<1,10,1,2><<<G2,B256,0,stream>>>(bufD, wb+o_w2a, wb+o_w2b, wb+o_w2c, b2a, b2b, b2c, bufE);
    aflb_nf<1,2,1,0,2><<<G2,B256,0,stream>>>(bufE, wb+o_aw3, ab3, wb+o_fw3, nullptr, bufF);
    aflb_nf<1,2,1,1,2><<<G2,B256,0,stream>>>(bufF, wb+o_aw4, ab4, wb+o_fw4, bufD,   bufE);

    // final: conv 30->4 + ms_up (f32 NCHW out)
    final_k<<<G2,B256,0,stream>>>(bufE, wb+o_c6, b_c6, ms_up, out);
}

// Round 5
// 292.802 us; speedup vs baseline: 5.8306x; 1.4207x over previous
//
#include <hip/hip_runtime.h>

typedef __attribute__((ext_vector_type(8))) short short8;
typedef __attribute__((ext_vector_type(4))) float f32x4;
typedef __attribute__((ext_vector_type(4))) int i32x4;

#define HW 65536

__device__ __forceinline__ float bf2f(unsigned short u){
    union { unsigned int i; float f; } x; x.i = ((unsigned int)u) << 16; return x.f;
}
__device__ __forceinline__ unsigned short f2bf(float f){
    union { float f; unsigned int i; } x; x.f = f;
    unsigned int r = x.i + 0x7fffu + ((x.i >> 16) & 1u);
    return (unsigned short)(r >> 16);
}
__device__ __forceinline__ unsigned int pack2(float a, float b){
    return (unsigned int)f2bf(a) | ((unsigned int)f2bf(b) << 16);
}
__device__ __forceinline__ i32x4 addrelu4(i32x4 a, i32x4 b){
    i32x4 o;
#pragma unroll
    for (int k = 0; k < 4; ++k) {
        unsigned int ua = (unsigned int)a[k], ub = (unsigned int)b[k];
        float x0 = bf2f((unsigned short)(ua & 0xffff)) + bf2f((unsigned short)(ub & 0xffff));
        float x1 = bf2f((unsigned short)(ua >> 16))    + bf2f((unsigned short)(ub >> 16));
        o[k] = (int)(((unsigned int)f2bf(fmaxf(x0, 0.f))) |
                     ((unsigned int)f2bf(fmaxf(x1, 0.f)) << 16));
    }
    return o;
}

// Coalesced write-back of a wave's LDS tile (used by conv_nf / trident).
template<int PXW, int R, int RES>
__device__ __forceinline__ void wave_store(unsigned int* tl, int lane,
    unsigned short* __restrict__ outb, const unsigned short* __restrict__ res,
    size_t gbase, int cpad)
{
    constexpr int SDW = R / 2, SWM = R / 8 - 1, CPP = R / 8;
    constexpr int IT = (PXW * CPP) / 64;
    constexpr int LC = (CPP == 8) ? 3 : 2;
#pragma unroll
    for (int it = 0; it < IT; ++it) {
        const int idx = it * 64 + lane;
        const int px = idx >> LC, c = idx & (CPP - 1);
        i32x4 v = *(i32x4*)(tl + px * SDW + ((4 * c) ^ ((px & SWM) << 2)));
        const size_t go = gbase + (size_t)px * cpad + c * 8;
        if (RES) v = addrelu4(v, *(const i32x4*)(res + go));
        *(i32x4*)(outb + go) = v;
    }
}

// ---------------------------------------------------------------------------
// Plain MFMA implicit-GEMM 3x3 conv, NHWC bf16 (cpad=KK*32), LDS epilogue.
// ---------------------------------------------------------------------------
template<int KK, int MT, int DIL, int NF, int PRELU>
__global__ __launch_bounds__(256, 4) void conv_nf(
    const unsigned short* __restrict__ in,
    const unsigned short* __restrict__ wfrag,
    const float* __restrict__ bias, int rl,
    const float* __restrict__ alphap,
    unsigned short* __restrict__ outb, int cpad, int coff)
{
    constexpr int CPIN = KK * 32;
    constexpr int R = MT * 16, SDW = R / 2, SWM = R / 8 - 1;
    constexpr int PXW = NF * 16;
    __shared__ unsigned int lds[4][PXW * SDW];
    const int lane = threadIdx.x & 63, wv = threadIdx.x >> 6;
    const int col = lane & 15, g = lane >> 4;
    const int bx = blockIdx.x;
    const int xcd = bx & 7, t = bx >> 3;
    const int y = xcd * 32 + (t & 31);
    const int xh = t >> 5;
    const int b = blockIdx.z;
    const int x0 = xh * (4 * PXW) + wv * PXW;

    const unsigned short* inb = in + (size_t)b * HW * CPIN;
    const short8 kz = {0,0,0,0,0,0,0,0};
    const short8* wp = (const short8*)wfrag;

    f32x4 acc[MT][NF];
#pragma unroll
    for (int mt = 0; mt < MT; ++mt)
#pragma unroll
        for (int nf = 0; nf < NF; ++nf) acc[mt][nf] = (f32x4){0.f,0.f,0.f,0.f};

#pragma unroll
    for (int tap = 0; tap < 9; ++tap) {
        const int dy = tap / 3 - 1, dx = tap % 3 - 1;
        const int yy = y + dy * DIL;
        const bool yok = (unsigned)yy < 256u;
        short8 af[MT][KK];
#pragma unroll
        for (int mt = 0; mt < MT; ++mt)
#pragma unroll
            for (int kk = 0; kk < KK; ++kk)
                af[mt][kk] = wp[((tap * MT + mt) * KK + kk) * 64 + lane];
#pragma unroll
        for (int nf = 0; nf < NF; ++nf) {
            const int xx = x0 + nf * 16 + col + dx * DIL;
            const bool ok = yok && ((unsigned)xx < 256u);
            const int pix = ok ? (yy * 256 + xx) : 0;
            const short8* bp = (const short8*)(inb + (size_t)pix * CPIN + g * 8);
#pragma unroll
            for (int kk = 0; kk < KK; ++kk) {
                short8 bf = bp[kk * 4];
                if (!ok) bf = kz;
#pragma unroll
                for (int mt = 0; mt < MT; ++mt)
                    acc[mt][nf] = __builtin_amdgcn_mfma_f32_16x16x32_bf16(
                        af[mt][kk], bf, acc[mt][nf], 0, 0, 0);
            }
        }
    }

    const float al = PRELU ? __ldg(alphap) : 0.f;
    unsigned int* tl = lds[wv];
#pragma unroll
    for (int mt = 0; mt < MT; ++mt)
#pragma unroll
        for (int nf = 0; nf < NF; ++nf)
#pragma unroll
            for (int e = 0; e < 2; ++e) {
                const int rb = mt * 16 + g * 4 + e * 2;
                float v0 = acc[mt][nf][e * 2], v1 = acc[mt][nf][e * 2 + 1];
                v0 += (rb     < rl) ? __ldg(bias + rb)     : 0.f;
                v1 += (rb + 1 < rl) ? __ldg(bias + rb + 1) : 0.f;
                if (PRELU) { v0 = v0 >= 0.f ? v0 : al * v0; v1 = v1 >= 0.f ? v1 : al * v1; }
                if (rb     >= rl) v0 = 0.f;
                if (rb + 1 >= rl) v1 = 0.f;
                const int px = nf * 16 + col;
                tl[px * SDW + ((rb >> 1) ^ ((px & SWM) << 2))] = pack2(v0, v1);
            }
    const size_t gbase = ((size_t)b * HW + y * 256 + x0) * cpad + coff;
    wave_store<PXW, R, 0>(tl, lane, outb, nullptr, gbase, cpad);
}

// ---------------------------------------------------------------------------
// Trident: three dilated convs (dil=1,2,3) sharing one input, packed output.
// ---------------------------------------------------------------------------
template<int KK, int MR, int MT, int NF>
__global__ __launch_bounds__(256, 4) void trident_k(
    const unsigned short* __restrict__ in,
    const unsigned short* __restrict__ wf0, const unsigned short* __restrict__ wf1,
    const unsigned short* __restrict__ wf2,
    const float* __restrict__ b0, const float* __restrict__ b1, const float* __restrict__ b2,
    unsigned short* __restrict__ outb)
{
    constexpr int CPIN = KK * 32, CPAD = KK * 32, R = CPAD;
    constexpr int SDW = R / 2, SWM = R / 8 - 1, PXW = NF * 16;
    __shared__ unsigned int lds[4][PXW * SDW];
    const int lane = threadIdx.x & 63, wv = threadIdx.x >> 6;
    const int col = lane & 15, g = lane >> 4;
    const int bx = blockIdx.x;
    const int xcd = bx & 7, t = bx >> 3;
    const int y = xcd * 32 + (t & 31);
    const int xh = t >> 5;
    const int b = blockIdx.z;
    const int x0 = xh * (4 * PXW) + wv * PXW;

    const unsigned short* inb = in + (size_t)b * HW * CPIN;
    const short8 kz = {0,0,0,0,0,0,0,0};
    const unsigned short* wfs[3] = {wf0, wf1, wf2};
    const float* bss[3] = {b0, b1, b2};
    unsigned int* tl = lds[wv];

    constexpr int ZD = (R - 3 * MR) / 2;
    for (int i = lane; i < PXW * ZD; i += 64) {
        const int px = i / ZD, d = 3 * MR / 2 + i % ZD;
        tl[px * SDW + (d ^ ((px & SWM) << 2))] = 0;
    }

#pragma unroll
    for (int which = 0; which < 3; ++which) {
        const int dil = which + 1;
        const short8* wp = (const short8*)wfs[which];
        const float* bs = bss[which];
        f32x4 acc[MT][NF];
#pragma unroll
        for (int mt = 0; mt < MT; ++mt)
#pragma unroll
            for (int nf = 0; nf < NF; ++nf) acc[mt][nf] = (f32x4){0.f,0.f,0.f,0.f};
#pragma unroll
        for (int tap = 0; tap < 9; ++tap) {
            const int dy = tap / 3 - 1, dx = tap % 3 - 1;
            const int yy = y + dy * dil;
            const bool yok = (unsigned)yy < 256u;
            short8 af[MT][KK];
#pragma unroll
            for (int mt = 0; mt < MT; ++mt)
#pragma unroll
                for (int kk = 0; kk < KK; ++kk)
                    af[mt][kk] = wp[((tap * MT + mt) * KK + kk) * 64 + lane];
#pragma unroll
            for (int nf = 0; nf < NF; ++nf) {
                const int xx = x0 + nf * 16 + col + dx * dil;
                const bool ok = yok && ((unsigned)xx < 256u);
                const int pix = ok ? (yy * 256 + xx) : 0;
                const short8* bp = (const short8*)(inb + (size_t)pix * CPIN + g * 8);
#pragma unroll
                for (int kk = 0; kk < KK; ++kk) {
                    short8 bf = bp[kk * 4];
                    if (!ok) bf = kz;
#pragma unroll
                    for (int mt = 0; mt < MT; ++mt)
                        acc[mt][nf] = __builtin_amdgcn_mfma_f32_16x16x32_bf16(
                            af[mt][kk], bf, acc[mt][nf], 0, 0, 0);
                }
            }
        }
#pragma unroll
        for (int mt = 0; mt < MT; ++mt)
#pragma unroll
            for (int nf = 0; nf < NF; ++nf)
#pragma unroll
                for (int e = 0; e < 2; ++e) {
                    const int rb = mt * 16 + g * 4 + e * 2;
                    if (rb < MR) {
                        float v0 = acc[mt][nf][e * 2]     + __ldg(bs + rb);
                        float v1 = acc[mt][nf][e * 2 + 1] + ((rb + 1 < MR) ? __ldg(bs + rb + 1) : 0.f);
                        const int px = nf * 16 + col;
                        const int d = (which * MR + rb) >> 1;
                        tl[px * SDW + (d ^ ((px & SWM) << 2))] = pack2(v0, v1);
                    }
                }
    }
    const size_t gbase = ((size_t)b * HW + y * 256 + x0) * CPAD;
    wave_store<PXW, R, 0>(tl, lane, outb, nullptr, gbase, CPAD);
}

// ---------------------------------------------------------------------------
// LDS-staged fused AFLB.
//   Block: 4 waves, 64-px segment, RPB output rows, ALL output channels.
//   Stage rows [y0-1, y0+RPB] x [x0-1, x0+65) in LDS (zeros outside image),
//   XOR-swizzled 16B granules. Pass1 (att conv, split over waves) -> softmax
//   -> att in LDS. Pass2 (modconv, M split over waves) reads LDS B-frags.
//   Epilogue: acc -> LDS (reuse staging) -> coalesced store (+res,relu).
// KK: channel blocks (2=64ch, 1=32ch). RPB: rows/block (1 for 60ch, 2 for 30).
// ---------------------------------------------------------------------------
template<int KK, int RPB, int RES>
__global__ __launch_bounds__(256, 4) void aflb_s(
    const unsigned short* __restrict__ in,
    const unsigned short* __restrict__ awf, const float* __restrict__ ab,
    const unsigned short* __restrict__ fwf,
    const unsigned short* __restrict__ res,
    unsigned short* __restrict__ outb)
{
    constexpr int CPIN = KK * 32, MTT = 2 * KK, CPAD = 16 * MTT, DPP = CPAD / 2;
    constexpr int SROWS = RPB + 2, SPX = 66, SGR = KK * 4, SWM = SGR - 1;
    constexpr int NSTG = SROWS * SPX * SGR;       // 16B granules staged
    constexpr int ATOFF = NSTG * 4;               // dword offset of att area
    constexpr int NATT = RPB * 64 * 9;
    __shared__ __align__(16) unsigned int sm[ATOFF + NATT];

    const int tid = threadIdx.x;
    const int lane = tid & 63, wv = tid >> 6;
    const int col = lane & 15, g = lane >> 4;
    const int bx = blockIdx.x;
    const int xcd = bx & 7, t = bx >> 3;
    const int y0 = (RPB == 1) ? (xcd * 32 + (t & 31)) : (xcd * 32 + (t & 15) * 2);
    const int xseg = (RPB == 1) ? ((t >> 5) & 3) : ((t >> 4) & 3);
    const int x0 = xseg * 64;
    const int b = blockIdx.z;
    const unsigned short* inb = in + (size_t)b * HW * CPIN;

    // ---- stage input tile (coalesced global reads, swizzled LDS writes) ----
    for (int u = tid; u < NSTG; u += 256) {
        const int slot = u & SWM;
        const int px = (u / SGR) % SPX;
        const int row = u / (SGR * SPX);
        const int yy = y0 + row - 1, xx = x0 + px - 1;
        i32x4 v = {0,0,0,0};
        if ((unsigned)yy < 256u && (unsigned)xx < 256u)
            v = *(const i32x4*)(inb + (size_t)(yy * 256 + xx) * CPIN + slot * 8);
        *(i32x4*)&sm[((row * SPX + px) * SGR + (slot ^ (px & SWM))) * 4] = v;
    }
    __syncthreads();

    const short8* awp = (const short8*)awf;
    const short8* fwp = (const short8*)fwf;

    // ---- pass 1: attention scores (split over waves) ----
    constexpr int NF1 = (RPB == 1) ? 1 : 2;
    const int arow = (RPB == 1) ? 0 : (wv >> 1);
    const int apx0 = (RPB == 1) ? (wv * 16) : ((wv & 1) * 32);
    f32x4 aacc[NF1];
#pragma unroll
    for (int nf = 0; nf < NF1; ++nf) aacc[nf] = (f32x4){0.f,0.f,0.f,0.f};
#pragma unroll
    for (int tap = 0; tap < 9; ++tap) {
        const int dy = tap / 3 - 1, dx = tap % 3 - 1;
        const int rl = arow + dy + 1;
        short8 afa[KK];
#pragma unroll
        for (int kk = 0; kk < KK; ++kk)
            afa[kk] = awp[(tap * KK + kk) * 64 + lane];
#pragma unroll
        for (int nf = 0; nf < NF1; ++nf) {
            const int pl = 1 + apx0 + nf * 16 + col + dx;
#pragma unroll
            for (int kk = 0; kk < KK; ++kk) {
                const int slot = kk * 4 + g;
                short8 bf = *(const short8*)&sm[((rl * SPX + pl) * SGR + (slot ^ (pl & SWM))) * 4];
                aacc[nf] = __builtin_amdgcn_mfma_f32_16x16x32_bf16(afa[kk], bf, aacc[nf], 0, 0, 0);
            }
        }
    }
    // softmax over 9 channels, write att to LDS
#pragma unroll
    for (int nf = 0; nf < NF1; ++nf) {
        float v[4];
        float m = -1e30f;
#pragma unroll
        for (int r = 0; r < 4; ++r) {
            const int row = g * 4 + r;
            v[r] = (row < 9) ? (aacc[nf][r] + __ldg(ab + row)) : -1e30f;
            m = fmaxf(m, v[r]);
        }
        m = fmaxf(m, __shfl_xor(m, 16));
        m = fmaxf(m, __shfl_xor(m, 32));
        float e[4]; float s = 0.f;
#pragma unroll
        for (int r = 0; r < 4; ++r) { e[r] = (g * 4 + r < 9) ? __expf(v[r] - m) : 0.f; s += e[r]; }
        s += __shfl_xor(s, 16);
        s += __shfl_xor(s, 32);
        const float inv = 1.f / s;
        const int px = apx0 + nf * 16 + col;
#pragma unroll
        for (int r = 0; r < 4; ++r) {
            const int row = g * 4 + r;
            if (row < 9) sm[ATOFF + (arow * 64 + px) * 9 + row] = __float_as_uint(e[r] * inv);
        }
    }
    __syncthreads();

    // ---- pass 2: modulated conv (M split over waves, NF=4 = 64 px) ----
    const int prow = (RPB == 1) ? 0 : (wv >> 1);
    const int mt = (RPB == 1) ? wv : (wv & 1);
    f32x4 acc[4];
#pragma unroll
    for (int nf = 0; nf < 4; ++nf) acc[nf] = (f32x4){0.f,0.f,0.f,0.f};
#pragma unroll
    for (int tap = 0; tap < 9; ++tap) {
        const int dy = tap / 3 - 1, dx = tap % 3 - 1;
        const int rl = prow + dy + 1;
        float av[4];
#pragma unroll
        for (int nf = 0; nf < 4; ++nf)
            av[nf] = __uint_as_float(sm[ATOFF + (prow * 64 + nf * 16 + col) * 9 + tap]);
        short8 af[KK];
#pragma unroll
        for (int kk = 0; kk < KK; ++kk)
            af[kk] = fwp[((tap * MTT + mt) * KK + kk) * 64 + lane];
#pragma unroll
        for (int nf = 0; nf < 4; ++nf) {
            const int pl = 1 + nf * 16 + col + dx;
            f32x4 p = (f32x4){0.f,0.f,0.f,0.f};
#pragma unroll
            for (int kk = 0; kk < KK; ++kk) {
                const int slot = kk * 4 + g;
                short8 bf = *(const short8*)&sm[((rl * SPX + pl) * SGR + (slot ^ (pl & SWM))) * 4];
                p = __builtin_amdgcn_mfma_f32_16x16x32_bf16(af[kk], bf, p, 0, 0, 0);
            }
#pragma unroll
            for (int r = 0; r < 4; ++r)
                acc[nf][r] = fmaf(av[nf], p[r], acc[nf][r]);
        }
    }
    __syncthreads();

    // ---- epilogue: acc -> LDS tile (reuse staging area) ----
#pragma unroll
    for (int nf = 0; nf < 4; ++nf) {
        const int px = nf * 16 + col;
        const int base = ((RPB == 2 ? prow * 64 : 0) + px) * DPP;
        const int rp = mt * 8 + g * 2;
        unsigned long long w =
            (unsigned long long)pack2(acc[nf][0], acc[nf][1]) |
            ((unsigned long long)pack2(acc[nf][2], acc[nf][3]) << 32);
        *(unsigned long long*)&sm[base + (rp ^ ((px & SWM) << 2))] = w;
    }
    __syncthreads();

    // ---- coalesced readout (+residual,relu) ----
    constexpr int NOUT = RPB * 64 * SGR;
    for (int u = tid; u < NOUT; u += 256) {
        const int slot = u & SWM;
        const int px = (u / SGR) & 63;
        const int r = (RPB == 2) ? (u / (SGR * 64)) : 0;
        i32x4 v = *(i32x4*)&sm[((r * 64 + px) * DPP) + ((slot ^ (px & SWM)) << 2)];
        const size_t go = ((size_t)b * HW + (size_t)(y0 + r) * 256 + x0 + px) * CPAD + slot * 8;
        if (RES) v = addrelu4(v, *(const i32x4*)(res + go));
        *(i32x4*)(outb + go) = v;
    }
}

// ---------------------------------------------------------------------------
// Final conv 30->4 + ms_up, f32 NCHW output.
// ---------------------------------------------------------------------------
__global__ __launch_bounds__(256, 4) void final_k(
    const unsigned short* __restrict__ in,
    const unsigned short* __restrict__ wfrag,
    const float* __restrict__ bias,
    const float* __restrict__ msup, float* __restrict__ outf)
{
    constexpr int CPIN = 32, NF = 2;
    const int lane = threadIdx.x & 63, wv = threadIdx.x >> 6;
    const int col = lane & 15, g = lane >> 4;
    const int bx = blockIdx.x;
    const int xcd = bx & 7, t = bx >> 3;
    const int y = xcd * 32 + (t & 31);
    const int xh = t >> 5;
    const int b = blockIdx.z;
    const int x0 = xh * 128 + wv * 32;

    const unsigned short* inb = in + (size_t)b * HW * CPIN;
    const short8 kz = {0,0,0,0,0,0,0,0};
    const short8* wp = (const short8*)wfrag;

    f32x4 acc[NF];
#pragma unroll
    for (int nf = 0; nf < NF; ++nf) acc[nf] = (f32x4){0.f,0.f,0.f,0.f};
#pragma unroll
    for (int tap = 0; tap < 9; ++tap) {
        const int dy = tap / 3 - 1, dx = tap % 3 - 1;
        const int yy = y + dy;
        const bool yok = (unsigned)yy < 256u;
        const short8 af = wp[tap * 64 + lane];
#pragma unroll
        for (int nf = 0; nf < NF; ++nf) {
            const int xx = x0 + nf * 16 + col + dx;
            const bool ok = yok && ((unsigned)xx < 256u);
            const int pix = ok ? (yy * 256 + xx) : 0;
            short8 bf = *(const short8*)(inb + (size_t)pix * CPIN + g * 8);
            if (!ok) bf = kz;
            acc[nf] = __builtin_amdgcn_mfma_f32_16x16x32_bf16(af, bf, acc[nf], 0, 0, 0);
        }
    }
#pragma unroll
    for (int nf = 0; nf < NF; ++nf) {
        const int pix = y * 256 + x0 + nf * 16 + col;
        if (g == 0) {
#pragma unroll
            for (int r = 0; r < 4; ++r) {
                const size_t oi = ((size_t)b * 4 + r) * HW + pix;
                outf[oi] = acc[nf][r] + __ldg(bias + r) + msup[oi];
            }
        }
    }
}

// ---------------------------------------------------------------------------
// Weight prep: f32 [O][I][3][3] -> bf16 A-fragment layout [tap][mt][kk][512].
// ---------------------------------------------------------------------------
struct PrepDesc { const float* src; int cout, cin, mt, kk, flags, dstoff; };
struct PrepArgs { PrepDesc d[18]; };

__global__ __launch_bounds__(256) void prep_k(PrepArgs pa, unsigned short* __restrict__ wb)
{
    PrepDesc d = pa.d[blockIdx.x];
    const int n = 9 * d.mt * d.kk * 512;
    for (int e = threadIdx.x; e < n; e += 256) {
        const int j = e & 7;
        const int lane = (e >> 3) & 63;
        const int i512 = e >> 9;
        const int kk = i512 % d.kk;
        const int mt = (i512 / d.kk) % d.mt;
        const int tap = i512 / (d.kk * d.mt);
        const int rpos = mt * 16 + (lane & 15);
        const int kpos = kk * 32 + (lane >> 4) * 8 + j;
        int o = rpos, ic = kpos;
        bool ok = true;
        if (d.flags & 2) {
            if (rpos < 30) o = rpos;
            else if (rpos >= 32 && rpos < 62) o = rpos - 2;
            else ok = false;
        }
        if (d.flags & 1) {
            if (kpos < 30) ic = kpos;
            else if (kpos >= 32 && kpos < 62) ic = kpos - 2;
            else ok = false;
        }
        float v = 0.f;
        if (ok && o < d.cout && ic < d.cin) v = d.src[(o * d.cin + ic) * 9 + tap];
        wb[d.dstoff + e] = f2bf(v);
    }
}

// ---------------------------------------------------------------------------
// up-conv (ms_org 4->64 @64x64, f32 NCHW) — small, VALU direct conv.
// ---------------------------------------------------------------------------
template<int CIN, int COUT, int OCB, int H, int W>
__launch_bounds__(256)
__global__ void upconv_k(const float* __restrict__ in, const float* __restrict__ wgt,
                         const float* __restrict__ bias, float* __restrict__ out)
{
    constexpr int HWp = H * W;
    constexpr int NOCB = COUT / OCB;
    const int tx = threadIdx.x;
    const int lx = tx & 63, ly = tx >> 6;
    const int gx = blockIdx.x * 64 + lx;
    const int gy = blockIdx.y * 4 + ly;
    const int b = blockIdx.z / NOCB;
    const int ocb = blockIdx.z % NOCB;
    const int pixp = gy * W + gx;
    const float* inb = in + (size_t)b * CIN * HWp;

    int off[9]; float mul[9];
#pragma unroll
    for (int dy = 0; dy < 3; ++dy)
#pragma unroll
        for (int dx = 0; dx < 3; ++dx) {
            int p = dy * 3 + dx;
            int yy = gy + dy - 1, xx = gx + dx - 1;
            bool okp = ((unsigned)yy < (unsigned)H) && ((unsigned)xx < (unsigned)W);
            off[p] = okp ? (yy * W + xx) : 0;
            mul[p] = okp ? 1.f : 0.f;
        }
    float acc[OCB];
#pragma unroll
    for (int o = 0; o < OCB; ++o) acc[o] = 0.f;
    const float* wbase = wgt + (size_t)(ocb * OCB) * CIN * 9;
#pragma unroll
    for (int ic = 0; ic < CIN; ++ic) {
        const float* ip = inb + (size_t)ic * HWp;
        float tv[9];
#pragma unroll
        for (int p = 0; p < 9; ++p) tv[p] = __ldg(ip + off[p]) * mul[p];
#pragma unroll
        for (int o = 0; o < OCB; ++o) {
            const float* wq = wbase + (size_t)(o * CIN + ic) * 9;
#pragma unroll
            for (int p = 0; p < 9; ++p) acc[o] = fmaf(tv[p], wq[p], acc[o]);
        }
    }
#pragma unroll
    for (int o = 0; o < OCB; ++o)
        out[((size_t)b * COUT + ocb * OCB + o) * HWp + pixp] = acc[o] + __ldg(bias + ocb * OCB + o);
}

// ---------------------------------------------------------------------------
// Build data1 (prelu(pixshuf(t_up))||pan) and ms_up as NHWC bf16 pad32.
// ---------------------------------------------------------------------------
__global__ __launch_bounds__(256) void build_inputs(
    const float* __restrict__ tup, const float* __restrict__ pan,
    const float* __restrict__ aup, const float* __restrict__ msup,
    unsigned short* __restrict__ data1, unsigned short* __restrict__ msb)
{
    const int i = blockIdx.x * 256 + threadIdx.x;
    const int b = i >> 16, pixp = i & 65535;
    const int y = pixp >> 8, x = pixp & 255;
    unsigned short o[32];
#pragma unroll
    for (int c = 0; c < 32; ++c) o[c] = 0;
    unsigned short* dst;
    if (blockIdx.y == 0) {
        const float a = __ldg(aup);
#pragma unroll
        for (int c = 0; c < 4; ++c) {
            const int ch = c * 16 + (y & 3) * 4 + (x & 3);
            float v = tup[(((size_t)b * 64 + ch) << 12) + ((y >> 2) << 6) + (x >> 2)];
            v = (v >= 0.f) ? v : a * v;
            o[c] = f2bf(v);
        }
        o[4] = f2bf(pan[((size_t)b << 16) + pixp]);
        dst = data1;
    } else {
#pragma unroll
        for (int c = 0; c < 4; ++c)
            o[c] = f2bf(msup[(((size_t)b * 4 + c) << 16) + pixp]);
        dst = msb;
    }
    short8* dp = (short8*)(dst + (size_t)i * 32);
#pragma unroll
    for (int q = 0; q < 4; ++q) {
        short8 s;
#pragma unroll
        for (int r = 0; r < 8; ++r) s[r] = (short)o[q * 8 + r];
        dp[q] = s;
    }
}

// ---------------------------------------------------------------------------
extern "C" void kernel_launch(void* const* d_in, const int* in_sizes, int n_in,
                              void* d_out, int out_size, void* d_ws, size_t ws_size,
                              hipStream_t stream) {
    const float* ms_up  = (const float*)d_in[0];
    const float* ms_org = (const float*)d_in[1];
    const float* pan    = (const float*)d_in[2];
    const float* w_up4  = (const float*)d_in[3];
    const float* b_up4  = (const float*)d_in[4];
    const float* a_up4  = (const float*)d_in[5];
    const float* w_blk53= (const float*)d_in[6];
    const float* b_blk53= (const float*)d_in[7];
    const float* a_blk53= (const float*)d_in[8];
    const float* w_blk43= (const float*)d_in[9];
    const float* b_blk43= (const float*)d_in[10];
    const float* a_blk43= (const float*)d_in[11];
    const float* w1a=(const float*)d_in[12]; const float* b1a=(const float*)d_in[13];
    const float* w1b=(const float*)d_in[14]; const float* b1b=(const float*)d_in[15];
    const float* w1c=(const float*)d_in[16]; const float* b1c=(const float*)d_in[17];
    const float* aw1=(const float*)d_in[18]; const float* ab1=(const float*)d_in[19];
    const float* fw1=(const float*)d_in[20];
    const float* aw2=(const float*)d_in[21]; const float* ab2=(const float*)d_in[22];
    const float* fw2=(const float*)d_in[23];
    const float* w_blk2=(const float*)d_in[24]; const float* b_blk2=(const float*)d_in[25]; const float* a_blk2=(const float*)d_in[26];
    const float* w2a=(const float*)d_in[27]; const float* b2a=(const float*)d_in[28];
    const float* w2b=(const float*)d_in[29]; const float* b2b=(const float*)d_in[30];
    const float* w2c=(const float*)d_in[31]; const float* b2c=(const float*)d_in[32];
    const float* aw3=(const float*)d_in[33]; const float* ab3=(const float*)d_in[34];
    const float* fw3=(const float*)d_in[35];
    const float* aw4=(const float*)d_in[36]; const float* ab4=(const float*)d_in[37];
    const float* fw4=(const float*)d_in[38];
    const float* w_c6=(const float*)d_in[39]; const float* b_c6=(const float*)d_in[40];

    float* out = (float*)d_out;
    char* ws = (char*)d_ws;

    const size_t BIG = (size_t)2 * HW * 64 * 2;   // 16.78 MB (NHWC pad64 bf16)
    const size_t HALF = BIG / 2;
    unsigned short* bufA = (unsigned short*)(ws);
    unsigned short* bufB = (unsigned short*)(ws + BIG);
    unsigned short* bufC = (unsigned short*)(ws + 2 * BIG);
    unsigned short* data1 = bufC;
    float*          t_up  = (float*)(ws + 2 * BIG + HALF);
    unsigned short* msb   = bufB;
    unsigned short* bufD = bufC;
    unsigned short* bufE = bufB;
    unsigned short* bufF = bufA;
    unsigned short* wb = (unsigned short*)(ws + 3 * BIG);

    if (ws_size < 3 * BIG + 1000000) return;

    PrepArgs pa;
    int off = 0, li = 0;
    auto add = [&](const float* s, int cout, int cin, int mt, int kk, int flags) {
        pa.d[li].src = s; pa.d[li].cout = cout; pa.d[li].cin = cin;
        pa.d[li].mt = mt; pa.d[li].kk = kk; pa.d[li].flags = flags; pa.d[li].dstoff = off;
        int ret = off; off += 9 * mt * kk * 512; ++li; return ret;
    };
    const int o_blk43 = add(w_blk43, 30, 4, 2, 1, 0);
    const int o_blk53 = add(w_blk53, 30, 5, 2, 1, 0);
    const int o_w1a   = add(w1a, 20, 60, 2, 2, 1);
    const int o_w1b   = add(w1b, 20, 60, 2, 2, 1);
    const int o_w1c   = add(w1c, 20, 60, 2, 2, 1);
    const int o_aw1   = add(aw1,  9, 60, 1, 2, 0);
    const int o_fw1   = add(fw1, 60, 60, 4, 2, 0);
    const int o_aw2   = add(aw2,  9, 60, 1, 2, 0);
    const int o_fw2   = add(fw2, 60, 60, 4, 2, 2);
    const int o_blk2  = add(w_blk2, 30, 60, 2, 2, 1);
    const int o_w2a   = add(w2a, 10, 30, 1, 1, 0);
    const int o_w2b   = add(w2b, 10, 30, 1, 1, 0);
    const int o_w2c   = add(w2c, 10, 30, 1, 1, 0);
    const int o_aw3   = add(aw3,  9, 30, 1, 1, 0);
    const int o_fw3   = add(fw3, 30, 30, 2, 1, 0);
    const int o_aw4   = add(aw4,  9, 30, 1, 1, 0);
    const int o_fw4   = add(fw4, 30, 30, 2, 1, 0);
    const int o_c6    = add(w_c6,  4, 30, 1, 1, 0);

    prep_k<<<dim3(18), 256, 0, stream>>>(pa, wb);

    upconv_k<4, 64, 16, 64, 64><<<dim3(1, 16, 8), 256, 0, stream>>>(ms_org, w_up4, b_up4, t_up);
    build_inputs<<<dim3(512, 2), 256, 0, stream>>>(t_up, pan, a_up4, ms_up, data1, msb);

    const dim3 B256(256);
    const dim3 G2(512, 1, 2);

    // out1 (bufA, pad64, split-60): blk43 -> rows 0..29, blk53 -> rows 32..61
    conv_nf<1,2,1,2,1><<<G2,B256,0,stream>>>(msb,   wb+o_blk43, b_blk43, 30, a_blk43, bufA, 64, 0);
    conv_nf<1,2,1,2,1><<<G2,B256,0,stream>>>(data1, wb+o_blk53, b_blk53, 30, a_blk53, bufA, 64, 32);

    // ---- rmrs1 (60 ch) ----
    trident_k<2,20,2,2><<<G2,B256,0,stream>>>(bufA, wb+o_w1a, wb+o_w1b, wb+o_w1c, b1a, b1b, b1c, bufB);
    aflb_s<2,1,0><<<dim3(1024,1,2),B256,0,stream>>>(bufB, wb+o_aw1, ab1, wb+o_fw1, nullptr, bufC);
    aflb_s<2,1,1><<<dim3(1024,1,2),B256,0,stream>>>(bufC, wb+o_aw2, ab2, wb+o_fw2, bufA,   bufB);

    // blk2: out2 -> 30ch (bufD pad32)
    conv_nf<2,2,1,2,1><<<G2,B256,0,stream>>>(bufB, wb+o_blk2, b_blk2, 30, a_blk2, bufD, 32, 0);

    // ---- rmrs2 (30 ch) ----
    trident_k<1,10,1,2><<<G2,B256,0,stream>>>(bufD, wb+o_w2a, wb+o_w2b, wb+o_w2c, b2a, b2b, b2c, bufE);
    aflb_s<1,2,0><<<dim3(512,1,2),B256,0,stream>>>(bufE, wb+o_aw3, ab3, wb+o_fw3, nullptr, bufF);
    aflb_s<1,2,1><<<dim3(512,1,2),B256,0,stream>>>(bufF, wb+o_aw4, ab4, wb+o_fw4, bufD,   bufE);

    // final: conv 30->4 + ms_up (f32 NCHW out)
    final_k<<<G2,B256,0,stream>>>(bufE, wb+o_c6, b_c6, ms_up, out);
}

// Round 6
// 259.234 us; speedup vs baseline: 6.5856x; 1.1295x over previous
//
#include <hip/hip_runtime.h>

typedef __attribute__((ext_vector_type(8))) short short8;
typedef __attribute__((ext_vector_type(4))) float f32x4;
typedef __attribute__((ext_vector_type(4))) int i32x4;

#define HW 65536

__device__ __forceinline__ float bf2f(unsigned short u){
    union { unsigned int i; float f; } x; x.i = ((unsigned int)u) << 16; return x.f;
}
__device__ __forceinline__ unsigned short f2bf(float f){
    union { float f; unsigned int i; } x; x.f = f;
    unsigned int r = x.i + 0x7fffu + ((x.i >> 16) & 1u);
    return (unsigned short)(r >> 16);
}
__device__ __forceinline__ unsigned int pack2(float a, float b){
    return (unsigned int)f2bf(a) | ((unsigned int)f2bf(b) << 16);
}
__device__ __forceinline__ i32x4 addrelu4(i32x4 a, i32x4 b){
    i32x4 o;
#pragma unroll
    for (int k = 0; k < 4; ++k) {
        unsigned int ua = (unsigned int)a[k], ub = (unsigned int)b[k];
        float x0 = bf2f((unsigned short)(ua & 0xffff)) + bf2f((unsigned short)(ub & 0xffff));
        float x1 = bf2f((unsigned short)(ua >> 16))    + bf2f((unsigned short)(ub >> 16));
        o[k] = (int)(((unsigned int)f2bf(fmaxf(x0, 0.f))) |
                     ((unsigned int)f2bf(fmaxf(x1, 0.f)) << 16));
    }
    return o;
}

// ---------------------------------------------------------------------------
// Staged single conv (dil=1): 3-row LDS stage (+1-granule pad), 30 out rows.
// out: cpad/coff runtime (pad64-half for out1, pad32 for blk2). PRELU epilogue.
// ---------------------------------------------------------------------------
template<int KK, int PRELU>
__global__ __launch_bounds__(256, 4) void sconv_k(
    const unsigned short* __restrict__ in,
    const unsigned short* __restrict__ wfrag,
    const float* __restrict__ bias,
    const float* __restrict__ alphap,
    unsigned short* __restrict__ outb, int cpad, int coff)
{
    constexpr int CPIN = KK * 32, SGR = KK * 4, SGRP = SGR + 1, SPX = 66;
    constexpr int NSTGDW = 3 * SPX * SGRP * 4;
    constexpr int ODP = 20;                       // (4+1)*4 dwords per px
    constexpr int OUTOFF = NSTGDW;
    __shared__ __align__(16) unsigned int sm[NSTGDW + 64 * ODP];
    const int tid = threadIdx.x;
    const int lane = tid & 63, wv = tid >> 6;
    const int col = lane & 15, g = lane >> 4;
    const int bx = blockIdx.x;
    const int xcd = bx & 7, t = bx >> 3;
    const int y0 = xcd * 32 + (t & 31);
    const int x0 = ((t >> 5) & 3) * 64;
    const int b = blockIdx.z;
    const unsigned short* inb = in + (size_t)b * HW * CPIN;

#pragma unroll
    for (int rr = 0; rr < 3; ++rr) {
        const int yy = y0 + rr - 1;
        for (int u = tid; u < SPX * SGR; u += 256) {
            const int slot = u & (SGR - 1), px = u / SGR;
            const int xx = x0 - 1 + px;
            i32x4 v = {0,0,0,0};
            if ((unsigned)yy < 256u && (unsigned)xx < 256u)
                v = *(const i32x4*)(inb + (size_t)(yy * 256 + xx) * CPIN + slot * 8);
            *(i32x4*)&sm[((rr * SPX + px) * SGRP + slot) * 4] = v;
        }
    }
    if (tid < 64) sm[OUTOFF + tid * ODP + 15] = 0;   // rows 30,31 pad
    __syncthreads();

    const short8* wp = (const short8*)wfrag;
    f32x4 acc[2];
    acc[0] = (f32x4){0.f,0.f,0.f,0.f}; acc[1] = (f32x4){0.f,0.f,0.f,0.f};
#pragma unroll
    for (int tap = 0; tap < 9; ++tap) {
        const int dy = tap / 3 - 1, dx = tap % 3 - 1;
        const int rl = dy + 1;
        short8 af[2][KK];
#pragma unroll
        for (int mt = 0; mt < 2; ++mt)
#pragma unroll
            for (int kk = 0; kk < KK; ++kk)
                af[mt][kk] = wp[((tap * 2 + mt) * KK + kk) * 64 + lane];
        const int pl = 1 + wv * 16 + col + dx;
#pragma unroll
        for (int kk = 0; kk < KK; ++kk) {
            short8 bf = *(const short8*)&sm[((rl * SPX + pl) * SGRP + kk * 4 + g) * 4];
#pragma unroll
            for (int mt = 0; mt < 2; ++mt)
                acc[mt] = __builtin_amdgcn_mfma_f32_16x16x32_bf16(af[mt][kk], bf, acc[mt], 0, 0, 0);
        }
    }
    const float al = PRELU ? __ldg(alphap) : 0.f;
    const int px = wv * 16 + col;
#pragma unroll
    for (int mt = 0; mt < 2; ++mt)
#pragma unroll
        for (int e = 0; e < 2; ++e) {
            const int rb = mt * 16 + g * 4 + e * 2;
            if (rb < 30) {
                float v0 = acc[mt][e * 2]     + __ldg(bias + rb);
                float v1 = acc[mt][e * 2 + 1] + ((rb + 1 < 30) ? __ldg(bias + rb + 1) : 0.f);
                if (PRELU) { v0 = v0 >= 0.f ? v0 : al * v0; v1 = v1 >= 0.f ? v1 : al * v1; }
                if (rb + 1 >= 30) v1 = 0.f;
                sm[OUTOFF + px * ODP + (rb >> 1)] = pack2(v0, v1);
            }
        }
    __syncthreads();
    {
        const int slot = tid & 3, opx = tid >> 2;
        i32x4 v = *(i32x4*)&sm[OUTOFF + opx * ODP + slot * 4];
        const size_t go = ((size_t)b * HW + (size_t)y0 * 256 + x0 + opx) * cpad + coff + slot * 8;
        *(i32x4*)(outb + go) = v;
    }
}

// ---------------------------------------------------------------------------
// Staged trident: 3 dilated convs (d=1,2,3), rotating 3-row LDS stage
// (slot0=center, slots1/2=y±d restaged per dilation). Output packed rows
// which*MR, CPAD=KK*32, pad rows zeroed. +1-granule-pad LDS layout.
// ---------------------------------------------------------------------------
template<int KK, int MR>
__global__ __launch_bounds__(256, 4) void trident_s(
    const unsigned short* __restrict__ in,
    const unsigned short* __restrict__ wf0, const unsigned short* __restrict__ wf1,
    const unsigned short* __restrict__ wf2,
    const float* __restrict__ b0, const float* __restrict__ b1, const float* __restrict__ b2,
    unsigned short* __restrict__ outb)
{
    constexpr int CPIN = KK * 32, CPAD = KK * 32;
    constexpr int SGR = KK * 4, SGRP = SGR + 1, SPX = 70;
    constexpr int MT_ = (KK == 2) ? 2 : 1;
    constexpr int CPP = KK * 4, ODP = (CPP + 1) * 4;
    constexpr int NSTGDW = 3 * SPX * SGRP * 4;
    constexpr int OUTOFF = NSTGDW;
    __shared__ __align__(16) unsigned int sm[NSTGDW + 64 * ODP];
    const int tid = threadIdx.x;
    const int lane = tid & 63, wv = tid >> 6;
    const int col = lane & 15, g = lane >> 4;
    const int bx = blockIdx.x;
    const int xcd = bx & 7, t = bx >> 3;
    const int y0 = xcd * 32 + (t & 31);
    const int x0 = ((t >> 5) & 3) * 64;
    const int b = blockIdx.z;
    const unsigned short* inb = in + (size_t)b * HW * CPIN;

    auto stage_row = [&](int srow, int yy) {
        for (int u = tid; u < SPX * SGR; u += 256) {
            const int slot = u & (SGR - 1), px = u / SGR;
            const int xx = x0 - 3 + px;
            i32x4 v = {0,0,0,0};
            if ((unsigned)yy < 256u && (unsigned)xx < 256u)
                v = *(const i32x4*)(inb + (size_t)(yy * 256 + xx) * CPIN + slot * 8);
            *(i32x4*)&sm[((srow * SPX + px) * SGRP + slot) * 4] = v;
        }
    };

    const unsigned short* wfs[3] = {wf0, wf1, wf2};
    const float* bss[3] = {b0, b1, b2};

    stage_row(0, y0); stage_row(1, y0 - 1); stage_row(2, y0 + 1);
    if (tid < 64) {
#pragma unroll
        for (int dwp = 3 * MR / 2; dwp < CPP * 4; ++dwp) sm[OUTOFF + tid * ODP + dwp] = 0;
    }
    __syncthreads();

#pragma unroll
    for (int which = 0; which < 3; ++which) {
        const int d = which + 1;
        const short8* wp = (const short8*)wfs[which];
        const float* bs = bss[which];
        f32x4 acc[MT_];
#pragma unroll
        for (int mt = 0; mt < MT_; ++mt) acc[mt] = (f32x4){0.f,0.f,0.f,0.f};
#pragma unroll
        for (int tap = 0; tap < 9; ++tap) {
            const int dy = tap / 3 - 1, dx = tap % 3 - 1;
            const int rl = (dy == 0) ? 0 : (dy < 0 ? 1 : 2);
            short8 af[MT_][KK];
#pragma unroll
            for (int mt = 0; mt < MT_; ++mt)
#pragma unroll
                for (int kk = 0; kk < KK; ++kk)
                    af[mt][kk] = wp[((tap * MT_ + mt) * KK + kk) * 64 + lane];
            const int pl = 3 + wv * 16 + col + dx * d;
#pragma unroll
            for (int kk = 0; kk < KK; ++kk) {
                short8 bf = *(const short8*)&sm[((rl * SPX + pl) * SGRP + kk * 4 + g) * 4];
#pragma unroll
                for (int mt = 0; mt < MT_; ++mt)
                    acc[mt] = __builtin_amdgcn_mfma_f32_16x16x32_bf16(af[mt][kk], bf, acc[mt], 0, 0, 0);
            }
        }
        const int px = wv * 16 + col;
#pragma unroll
        for (int mt = 0; mt < MT_; ++mt)
#pragma unroll
            for (int e = 0; e < 2; ++e) {
                const int rb = mt * 16 + g * 4 + e * 2;
                if (rb < MR) {
                    float v0 = acc[mt][e * 2]     + __ldg(bs + rb);
                    float v1 = acc[mt][e * 2 + 1] + ((rb + 1 < MR) ? __ldg(bs + rb + 1) : 0.f);
                    if (rb + 1 >= MR) v1 = 0.f;
                    sm[OUTOFF + px * ODP + ((which * MR + rb) >> 1)] = pack2(v0, v1);
                }
            }
        __syncthreads();
        if (which < 2) {
            stage_row(1, y0 - (d + 1)); stage_row(2, y0 + (d + 1));
            __syncthreads();
        }
    }

    for (int u = tid; u < 64 * CPP; u += 256) {
        const int slot = u & (CPP - 1), opx = u / CPP;
        i32x4 v = *(i32x4*)&sm[OUTOFF + opx * ODP + slot * 4];
        const size_t go = ((size_t)b * HW + (size_t)y0 * 256 + x0 + opx) * CPAD + slot * 8;
        *(i32x4*)(outb + go) = v;
    }
}

// ---------------------------------------------------------------------------
// Staged fused AFLB (+1-granule-pad LDS): stage SROWS rows, att conv ->
// softmax -> att in LDS -> modulated conv -> out tile -> coalesced store.
// KK: input ch blocks. RPB: output rows per block (1 for 60ch, 2 for 30ch).
// ---------------------------------------------------------------------------
template<int KK, int RPB, int RES>
__global__ __launch_bounds__(256, 4) void aflb_p(
    const unsigned short* __restrict__ in,
    const unsigned short* __restrict__ awf, const float* __restrict__ ab,
    const unsigned short* __restrict__ fwf,
    const unsigned short* __restrict__ res,
    unsigned short* __restrict__ outb)
{
    constexpr int CPIN = KK * 32, MTT = 2 * KK, CPAD = 16 * MTT;
    constexpr int SROWS = RPB + 2, SPX = 66, SGR = KK * 4, SGRP = SGR + 1;
    constexpr int CPP = CPAD / 8, ODP = (CPP + 1) * 4;
    constexpr int NSTGDW = SROWS * SPX * SGRP * 4;
    constexpr int ATOFF = NSTGDW;
    constexpr int NATT = RPB * 64 * 9;
    constexpr int OUTOFF = ATOFF + NATT;
    __shared__ __align__(16) unsigned int sm[OUTOFF + RPB * 64 * ODP];

    const int tid = threadIdx.x;
    const int lane = tid & 63, wv = tid >> 6;
    const int col = lane & 15, g = lane >> 4;
    const int bx = blockIdx.x;
    const int xcd = bx & 7, t = bx >> 3;
    const int y0 = (RPB == 1) ? (xcd * 32 + (t & 31)) : (xcd * 32 + (t & 15) * 2);
    const int xseg = (RPB == 1) ? ((t >> 5) & 3) : ((t >> 4) & 3);
    const int x0 = xseg * 64;
    const int b = blockIdx.z;
    const unsigned short* inb = in + (size_t)b * HW * CPIN;

    for (int u = tid; u < SROWS * SPX * SGR; u += 256) {
        const int slot = u & (SGR - 1);
        const int px = (u / SGR) % SPX;
        const int row = u / (SGR * SPX);
        const int yy = y0 + row - 1, xx = x0 - 1 + px;
        i32x4 v = {0,0,0,0};
        if ((unsigned)yy < 256u && (unsigned)xx < 256u)
            v = *(const i32x4*)(inb + (size_t)(yy * 256 + xx) * CPIN + slot * 8);
        *(i32x4*)&sm[((row * SPX + px) * SGRP + slot) * 4] = v;
    }
    __syncthreads();

    const short8* awp = (const short8*)awf;
    const short8* fwp = (const short8*)fwf;

    // ---- pass 1: attention scores (split over waves) ----
    constexpr int NF1 = (RPB == 1) ? 1 : 2;
    const int arow = (RPB == 1) ? 0 : (wv >> 1);
    const int apx0 = (RPB == 1) ? (wv * 16) : ((wv & 1) * 32);
    f32x4 aacc[NF1];
#pragma unroll
    for (int nf = 0; nf < NF1; ++nf) aacc[nf] = (f32x4){0.f,0.f,0.f,0.f};
#pragma unroll
    for (int tap = 0; tap < 9; ++tap) {
        const int dy = tap / 3 - 1, dx = tap % 3 - 1;
        const int rl = arow + dy + 1;
        short8 afa[KK];
#pragma unroll
        for (int kk = 0; kk < KK; ++kk)
            afa[kk] = awp[(tap * KK + kk) * 64 + lane];
#pragma unroll
        for (int nf = 0; nf < NF1; ++nf) {
            const int pl = 1 + apx0 + nf * 16 + col + dx;
#pragma unroll
            for (int kk = 0; kk < KK; ++kk) {
                short8 bf = *(const short8*)&sm[((rl * SPX + pl) * SGRP + kk * 4 + g) * 4];
                aacc[nf] = __builtin_amdgcn_mfma_f32_16x16x32_bf16(afa[kk], bf, aacc[nf], 0, 0, 0);
            }
        }
    }
#pragma unroll
    for (int nf = 0; nf < NF1; ++nf) {
        float v[4];
        float m = -1e30f;
#pragma unroll
        for (int r = 0; r < 4; ++r) {
            const int row = g * 4 + r;
            v[r] = (row < 9) ? (aacc[nf][r] + __ldg(ab + row)) : -1e30f;
            m = fmaxf(m, v[r]);
        }
        m = fmaxf(m, __shfl_xor(m, 16));
        m = fmaxf(m, __shfl_xor(m, 32));
        float e[4]; float s = 0.f;
#pragma unroll
        for (int r = 0; r < 4; ++r) { e[r] = (g * 4 + r < 9) ? __expf(v[r] - m) : 0.f; s += e[r]; }
        s += __shfl_xor(s, 16);
        s += __shfl_xor(s, 32);
        const float inv = 1.f / s;
        const int px = apx0 + nf * 16 + col;
#pragma unroll
        for (int r = 0; r < 4; ++r) {
            const int row = g * 4 + r;
            if (row < 9) sm[ATOFF + (arow * 64 + px) * 9 + row] = __float_as_uint(e[r] * inv);
        }
    }
    __syncthreads();

    // ---- pass 2: modulated conv (M split over waves, 64 px) ----
    const int prow = (RPB == 1) ? 0 : (wv >> 1);
    const int mt = (RPB == 1) ? wv : (wv & 1);
    f32x4 acc[4];
#pragma unroll
    for (int nf = 0; nf < 4; ++nf) acc[nf] = (f32x4){0.f,0.f,0.f,0.f};
#pragma unroll
    for (int tap = 0; tap < 9; ++tap) {
        const int dy = tap / 3 - 1, dx = tap % 3 - 1;
        const int rl = prow + dy + 1;
        float av[4];
#pragma unroll
        for (int nf = 0; nf < 4; ++nf)
            av[nf] = __uint_as_float(sm[ATOFF + (prow * 64 + nf * 16 + col) * 9 + tap]);
        short8 af[KK];
#pragma unroll
        for (int kk = 0; kk < KK; ++kk)
            af[kk] = fwp[((tap * MTT + mt) * KK + kk) * 64 + lane];
#pragma unroll
        for (int nf = 0; nf < 4; ++nf) {
            const int pl = 1 + nf * 16 + col + dx;
            f32x4 p = (f32x4){0.f,0.f,0.f,0.f};
#pragma unroll
            for (int kk = 0; kk < KK; ++kk) {
                short8 bf = *(const short8*)&sm[((rl * SPX + pl) * SGRP + kk * 4 + g) * 4];
                p = __builtin_amdgcn_mfma_f32_16x16x32_bf16(af[kk], bf, p, 0, 0, 0);
            }
#pragma unroll
            for (int r = 0; r < 4; ++r)
                acc[nf][r] = fmaf(av[nf], p[r], acc[nf][r]);
        }
    }
    __syncthreads();

#pragma unroll
    for (int nf = 0; nf < 4; ++nf) {
        const int px = nf * 16 + col;
        const int base = OUTOFF + ((RPB == 2 ? prow * 64 : 0) + px) * ODP;
        const int rp = mt * 8 + g * 2;
        unsigned long long w =
            (unsigned long long)pack2(acc[nf][0], acc[nf][1]) |
            ((unsigned long long)pack2(acc[nf][2], acc[nf][3]) << 32);
        *(unsigned long long*)&sm[base + rp] = w;
    }
    __syncthreads();

    constexpr int NOUT = RPB * 64 * CPP;
    for (int u = tid; u < NOUT; u += 256) {
        const int slot = u & (CPP - 1);
        const int px = (u / CPP) & 63;
        const int r = (RPB == 2) ? (u / (CPP * 64)) : 0;
        i32x4 v = *(i32x4*)&sm[OUTOFF + ((r * 64 + px) * ODP) + slot * 4];
        const size_t go = ((size_t)b * HW + (size_t)(y0 + r) * 256 + x0 + px) * CPAD + slot * 8;
        if (RES) v = addrelu4(v, *(const i32x4*)(res + go));
        *(i32x4*)(outb + go) = v;
    }
}

// ---------------------------------------------------------------------------
// Final conv 30->4 + ms_up, f32 NCHW output.
// ---------------------------------------------------------------------------
__global__ __launch_bounds__(256, 4) void final_k(
    const unsigned short* __restrict__ in,
    const unsigned short* __restrict__ wfrag,
    const float* __restrict__ bias,
    const float* __restrict__ msup, float* __restrict__ outf)
{
    constexpr int CPIN = 32, NF = 2;
    const int lane = threadIdx.x & 63, wv = threadIdx.x >> 6;
    const int col = lane & 15, g = lane >> 4;
    const int bx = blockIdx.x;
    const int xcd = bx & 7, t = bx >> 3;
    const int y = xcd * 32 + (t & 31);
    const int xh = t >> 5;
    const int b = blockIdx.z;
    const int x0 = xh * 128 + wv * 32;

    const unsigned short* inb = in + (size_t)b * HW * CPIN;
    const short8 kz = {0,0,0,0,0,0,0,0};
    const short8* wp = (const short8*)wfrag;

    f32x4 acc[NF];
#pragma unroll
    for (int nf = 0; nf < NF; ++nf) acc[nf] = (f32x4){0.f,0.f,0.f,0.f};
#pragma unroll
    for (int tap = 0; tap < 9; ++tap) {
        const int dy = tap / 3 - 1, dx = tap % 3 - 1;
        const int yy = y + dy;
        const bool yok = (unsigned)yy < 256u;
        const short8 af = wp[tap * 64 + lane];
#pragma unroll
        for (int nf = 0; nf < NF; ++nf) {
            const int xx = x0 + nf * 16 + col + dx;
            const bool ok = yok && ((unsigned)xx < 256u);
            const int pix = ok ? (yy * 256 + xx) : 0;
            short8 bf = *(const short8*)(inb + (size_t)pix * CPIN + g * 8);
            if (!ok) bf = kz;
            acc[nf] = __builtin_amdgcn_mfma_f32_16x16x32_bf16(af, bf, acc[nf], 0, 0, 0);
        }
    }
#pragma unroll
    for (int nf = 0; nf < NF; ++nf) {
        const int pix = y * 256 + x0 + nf * 16 + col;
        if (g == 0) {
#pragma unroll
            for (int r = 0; r < 4; ++r) {
                const size_t oi = ((size_t)b * 4 + r) * HW + pix;
                outf[oi] = acc[nf][r] + __ldg(bias + r) + msup[oi];
            }
        }
    }
}

// ---------------------------------------------------------------------------
// Weight prep: f32 [O][I][3][3] -> bf16 A-fragment layout [tap][mt][kk][512].
// ---------------------------------------------------------------------------
struct PrepDesc { const float* src; int cout, cin, mt, kk, flags, dstoff; };
struct PrepArgs { PrepDesc d[18]; };

__global__ __launch_bounds__(256) void prep_k(PrepArgs pa, unsigned short* __restrict__ wb)
{
    PrepDesc d = pa.d[blockIdx.x];
    const int n = 9 * d.mt * d.kk * 512;
    for (int e = threadIdx.x; e < n; e += 256) {
        const int j = e & 7;
        const int lane = (e >> 3) & 63;
        const int i512 = e >> 9;
        const int kk = i512 % d.kk;
        const int mt = (i512 / d.kk) % d.mt;
        const int tap = i512 / (d.kk * d.mt);
        const int rpos = mt * 16 + (lane & 15);
        const int kpos = kk * 32 + (lane >> 4) * 8 + j;
        int o = rpos, ic = kpos;
        bool ok = true;
        if (d.flags & 2) {
            if (rpos < 30) o = rpos;
            else if (rpos >= 32 && rpos < 62) o = rpos - 2;
            else ok = false;
        }
        if (d.flags & 1) {
            if (kpos < 30) ic = kpos;
            else if (kpos >= 32 && kpos < 62) ic = kpos - 2;
            else ok = false;
        }
        float v = 0.f;
        if (ok && o < d.cout && ic < d.cin) v = d.src[(o * d.cin + ic) * 9 + tap];
        wb[d.dstoff + e] = f2bf(v);
    }
}

// ---------------------------------------------------------------------------
// up-conv (ms_org 4->64 @64x64, f32 NCHW) — small, VALU direct conv.
// ---------------------------------------------------------------------------
template<int CIN, int COUT, int OCB, int H, int W>
__launch_bounds__(256)
__global__ void upconv_k(const float* __restrict__ in, const float* __restrict__ wgt,
                         const float* __restrict__ bias, float* __restrict__ out)
{
    constexpr int HWp = H * W;
    constexpr int NOCB = COUT / OCB;
    const int tx = threadIdx.x;
    const int lx = tx & 63, ly = tx >> 6;
    const int gx = blockIdx.x * 64 + lx;
    const int gy = blockIdx.y * 4 + ly;
    const int b = blockIdx.z / NOCB;
    const int ocb = blockIdx.z % NOCB;
    const int pixp = gy * W + gx;
    const float* inb = in + (size_t)b * CIN * HWp;

    int off[9]; float mul[9];
#pragma unroll
    for (int dy = 0; dy < 3; ++dy)
#pragma unroll
        for (int dx = 0; dx < 3; ++dx) {
            int p = dy * 3 + dx;
            int yy = gy + dy - 1, xx = gx + dx - 1;
            bool okp = ((unsigned)yy < (unsigned)H) && ((unsigned)xx < (unsigned)W);
            off[p] = okp ? (yy * W + xx) : 0;
            mul[p] = okp ? 1.f : 0.f;
        }
    float acc[OCB];
#pragma unroll
    for (int o = 0; o < OCB; ++o) acc[o] = 0.f;
    const float* wbase = wgt + (size_t)(ocb * OCB) * CIN * 9;
#pragma unroll
    for (int ic = 0; ic < CIN; ++ic) {
        const float* ip = inb + (size_t)ic * HWp;
        float tv[9];
#pragma unroll
        for (int p = 0; p < 9; ++p) tv[p] = __ldg(ip + off[p]) * mul[p];
#pragma unroll
        for (int o = 0; o < OCB; ++o) {
            const float* wq = wbase + (size_t)(o * CIN + ic) * 9;
#pragma unroll
            for (int p = 0; p < 9; ++p) acc[o] = fmaf(tv[p], wq[p], acc[o]);
        }
    }
#pragma unroll
    for (int o = 0; o < OCB; ++o)
        out[((size_t)b * COUT + ocb * OCB + o) * HWp + pixp] = acc[o] + __ldg(bias + ocb * OCB + o);
}

// ---------------------------------------------------------------------------
// Build data1 (prelu(pixshuf(t_up))||pan) and ms_up as NHWC bf16 pad32.
// ---------------------------------------------------------------------------
__global__ __launch_bounds__(256) void build_inputs(
    const float* __restrict__ tup, const float* __restrict__ pan,
    const float* __restrict__ aup, const float* __restrict__ msup,
    unsigned short* __restrict__ data1, unsigned short* __restrict__ msb)
{
    const int i = blockIdx.x * 256 + threadIdx.x;
    const int b = i >> 16, pixp = i & 65535;
    const int y = pixp >> 8, x = pixp & 255;
    unsigned short o[32];
#pragma unroll
    for (int c = 0; c < 32; ++c) o[c] = 0;
    unsigned short* dst;
    if (blockIdx.y == 0) {
        const float a = __ldg(aup);
#pragma unroll
        for (int c = 0; c < 4; ++c) {
            const int ch = c * 16 + (y & 3) * 4 + (x & 3);
            float v = tup[(((size_t)b * 64 + ch) << 12) + ((y >> 2) << 6) + (x >> 2)];
            v = (v >= 0.f) ? v : a * v;
            o[c] = f2bf(v);
        }
        o[4] = f2bf(pan[((size_t)b << 16) + pixp]);
        dst = data1;
    } else {
#pragma unroll
        for (int c = 0; c < 4; ++c)
            o[c] = f2bf(msup[(((size_t)b * 4 + c) << 16) + pixp]);
        dst = msb;
    }
    short8* dp = (short8*)(dst + (size_t)i * 32);
#pragma unroll
    for (int q = 0; q < 4; ++q) {
        short8 s;
#pragma unroll
        for (int r = 0; r < 8; ++r) s[r] = (short)o[q * 8 + r];
        dp[q] = s;
    }
}

// ---------------------------------------------------------------------------
extern "C" void kernel_launch(void* const* d_in, const int* in_sizes, int n_in,
                              void* d_out, int out_size, void* d_ws, size_t ws_size,
                              hipStream_t stream) {
    const float* ms_up  = (const float*)d_in[0];
    const float* ms_org = (const float*)d_in[1];
    const float* pan    = (const float*)d_in[2];
    const float* w_up4  = (const float*)d_in[3];
    const float* b_up4  = (const float*)d_in[4];
    const float* a_up4  = (const float*)d_in[5];
    const float* w_blk53= (const float*)d_in[6];
    const float* b_blk53= (const float*)d_in[7];
    const float* a_blk53= (const float*)d_in[8];
    const float* w_blk43= (const float*)d_in[9];
    const float* b_blk43= (const float*)d_in[10];
    const float* a_blk43= (const float*)d_in[11];
    const float* w1a=(const float*)d_in[12]; const float* b1a=(const float*)d_in[13];
    const float* w1b=(const float*)d_in[14]; const float* b1b=(const float*)d_in[15];
    const float* w1c=(const float*)d_in[16]; const float* b1c=(const float*)d_in[17];
    const float* aw1=(const float*)d_in[18]; const float* ab1=(const float*)d_in[19];
    const float* fw1=(const float*)d_in[20];
    const float* aw2=(const float*)d_in[21]; const float* ab2=(const float*)d_in[22];
    const float* fw2=(const float*)d_in[23];
    const float* w_blk2=(const float*)d_in[24]; const float* b_blk2=(const float*)d_in[25]; const float* a_blk2=(const float*)d_in[26];
    const float* w2a=(const float*)d_in[27]; const float* b2a=(const float*)d_in[28];
    const float* w2b=(const float*)d_in[29]; const float* b2b=(const float*)d_in[30];
    const float* w2c=(const float*)d_in[31]; const float* b2c=(const float*)d_in[32];
    const float* aw3=(const float*)d_in[33]; const float* ab3=(const float*)d_in[34];
    const float* fw3=(const float*)d_in[35];
    const float* aw4=(const float*)d_in[36]; const float* ab4=(const float*)d_in[37];
    const float* fw4=(const float*)d_in[38];
    const float* w_c6=(const float*)d_in[39]; const float* b_c6=(const float*)d_in[40];

    float* out = (float*)d_out;
    char* ws = (char*)d_ws;

    const size_t BIG = (size_t)2 * HW * 64 * 2;   // 16.78 MB (NHWC pad64 bf16)
    const size_t HALF = BIG / 2;
    unsigned short* bufA = (unsigned short*)(ws);
    unsigned short* bufB = (unsigned short*)(ws + BIG);
    unsigned short* bufC = (unsigned short*)(ws + 2 * BIG);
    unsigned short* data1 = bufC;
    float*          t_up  = (float*)(ws + 2 * BIG + HALF);
    unsigned short* msb   = bufB;
    unsigned short* bufD = bufC;
    unsigned short* bufE = bufB;
    unsigned short* bufF = bufA;
    unsigned short* wb = (unsigned short*)(ws + 3 * BIG);

    if (ws_size < 3 * BIG + 1000000) return;

    PrepArgs pa;
    int off = 0, li = 0;
    auto add = [&](const float* s, int cout, int cin, int mt, int kk, int flags) {
        pa.d[li].src = s; pa.d[li].cout = cout; pa.d[li].cin = cin;
        pa.d[li].mt = mt; pa.d[li].kk = kk; pa.d[li].flags = flags; pa.d[li].dstoff = off;
        int ret = off; off += 9 * mt * kk * 512; ++li; return ret;
    };
    const int o_blk43 = add(w_blk43, 30, 4, 2, 1, 0);
    const int o_blk53 = add(w_blk53, 30, 5, 2, 1, 0);
    const int o_w1a   = add(w1a, 20, 60, 2, 2, 1);
    const int o_w1b   = add(w1b, 20, 60, 2, 2, 1);
    const int o_w1c   = add(w1c, 20, 60, 2, 2, 1);
    const int o_aw1   = add(aw1,  9, 60, 1, 2, 0);
    const int o_fw1   = add(fw1, 60, 60, 4, 2, 0);
    const int o_aw2   = add(aw2,  9, 60, 1, 2, 0);
    const int o_fw2   = add(fw2, 60, 60, 4, 2, 2);
    const int o_blk2  = add(w_blk2, 30, 60, 2, 2, 1);
    const int o_w2a   = add(w2a, 10, 30, 1, 1, 0);
    const int o_w2b   = add(w2b, 10, 30, 1, 1, 0);
    const int o_w2c   = add(w2c, 10, 30, 1, 1, 0);
    const int o_aw3   = add(aw3,  9, 30, 1, 1, 0);
    const int o_fw3   = add(fw3, 30, 30, 2, 1, 0);
    const int o_aw4   = add(aw4,  9, 30, 1, 1, 0);
    const int o_fw4   = add(fw4, 30, 30, 2, 1, 0);
    const int o_c6    = add(w_c6,  4, 30, 1, 1, 0);

    prep_k<<<dim3(18), 256, 0, stream>>>(pa, wb);

    upconv_k<4, 64, 16, 64, 64><<<dim3(1, 16, 8), 256, 0, stream>>>(ms_org, w_up4, b_up4, t_up);
    build_inputs<<<dim3(512, 2), 256, 0, stream>>>(t_up, pan, a_up4, ms_up, data1, msb);

    const dim3 B256(256);
    const dim3 G1(1024, 1, 2);   // 64-px staged kernels
    const dim3 GH(512, 1, 2);    // RPB=2 staged / final

    // out1 (bufA, pad64, split-60): blk43 -> rows 0..29, blk53 -> rows 32..61
    sconv_k<1,1><<<G1,B256,0,stream>>>(msb,   wb+o_blk43, b_blk43, a_blk43, bufA, 64, 0);
    sconv_k<1,1><<<G1,B256,0,stream>>>(data1, wb+o_blk53, b_blk53, a_blk53, bufA, 64, 32);

    // ---- rmrs1 (60 ch) ----
    trident_s<2,20><<<G1,B256,0,stream>>>(bufA, wb+o_w1a, wb+o_w1b, wb+o_w1c, b1a, b1b, b1c, bufB);
    aflb_p<2,1,0><<<G1,B256,0,stream>>>(bufB, wb+o_aw1, ab1, wb+o_fw1, nullptr, bufC);
    aflb_p<2,1,1><<<G1,B256,0,stream>>>(bufC, wb+o_aw2, ab2, wb+o_fw2, bufA,   bufB);

    // blk2: out2 -> 30ch (bufD pad32)
    sconv_k<2,1><<<G1,B256,0,stream>>>(bufB, wb+o_blk2, b_blk2, a_blk2, bufD, 32, 0);

    // ---- rmrs2 (30 ch) ----
    trident_s<1,10><<<G1,B256,0,stream>>>(bufD, wb+o_w2a, wb+o_w2b, wb+o_w2c, b2a, b2b, b2c, bufE);
    aflb_p<1,2,0><<<GH,B256,0,stream>>>(bufE, wb+o_aw3, ab3, wb+o_fw3, nullptr, bufF);
    aflb_p<1,2,1><<<GH,B256,0,stream>>>(bufF, wb+o_aw4, ab4, wb+o_fw4, bufD,   bufE);

    // final: conv 30->4 + ms_up (f32 NCHW out)
    final_k<<<GH,B256,0,stream>>>(bufE, wb+o_c6, b_c6, ms_up, out);
}

// Round 7
// 210.549 us; speedup vs baseline: 8.1084x; 1.2312x over previous
//
#include <hip/hip_runtime.h>

typedef __attribute__((ext_vector_type(8))) short short8;
typedef __attribute__((ext_vector_type(4))) float f32x4;
typedef __attribute__((ext_vector_type(4))) int i32x4;

#define HW 65536

__device__ __forceinline__ float bf2f(unsigned short u){
    union { unsigned int i; float f; } x; x.i = ((unsigned int)u) << 16; return x.f;
}
__device__ __forceinline__ unsigned short f2bf(float f){
    union { float f; unsigned int i; } x; x.f = f;
    unsigned int r = x.i + 0x7fffu + ((x.i >> 16) & 1u);
    return (unsigned short)(r >> 16);
}
__device__ __forceinline__ unsigned int pack2(float a, float b){
    return (unsigned int)f2bf(a) | ((unsigned int)f2bf(b) << 16);
}
__device__ __forceinline__ i32x4 addrelu4(i32x4 a, i32x4 b){
    i32x4 o;
#pragma unroll
    for (int k = 0; k < 4; ++k) {
        unsigned int ua = (unsigned int)a[k], ub = (unsigned int)b[k];
        float x0 = bf2f((unsigned short)(ua & 0xffff)) + bf2f((unsigned short)(ub & 0xffff));
        float x1 = bf2f((unsigned short)(ua >> 16))    + bf2f((unsigned short)(ub >> 16));
        o[k] = (int)(((unsigned int)f2bf(fmaxf(x0, 0.f))) |
                     ((unsigned int)f2bf(fmaxf(x1, 0.f)) << 16));
    }
    return o;
}

// ---------------------------------------------------------------------------
// Staged single conv (dil=1): 3-row LDS stage (+1-granule pad), 30 out rows.
// ---------------------------------------------------------------------------
template<int KK, int PRELU>
__global__ __launch_bounds__(256, 4) void sconv_k(
    const unsigned short* __restrict__ in,
    const unsigned short* __restrict__ wfrag,
    const float* __restrict__ bias,
    const float* __restrict__ alphap,
    unsigned short* __restrict__ outb, int cpad, int coff)
{
    constexpr int CPIN = KK * 32, SGR = KK * 4, SGRP = SGR + 1, SPX = 66;
    constexpr int NSTGDW = 3 * SPX * SGRP * 4;
    constexpr int ODP = 20;
    constexpr int OUTOFF = NSTGDW;
    __shared__ __align__(16) unsigned int sm[NSTGDW + 64 * ODP];
    const int tid = threadIdx.x;
    const int lane = tid & 63, wv = tid >> 6;
    const int col = lane & 15, g = lane >> 4;
    const int bx = blockIdx.x;
    const int xcd = bx & 7, t = bx >> 3;
    const int y0 = xcd * 32 + (t & 31);
    const int x0 = ((t >> 5) & 3) * 64;
    const int b = blockIdx.z;
    const unsigned short* inb = in + (size_t)b * HW * CPIN;

#pragma unroll
    for (int rr = 0; rr < 3; ++rr) {
        const int yy = y0 + rr - 1;
        for (int u = tid; u < SPX * SGR; u += 256) {
            const int slot = u & (SGR - 1), px = u / SGR;
            const int xx = x0 - 1 + px;
            i32x4 v = {0,0,0,0};
            if ((unsigned)yy < 256u && (unsigned)xx < 256u)
                v = *(const i32x4*)(inb + (size_t)(yy * 256 + xx) * CPIN + slot * 8);
            *(i32x4*)&sm[((rr * SPX + px) * SGRP + slot) * 4] = v;
        }
    }
    if (tid < 64) sm[OUTOFF + tid * ODP + 15] = 0;
    __syncthreads();

    const short8* wp = (const short8*)wfrag;
    f32x4 acc[2];
    acc[0] = (f32x4){0.f,0.f,0.f,0.f}; acc[1] = (f32x4){0.f,0.f,0.f,0.f};
#pragma unroll
    for (int tap = 0; tap < 9; ++tap) {
        const int dy = tap / 3 - 1, dx = tap % 3 - 1;
        const int rl = dy + 1;
        short8 af[2][KK];
#pragma unroll
        for (int mt = 0; mt < 2; ++mt)
#pragma unroll
            for (int kk = 0; kk < KK; ++kk)
                af[mt][kk] = wp[((tap * 2 + mt) * KK + kk) * 64 + lane];
        const int pl = 1 + wv * 16 + col + dx;
#pragma unroll
        for (int kk = 0; kk < KK; ++kk) {
            short8 bf = *(const short8*)&sm[((rl * SPX + pl) * SGRP + kk * 4 + g) * 4];
#pragma unroll
            for (int mt = 0; mt < 2; ++mt)
                acc[mt] = __builtin_amdgcn_mfma_f32_16x16x32_bf16(af[mt][kk], bf, acc[mt], 0, 0, 0);
        }
    }
    const float al = PRELU ? __ldg(alphap) : 0.f;
    const int px = wv * 16 + col;
#pragma unroll
    for (int mt = 0; mt < 2; ++mt)
#pragma unroll
        for (int e = 0; e < 2; ++e) {
            const int rb = mt * 16 + g * 4 + e * 2;
            if (rb < 30) {
                float v0 = acc[mt][e * 2]     + __ldg(bias + rb);
                float v1 = acc[mt][e * 2 + 1] + ((rb + 1 < 30) ? __ldg(bias + rb + 1) : 0.f);
                if (PRELU) { v0 = v0 >= 0.f ? v0 : al * v0; v1 = v1 >= 0.f ? v1 : al * v1; }
                if (rb + 1 >= 30) v1 = 0.f;
                sm[OUTOFF + px * ODP + (rb >> 1)] = pack2(v0, v1);
            }
        }
    __syncthreads();
    {
        const int slot = tid & 3, opx = tid >> 2;
        i32x4 v = *(i32x4*)&sm[OUTOFF + opx * ODP + slot * 4];
        const size_t go = ((size_t)b * HW + (size_t)y0 * 256 + x0 + opx) * cpad + coff + slot * 8;
        *(i32x4*)(outb + go) = v;
    }
}

// ---------------------------------------------------------------------------
// Staged trident: 3 dilated convs (d=1,2,3), rotating 3-row LDS stage.
// ---------------------------------------------------------------------------
template<int KK, int MR>
__global__ __launch_bounds__(256, 4) void trident_s(
    const unsigned short* __restrict__ in,
    const unsigned short* __restrict__ wf0, const unsigned short* __restrict__ wf1,
    const unsigned short* __restrict__ wf2,
    const float* __restrict__ b0, const float* __restrict__ b1, const float* __restrict__ b2,
    unsigned short* __restrict__ outb)
{
    constexpr int CPIN = KK * 32, CPAD = KK * 32;
    constexpr int SGR = KK * 4, SGRP = SGR + 1, SPX = 70;
    constexpr int MT_ = (KK == 2) ? 2 : 1;
    constexpr int CPP = KK * 4, ODP = (CPP + 1) * 4;
    constexpr int NSTGDW = 3 * SPX * SGRP * 4;
    constexpr int OUTOFF = NSTGDW;
    __shared__ __align__(16) unsigned int sm[NSTGDW + 64 * ODP];
    const int tid = threadIdx.x;
    const int lane = tid & 63, wv = tid >> 6;
    const int col = lane & 15, g = lane >> 4;
    const int bx = blockIdx.x;
    const int xcd = bx & 7, t = bx >> 3;
    const int y0 = xcd * 32 + (t & 31);
    const int x0 = ((t >> 5) & 3) * 64;
    const int b = blockIdx.z;
    const unsigned short* inb = in + (size_t)b * HW * CPIN;

    auto stage_row = [&](int srow, int yy) {
        for (int u = tid; u < SPX * SGR; u += 256) {
            const int slot = u & (SGR - 1), px = u / SGR;
            const int xx = x0 - 3 + px;
            i32x4 v = {0,0,0,0};
            if ((unsigned)yy < 256u && (unsigned)xx < 256u)
                v = *(const i32x4*)(inb + (size_t)(yy * 256 + xx) * CPIN + slot * 8);
            *(i32x4*)&sm[((srow * SPX + px) * SGRP + slot) * 4] = v;
        }
    };

    const unsigned short* wfs[3] = {wf0, wf1, wf2};
    const float* bss[3] = {b0, b1, b2};

    stage_row(0, y0); stage_row(1, y0 - 1); stage_row(2, y0 + 1);
    if (tid < 64) {
#pragma unroll
        for (int dwp = 3 * MR / 2; dwp < CPP * 4; ++dwp) sm[OUTOFF + tid * ODP + dwp] = 0;
    }
    __syncthreads();

#pragma unroll
    for (int which = 0; which < 3; ++which) {
        const int d = which + 1;
        const short8* wp = (const short8*)wfs[which];
        const float* bs = bss[which];
        f32x4 acc[MT_];
#pragma unroll
        for (int mt = 0; mt < MT_; ++mt) acc[mt] = (f32x4){0.f,0.f,0.f,0.f};
#pragma unroll
        for (int tap = 0; tap < 9; ++tap) {
            const int dy = tap / 3 - 1, dx = tap % 3 - 1;
            const int rl = (dy == 0) ? 0 : (dy < 0 ? 1 : 2);
            short8 af[MT_][KK];
#pragma unroll
            for (int mt = 0; mt < MT_; ++mt)
#pragma unroll
                for (int kk = 0; kk < KK; ++kk)
                    af[mt][kk] = wp[((tap * MT_ + mt) * KK + kk) * 64 + lane];
            const int pl = 3 + wv * 16 + col + dx * d;
#pragma unroll
            for (int kk = 0; kk < KK; ++kk) {
                short8 bf = *(const short8*)&sm[((rl * SPX + pl) * SGRP + kk * 4 + g) * 4];
#pragma unroll
                for (int mt = 0; mt < MT_; ++mt)
                    acc[mt] = __builtin_amdgcn_mfma_f32_16x16x32_bf16(af[mt][kk], bf, acc[mt], 0, 0, 0);
            }
        }
        const int px = wv * 16 + col;
#pragma unroll
        for (int mt = 0; mt < MT_; ++mt)
#pragma unroll
            for (int e = 0; e < 2; ++e) {
                const int rb = mt * 16 + g * 4 + e * 2;
                if (rb < MR) {
                    float v0 = acc[mt][e * 2]     + __ldg(bs + rb);
                    float v1 = acc[mt][e * 2 + 1] + ((rb + 1 < MR) ? __ldg(bs + rb + 1) : 0.f);
                    if (rb + 1 >= MR) v1 = 0.f;
                    sm[OUTOFF + px * ODP + ((which * MR + rb) >> 1)] = pack2(v0, v1);
                }
            }
        __syncthreads();
        if (which < 2) {
            stage_row(1, y0 - (d + 1)); stage_row(2, y0 + (d + 1));
            __syncthreads();
        }
    }

    for (int u = tid; u < 64 * CPP; u += 256) {
        const int slot = u & (CPP - 1), opx = u / CPP;
        i32x4 v = *(i32x4*)&sm[OUTOFF + opx * ODP + slot * 4];
        const size_t go = ((size_t)b * HW + (size_t)y0 * 256 + x0 + opx) * CPAD + slot * 8;
        *(i32x4*)(outb + go) = v;
    }
}

// ---------------------------------------------------------------------------
// Staged fused AFLB (+1-granule-pad LDS).
// ---------------------------------------------------------------------------
template<int KK, int RPB, int RES>
__global__ __launch_bounds__(256, 4) void aflb_p(
    const unsigned short* __restrict__ in,
    const unsigned short* __restrict__ awf, const float* __restrict__ ab,
    const unsigned short* __restrict__ fwf,
    const unsigned short* __restrict__ res,
    unsigned short* __restrict__ outb)
{
    constexpr int CPIN = KK * 32, MTT = 2 * KK, CPAD = 16 * MTT;
    constexpr int SROWS = RPB + 2, SPX = 66, SGR = KK * 4, SGRP = SGR + 1;
    constexpr int CPP = CPAD / 8, ODP = (CPP + 1) * 4;
    constexpr int NSTGDW = SROWS * SPX * SGRP * 4;
    constexpr int ATOFF = NSTGDW;
    constexpr int NATT = RPB * 64 * 9;
    constexpr int OUTOFF = ATOFF + NATT;
    __shared__ __align__(16) unsigned int sm[OUTOFF + RPB * 64 * ODP];

    const int tid = threadIdx.x;
    const int lane = tid & 63, wv = tid >> 6;
    const int col = lane & 15, g = lane >> 4;
    const int bx = blockIdx.x;
    const int xcd = bx & 7, t = bx >> 3;
    const int y0 = (RPB == 1) ? (xcd * 32 + (t & 31)) : (xcd * 32 + (t & 15) * 2);
    const int xseg = (RPB == 1) ? ((t >> 5) & 3) : ((t >> 4) & 3);
    const int x0 = xseg * 64;
    const int b = blockIdx.z;
    const unsigned short* inb = in + (size_t)b * HW * CPIN;

    for (int u = tid; u < SROWS * SPX * SGR; u += 256) {
        const int slot = u & (SGR - 1);
        const int px = (u / SGR) % SPX;
        const int row = u / (SGR * SPX);
        const int yy = y0 + row - 1, xx = x0 - 1 + px;
        i32x4 v = {0,0,0,0};
        if ((unsigned)yy < 256u && (unsigned)xx < 256u)
            v = *(const i32x4*)(inb + (size_t)(yy * 256 + xx) * CPIN + slot * 8);
        *(i32x4*)&sm[((row * SPX + px) * SGRP + slot) * 4] = v;
    }
    __syncthreads();

    const short8* awp = (const short8*)awf;
    const short8* fwp = (const short8*)fwf;

    constexpr int NF1 = (RPB == 1) ? 1 : 2;
    const int arow = (RPB == 1) ? 0 : (wv >> 1);
    const int apx0 = (RPB == 1) ? (wv * 16) : ((wv & 1) * 32);
    f32x4 aacc[NF1];
#pragma unroll
    for (int nf = 0; nf < NF1; ++nf) aacc[nf] = (f32x4){0.f,0.f,0.f,0.f};
#pragma unroll
    for (int tap = 0; tap < 9; ++tap) {
        const int dy = tap / 3 - 1, dx = tap % 3 - 1;
        const int rl = arow + dy + 1;
        short8 afa[KK];
#pragma unroll
        for (int kk = 0; kk < KK; ++kk)
            afa[kk] = awp[(tap * KK + kk) * 64 + lane];
#pragma unroll
        for (int nf = 0; nf < NF1; ++nf) {
            const int pl = 1 + apx0 + nf * 16 + col + dx;
#pragma unroll
            for (int kk = 0; kk < KK; ++kk) {
                short8 bf = *(const short8*)&sm[((rl * SPX + pl) * SGRP + kk * 4 + g) * 4];
                aacc[nf] = __builtin_amdgcn_mfma_f32_16x16x32_bf16(afa[kk], bf, aacc[nf], 0, 0, 0);
            }
        }
    }
#pragma unroll
    for (int nf = 0; nf < NF1; ++nf) {
        float v[4];
        float m = -1e30f;
#pragma unroll
        for (int r = 0; r < 4; ++r) {
            const int row = g * 4 + r;
            v[r] = (row < 9) ? (aacc[nf][r] + __ldg(ab + row)) : -1e30f;
            m = fmaxf(m, v[r]);
        }
        m = fmaxf(m, __shfl_xor(m, 16));
        m = fmaxf(m, __shfl_xor(m, 32));
        float e[4]; float s = 0.f;
#pragma unroll
        for (int r = 0; r < 4; ++r) { e[r] = (g * 4 + r < 9) ? __expf(v[r] - m) : 0.f; s += e[r]; }
        s += __shfl_xor(s, 16);
        s += __shfl_xor(s, 32);
        const float inv = 1.f / s;
        const int px = apx0 + nf * 16 + col;
#pragma unroll
        for (int r = 0; r < 4; ++r) {
            const int row = g * 4 + r;
            if (row < 9) sm[ATOFF + (arow * 64 + px) * 9 + row] = __float_as_uint(e[r] * inv);
        }
    }
    __syncthreads();

    const int prow = (RPB == 1) ? 0 : (wv >> 1);
    const int mt = (RPB == 1) ? wv : (wv & 1);
    f32x4 acc[4];
#pragma unroll
    for (int nf = 0; nf < 4; ++nf) acc[nf] = (f32x4){0.f,0.f,0.f,0.f};
#pragma unroll
    for (int tap = 0; tap < 9; ++tap) {
        const int dy = tap / 3 - 1, dx = tap % 3 - 1;
        const int rl = prow + dy + 1;
        float av[4];
#pragma unroll
        for (int nf = 0; nf < 4; ++nf)
            av[nf] = __uint_as_float(sm[ATOFF + (prow * 64 + nf * 16 + col) * 9 + tap]);
        short8 af[KK];
#pragma unroll
        for (int kk = 0; kk < KK; ++kk)
            af[kk] = fwp[((tap * MTT + mt) * KK + kk) * 64 + lane];
#pragma unroll
        for (int nf = 0; nf < 4; ++nf) {
            const int pl = 1 + nf * 16 + col + dx;
            f32x4 p = (f32x4){0.f,0.f,0.f,0.f};
#pragma unroll
            for (int kk = 0; kk < KK; ++kk) {
                short8 bf = *(const short8*)&sm[((rl * SPX + pl) * SGRP + kk * 4 + g) * 4];
                p = __builtin_amdgcn_mfma_f32_16x16x32_bf16(af[kk], bf, p, 0, 0, 0);
            }
#pragma unroll
            for (int r = 0; r < 4; ++r)
                acc[nf][r] = fmaf(av[nf], p[r], acc[nf][r]);
        }
    }
    __syncthreads();

#pragma unroll
    for (int nf = 0; nf < 4; ++nf) {
        const int px = nf * 16 + col;
        const int base = OUTOFF + ((RPB == 2 ? prow * 64 : 0) + px) * ODP;
        const int rp = mt * 8 + g * 2;
        unsigned long long w =
            (unsigned long long)pack2(acc[nf][0], acc[nf][1]) |
            ((unsigned long long)pack2(acc[nf][2], acc[nf][3]) << 32);
        *(unsigned long long*)&sm[base + rp] = w;
    }
    __syncthreads();

    constexpr int NOUT = RPB * 64 * CPP;
    for (int u = tid; u < NOUT; u += 256) {
        const int slot = u & (CPP - 1);
        const int px = (u / CPP) & 63;
        const int r = (RPB == 2) ? (u / (CPP * 64)) : 0;
        i32x4 v = *(i32x4*)&sm[OUTOFF + ((r * 64 + px) * ODP) + slot * 4];
        const size_t go = ((size_t)b * HW + (size_t)(y0 + r) * 256 + x0 + px) * CPAD + slot * 8;
        if (RES) v = addrelu4(v, *(const i32x4*)(res + go));
        *(i32x4*)(outb + go) = v;
    }
}

// ---------------------------------------------------------------------------
// Final conv 30->4 + ms_up, f32 NCHW output.
// ---------------------------------------------------------------------------
__global__ __launch_bounds__(256, 4) void final_k(
    const unsigned short* __restrict__ in,
    const unsigned short* __restrict__ wfrag,
    const float* __restrict__ bias,
    const float* __restrict__ msup, float* __restrict__ outf)
{
    constexpr int CPIN = 32, NF = 2;
    const int lane = threadIdx.x & 63, wv = threadIdx.x >> 6;
    const int col = lane & 15, g = lane >> 4;
    const int bx = blockIdx.x;
    const int xcd = bx & 7, t = bx >> 3;
    const int y = xcd * 32 + (t & 31);
    const int xh = t >> 5;
    const int b = blockIdx.z;
    const int x0 = xh * 128 + wv * 32;

    const unsigned short* inb = in + (size_t)b * HW * CPIN;
    const short8 kz = {0,0,0,0,0,0,0,0};
    const short8* wp = (const short8*)wfrag;

    f32x4 acc[NF];
#pragma unroll
    for (int nf = 0; nf < NF; ++nf) acc[nf] = (f32x4){0.f,0.f,0.f,0.f};
#pragma unroll
    for (int tap = 0; tap < 9; ++tap) {
        const int dy = tap / 3 - 1, dx = tap % 3 - 1;
        const int yy = y + dy;
        const bool yok = (unsigned)yy < 256u;
        const short8 af = wp[tap * 64 + lane];
#pragma unroll
        for (int nf = 0; nf < NF; ++nf) {
            const int xx = x0 + nf * 16 + col + dx;
            const bool ok = yok && ((unsigned)xx < 256u);
            const int pix = ok ? (yy * 256 + xx) : 0;
            short8 bf = *(const short8*)(inb + (size_t)pix * CPIN + g * 8);
            if (!ok) bf = kz;
            acc[nf] = __builtin_amdgcn_mfma_f32_16x16x32_bf16(af, bf, acc[nf], 0, 0, 0);
        }
    }
#pragma unroll
    for (int nf = 0; nf < NF; ++nf) {
        const int pix = y * 256 + x0 + nf * 16 + col;
        if (g == 0) {
#pragma unroll
            for (int r = 0; r < 4; ++r) {
                const size_t oi = ((size_t)b * 4 + r) * HW + pix;
                outf[oi] = acc[nf][r] + __ldg(bias + r) + msup[oi];
            }
        }
    }
}

// ---------------------------------------------------------------------------
// Weight prep (PARALLEL): one element per thread, grid (chunks, desc).
// kksh/mtsh are log2 of kk/mt (powers of two) -> no runtime divides.
// ---------------------------------------------------------------------------
struct PrepDesc { const float* src; int cout, cin, kksh, mtsh, flags, dstoff, n; };
struct PrepArgs { PrepDesc d[18]; };

__global__ __launch_bounds__(256) void prep_k(PrepArgs pa, unsigned short* __restrict__ wb)
{
    const PrepDesc d = pa.d[blockIdx.y];
    const int e = blockIdx.x * 256 + threadIdx.x;
    if (e >= d.n) return;
    const int j = e & 7;
    const int lane = (e >> 3) & 63;
    const int i512 = e >> 9;
    const int kk = i512 & ((1 << d.kksh) - 1);
    const int mt = (i512 >> d.kksh) & ((1 << d.mtsh) - 1);
    const int tap = i512 >> (d.kksh + d.mtsh);
    const int rpos = mt * 16 + (lane & 15);
    const int kpos = kk * 32 + (lane >> 4) * 8 + j;
    int o = rpos, ic = kpos;
    bool ok = true;
    if (d.flags & 2) {
        if (rpos < 30) o = rpos;
        else if (rpos >= 32 && rpos < 62) o = rpos - 2;
        else ok = false;
    }
    if (d.flags & 1) {
        if (kpos < 30) ic = kpos;
        else if (kpos >= 32 && kpos < 62) ic = kpos - 2;
        else ok = false;
    }
    float v = 0.f;
    if (ok && o < d.cout && ic < d.cin) v = d.src[(o * d.cin + ic) * 9 + tap];
    wb[d.dstoff + e] = f2bf(v);
}

// ---------------------------------------------------------------------------
// up-conv (ms_org 4->64 @64x64, f32 NCHW) — small, VALU direct conv.
// ---------------------------------------------------------------------------
template<int CIN, int COUT, int OCB, int H, int W>
__launch_bounds__(256)
__global__ void upconv_k(const float* __restrict__ in, const float* __restrict__ wgt,
                         const float* __restrict__ bias, float* __restrict__ out)
{
    constexpr int HWp = H * W;
    constexpr int NOCB = COUT / OCB;
    const int tx = threadIdx.x;
    const int lx = tx & 63, ly = tx >> 6;
    const int gx = blockIdx.x * 64 + lx;
    const int gy = blockIdx.y * 4 + ly;
    const int b = blockIdx.z / NOCB;
    const int ocb = blockIdx.z % NOCB;
    const int pixp = gy * W + gx;
    const float* inb = in + (size_t)b * CIN * HWp;

    int off[9]; float mul[9];
#pragma unroll
    for (int dy = 0; dy < 3; ++dy)
#pragma unroll
        for (int dx = 0; dx < 3; ++dx) {
            int p = dy * 3 + dx;
            int yy = gy + dy - 1, xx = gx + dx - 1;
            bool okp = ((unsigned)yy < (unsigned)H) && ((unsigned)xx < (unsigned)W);
            off[p] = okp ? (yy * W + xx) : 0;
            mul[p] = okp ? 1.f : 0.f;
        }
    float acc[OCB];
#pragma unroll
    for (int o = 0; o < OCB; ++o) acc[o] = 0.f;
    const float* wbase = wgt + (size_t)(ocb * OCB) * CIN * 9;
#pragma unroll
    for (int ic = 0; ic < CIN; ++ic) {
        const float* ip = inb + (size_t)ic * HWp;
        float tv[9];
#pragma unroll
        for (int p = 0; p < 9; ++p) tv[p] = __ldg(ip + off[p]) * mul[p];
#pragma unroll
        for (int o = 0; o < OCB; ++o) {
            const float* wq = wbase + (size_t)(o * CIN + ic) * 9;
#pragma unroll
            for (int p = 0; p < 9; ++p) acc[o] = fmaf(tv[p], wq[p], acc[o]);
        }
    }
#pragma unroll
    for (int o = 0; o < OCB; ++o)
        out[((size_t)b * COUT + ocb * OCB + o) * HWp + pixp] = acc[o] + __ldg(bias + ocb * OCB + o);
}

// ---------------------------------------------------------------------------
// Build data1 (prelu(pixshuf(t_up))||pan) and ms_up as NHWC bf16 pad32.
// ---------------------------------------------------------------------------
__global__ __launch_bounds__(256) void build_inputs(
    const float* __restrict__ tup, const float* __restrict__ pan,
    const float* __restrict__ aup, const float* __restrict__ msup,
    unsigned short* __restrict__ data1, unsigned short* __restrict__ msb)
{
    const int i = blockIdx.x * 256 + threadIdx.x;
    const int b = i >> 16, pixp = i & 65535;
    const int y = pixp >> 8, x = pixp & 255;
    unsigned short o[32];
#pragma unroll
    for (int c = 0; c < 32; ++c) o[c] = 0;
    unsigned short* dst;
    if (blockIdx.y == 0) {
        const float a = __ldg(aup);
#pragma unroll
        for (int c = 0; c < 4; ++c) {
            const int ch = c * 16 + (y & 3) * 4 + (x & 3);
            float v = tup[(((size_t)b * 64 + ch) << 12) + ((y >> 2) << 6) + (x >> 2)];
            v = (v >= 0.f) ? v : a * v;
            o[c] = f2bf(v);
        }
        o[4] = f2bf(pan[((size_t)b << 16) + pixp]);
        dst = data1;
    } else {
#pragma unroll
        for (int c = 0; c < 4; ++c)
            o[c] = f2bf(msup[(((size_t)b * 4 + c) << 16) + pixp]);
        dst = msb;
    }
    short8* dp = (short8*)(dst + (size_t)i * 32);
#pragma unroll
    for (int q = 0; q < 4; ++q) {
        short8 s;
#pragma unroll
        for (int r = 0; r < 8; ++r) s[r] = (short)o[q * 8 + r];
        dp[q] = s;
    }
}

// ---------------------------------------------------------------------------
extern "C" void kernel_launch(void* const* d_in, const int* in_sizes, int n_in,
                              void* d_out, int out_size, void* d_ws, size_t ws_size,
                              hipStream_t stream) {
    const float* ms_up  = (const float*)d_in[0];
    const float* ms_org = (const float*)d_in[1];
    const float* pan    = (const float*)d_in[2];
    const float* w_up4  = (const float*)d_in[3];
    const float* b_up4  = (const float*)d_in[4];
    const float* a_up4  = (const float*)d_in[5];
    const float* w_blk53= (const float*)d_in[6];
    const float* b_blk53= (const float*)d_in[7];
    const float* a_blk53= (const float*)d_in[8];
    const float* w_blk43= (const float*)d_in[9];
    const float* b_blk43= (const float*)d_in[10];
    const float* a_blk43= (const float*)d_in[11];
    const float* w1a=(const float*)d_in[12]; const float* b1a=(const float*)d_in[13];
    const float* w1b=(const float*)d_in[14]; const float* b1b=(const float*)d_in[15];
    const float* w1c=(const float*)d_in[16]; const float* b1c=(const float*)d_in[17];
    const float* aw1=(const float*)d_in[18]; const float* ab1=(const float*)d_in[19];
    const float* fw1=(const float*)d_in[20];
    const float* aw2=(const float*)d_in[21]; const float* ab2=(const float*)d_in[22];
    const float* fw2=(const float*)d_in[23];
    const float* w_blk2=(const float*)d_in[24]; const float* b_blk2=(const float*)d_in[25]; const float* a_blk2=(const float*)d_in[26];
    const float* w2a=(const float*)d_in[27]; const float* b2a=(const float*)d_in[28];
    const float* w2b=(const float*)d_in[29]; const float* b2b=(const float*)d_in[30];
    const float* w2c=(const float*)d_in[31]; const float* b2c=(const float*)d_in[32];
    const float* aw3=(const float*)d_in[33]; const float* ab3=(const float*)d_in[34];
    const float* fw3=(const float*)d_in[35];
    const float* aw4=(const float*)d_in[36]; const float* ab4=(const float*)d_in[37];
    const float* fw4=(const float*)d_in[38];
    const float* w_c6=(const float*)d_in[39]; const float* b_c6=(const float*)d_in[40];

    float* out = (float*)d_out;
    char* ws = (char*)d_ws;

    const size_t BIG = (size_t)2 * HW * 64 * 2;   // 16.78 MB (NHWC pad64 bf16)
    const size_t HALF = BIG / 2;
    unsigned short* bufA = (unsigned short*)(ws);
    unsigned short* bufB = (unsigned short*)(ws + BIG);
    unsigned short* bufC = (unsigned short*)(ws + 2 * BIG);
    unsigned short* data1 = bufC;
    float*          t_up  = (float*)(ws + 2 * BIG + HALF);
    unsigned short* msb   = bufB;
    unsigned short* bufD = bufC;
    unsigned short* bufE = bufB;
    unsigned short* bufF = bufA;
    unsigned short* wb = (unsigned short*)(ws + 3 * BIG);

    if (ws_size < 3 * BIG + 1000000) return;

    PrepArgs pa;
    int off = 0, li = 0;
    auto add = [&](const float* s, int cout, int cin, int mtsh, int kksh, int flags) {
        const int n = 9 << (mtsh + kksh + 9);
        pa.d[li].src = s; pa.d[li].cout = cout; pa.d[li].cin = cin;
        pa.d[li].kksh = kksh; pa.d[li].mtsh = mtsh; pa.d[li].flags = flags;
        pa.d[li].dstoff = off; pa.d[li].n = n;
        int ret = off; off += n; ++li; return ret;
    };
    // (mtsh, kksh) = log2(mt), log2(kk)
    const int o_blk43 = add(w_blk43, 30, 4, 1, 0, 0);
    const int o_blk53 = add(w_blk53, 30, 5, 1, 0, 0);
    const int o_w1a   = add(w1a, 20, 60, 1, 1, 1);
    const int o_w1b   = add(w1b, 20, 60, 1, 1, 1);
    const int o_w1c   = add(w1c, 20, 60, 1, 1, 1);
    const int o_aw1   = add(aw1,  9, 60, 0, 1, 0);
    const int o_fw1   = add(fw1, 60, 60, 2, 1, 0);
    const int o_aw2   = add(aw2,  9, 60, 0, 1, 0);
    const int o_fw2   = add(fw2, 60, 60, 2, 1, 2);
    const int o_blk2  = add(w_blk2, 30, 60, 1, 1, 1);
    const int o_w2a   = add(w2a, 10, 30, 0, 0, 0);
    const int o_w2b   = add(w2b, 10, 30, 0, 0, 0);
    const int o_w2c   = add(w2c, 10, 30, 0, 0, 0);
    const int o_aw3   = add(aw3,  9, 30, 0, 0, 0);
    const int o_fw3   = add(fw3, 30, 30, 1, 0, 0);
    const int o_aw4   = add(aw4,  9, 30, 0, 0, 0);
    const int o_fw4   = add(fw4, 30, 30, 1, 0, 0);
    const int o_c6    = add(w_c6,  4, 30, 0, 0, 0);

    // max n = 9*8*512 = 36864 -> 144 chunks of 256
    prep_k<<<dim3(144, 18), 256, 0, stream>>>(pa, wb);

    upconv_k<4, 64, 16, 64, 64><<<dim3(1, 16, 8), 256, 0, stream>>>(ms_org, w_up4, b_up4, t_up);
    build_inputs<<<dim3(512, 2), 256, 0, stream>>>(t_up, pan, a_up4, ms_up, data1, msb);

    const dim3 B256(256);
    const dim3 G1(1024, 1, 2);   // 64-px staged kernels
    const dim3 GH(512, 1, 2);    // RPB=2 staged / final

    // out1 (bufA, pad64, split-60): blk43 -> rows 0..29, blk53 -> rows 32..61
    sconv_k<1,1><<<G1,B256,0,stream>>>(msb,   wb+o_blk43, b_blk43, a_blk43, bufA, 64, 0);
    sconv_k<1,1><<<G1,B256,0,stream>>>(data1, wb+o_blk53, b_blk53, a_blk53, bufA, 64, 32);

    // ---- rmrs1 (60 ch) ----
    trident_s<2,20><<<G1,B256,0,stream>>>(bufA, wb+o_w1a, wb+o_w1b, wb+o_w1c, b1a, b1b, b1c, bufB);
    aflb_p<2,1,0><<<G1,B256,0,stream>>>(bufB, wb+o_aw1, ab1, wb+o_fw1, nullptr, bufC);
    aflb_p<2,1,1><<<G1,B256,0,stream>>>(bufC, wb+o_aw2, ab2, wb+o_fw2, bufA,   bufB);

    // blk2: out2 -> 30ch (bufD pad32)
    sconv_k<2,1><<<G1,B256,0,stream>>>(bufB, wb+o_blk2, b_blk2, a_blk2, bufD, 32, 0);

    // ---- rmrs2 (30 ch) ----
    trident_s<1,10><<<G1,B256,0,stream>>>(bufD, wb+o_w2a, wb+o_w2b, wb+o_w2c, b2a, b2b, b2c, bufE);
    aflb_p<1,2,0><<<GH,B256,0,stream>>>(bufE, wb+o_aw3, ab3, wb+o_fw3, nullptr, bufF);
    aflb_p<1,2,1><<<GH,B256,0,stream>>>(bufF, wb+o_aw4, ab4, wb+o_fw4, bufD,   bufE);

    // final: conv 30->4 + ms_up (f32 NCHW out)
    final_k<<<GH,B256,0,stream>>>(bufE, wb+o_c6, b_c6, ms_up, out);
}

// Round 8
// 206.457 us; speedup vs baseline: 8.2691x; 1.0198x over previous
//
#include <hip/hip_runtime.h>

typedef __attribute__((ext_vector_type(8))) short short8;
typedef __attribute__((ext_vector_type(4))) float f32x4;
typedef __attribute__((ext_vector_type(4))) int i32x4;

#define HW 65536

__device__ __forceinline__ float bf2f(unsigned short u){
    union { unsigned int i; float f; } x; x.i = ((unsigned int)u) << 16; return x.f;
}
__device__ __forceinline__ unsigned short f2bf(float f){
    union { float f; unsigned int i; } x; x.f = f;
    unsigned int r = x.i + 0x7fffu + ((x.i >> 16) & 1u);
    return (unsigned short)(r >> 16);
}
__device__ __forceinline__ unsigned int pack2(float a, float b){
    return (unsigned int)f2bf(a) | ((unsigned int)f2bf(b) << 16);
}
__device__ __forceinline__ i32x4 addrelu4(i32x4 a, i32x4 b){
    i32x4 o;
#pragma unroll
    for (int k = 0; k < 4; ++k) {
        unsigned int ua = (unsigned int)a[k], ub = (unsigned int)b[k];
        float x0 = bf2f((unsigned short)(ua & 0xffff)) + bf2f((unsigned short)(ub & 0xffff));
        float x1 = bf2f((unsigned short)(ua >> 16))    + bf2f((unsigned short)(ub >> 16));
        o[k] = (int)(((unsigned int)f2bf(fmaxf(x0, 0.f))) |
                     ((unsigned int)f2bf(fmaxf(x1, 0.f)) << 16));
    }
    return o;
}

// ---------------------------------------------------------------------------
// Staged single conv (dil=1): 3-row LDS stage (+1-granule pad), 30 out rows.
// ---------------------------------------------------------------------------
template<int KK, int PRELU>
__global__ __launch_bounds__(256, 4) void sconv_k(
    const unsigned short* __restrict__ in,
    const unsigned short* __restrict__ wfrag,
    const float* __restrict__ bias,
    const float* __restrict__ alphap,
    unsigned short* __restrict__ outb, int cpad, int coff)
{
    constexpr int CPIN = KK * 32, SGR = KK * 4, SGRP = SGR + 1, SPX = 66;
    constexpr int NSTGDW = 3 * SPX * SGRP * 4;
    constexpr int ODP = 20;
    constexpr int OUTOFF = NSTGDW;
    __shared__ __align__(16) unsigned int sm[NSTGDW + 64 * ODP];
    const int tid = threadIdx.x;
    const int lane = tid & 63, wv = tid >> 6;
    const int col = lane & 15, g = lane >> 4;
    const int bx = blockIdx.x;
    const int xcd = bx & 7, t = bx >> 3;
    const int y0 = xcd * 32 + (t & 31);
    const int x0 = ((t >> 5) & 3) * 64;
    const int b = blockIdx.z;
    const unsigned short* inb = in + (size_t)b * HW * CPIN;

#pragma unroll
    for (int rr = 0; rr < 3; ++rr) {
        const int yy = y0 + rr - 1;
        for (int u = tid; u < SPX * SGR; u += 256) {
            const int slot = u & (SGR - 1), px = u / SGR;
            const int xx = x0 - 1 + px;
            i32x4 v = {0,0,0,0};
            if ((unsigned)yy < 256u && (unsigned)xx < 256u)
                v = *(const i32x4*)(inb + (size_t)(yy * 256 + xx) * CPIN + slot * 8);
            *(i32x4*)&sm[((rr * SPX + px) * SGRP + slot) * 4] = v;
        }
    }
    if (tid < 64) sm[OUTOFF + tid * ODP + 15] = 0;
    __syncthreads();

    const short8* wp = (const short8*)wfrag;
    f32x4 acc[2];
    acc[0] = (f32x4){0.f,0.f,0.f,0.f}; acc[1] = (f32x4){0.f,0.f,0.f,0.f};
#pragma unroll
    for (int tap = 0; tap < 9; ++tap) {
        const int dy = tap / 3 - 1, dx = tap % 3 - 1;
        const int rl = dy + 1;
        short8 af[2][KK];
#pragma unroll
        for (int mt = 0; mt < 2; ++mt)
#pragma unroll
            for (int kk = 0; kk < KK; ++kk)
                af[mt][kk] = wp[((tap * 2 + mt) * KK + kk) * 64 + lane];
        const int pl = 1 + wv * 16 + col + dx;
#pragma unroll
        for (int kk = 0; kk < KK; ++kk) {
            short8 bf = *(const short8*)&sm[((rl * SPX + pl) * SGRP + kk * 4 + g) * 4];
#pragma unroll
            for (int mt = 0; mt < 2; ++mt)
                acc[mt] = __builtin_amdgcn_mfma_f32_16x16x32_bf16(af[mt][kk], bf, acc[mt], 0, 0, 0);
        }
    }
    const float al = PRELU ? __ldg(alphap) : 0.f;
    const int px = wv * 16 + col;
#pragma unroll
    for (int mt = 0; mt < 2; ++mt)
#pragma unroll
        for (int e = 0; e < 2; ++e) {
            const int rb = mt * 16 + g * 4 + e * 2;
            if (rb < 30) {
                float v0 = acc[mt][e * 2]     + __ldg(bias + rb);
                float v1 = acc[mt][e * 2 + 1] + ((rb + 1 < 30) ? __ldg(bias + rb + 1) : 0.f);
                if (PRELU) { v0 = v0 >= 0.f ? v0 : al * v0; v1 = v1 >= 0.f ? v1 : al * v1; }
                if (rb + 1 >= 30) v1 = 0.f;
                sm[OUTOFF + px * ODP + (rb >> 1)] = pack2(v0, v1);
            }
        }
    __syncthreads();
    {
        const int slot = tid & 3, opx = tid >> 2;
        i32x4 v = *(i32x4*)&sm[OUTOFF + opx * ODP + slot * 4];
        const size_t go = ((size_t)b * HW + (size_t)y0 * 256 + x0 + opx) * cpad + coff + slot * 8;
        *(i32x4*)(outb + go) = v;
    }
}

// ---------------------------------------------------------------------------
// Staged trident with T14 async-STAGE split: loads for the next dilation's
// halo rows are ISSUED before the current dilation's MFMA phase and WRITTEN
// to LDS after its barrier — HBM/L2 latency hides under compute.
// Rows: slot0 = y (all dils), slots 1/2 = y-d / y+d (restaged per dilation).
// ---------------------------------------------------------------------------
template<int KK, int MR>
__global__ __launch_bounds__(256, 4) void trident_s(
    const unsigned short* __restrict__ in,
    const unsigned short* __restrict__ wf0, const unsigned short* __restrict__ wf1,
    const unsigned short* __restrict__ wf2,
    const float* __restrict__ b0, const float* __restrict__ b1, const float* __restrict__ b2,
    unsigned short* __restrict__ outb)
{
    constexpr int CPIN = KK * 32, CPAD = KK * 32;
    constexpr int SGR = KK * 4, SGRP = SGR + 1, SPX = 70;
    constexpr int MT_ = (KK == 2) ? 2 : 1;
    constexpr int CPP = KK * 4, ODP = (CPP + 1) * 4;
    constexpr int NSTGDW = 3 * SPX * SGRP * 4;
    constexpr int OUTOFF = NSTGDW;
    constexpr int NG1 = SPX * SGR;                 // 16B granules per row
    constexpr int NIT2 = (2 * NG1 + 255) / 256;    // iters for a 2-row batch
    __shared__ __align__(16) unsigned int sm[NSTGDW + 64 * ODP];
    const int tid = threadIdx.x;
    const int lane = tid & 63, wv = tid >> 6;
    const int col = lane & 15, g = lane >> 4;
    const int bx = blockIdx.x;
    const int xcd = bx & 7, t = bx >> 3;
    const int y0 = xcd * 32 + (t & 31);
    const int x0 = ((t >> 5) & 3) * 64;
    const int b = blockIdx.z;
    const unsigned short* inb = in + (size_t)b * HW * CPIN;

    // direct stage of the 3 first-needed rows (y, y-1, y+1)
    auto stage_row = [&](int srow, int yy) {
        for (int u = tid; u < NG1; u += 256) {
            const int slot = u & (SGR - 1), px = u / SGR;
            const int xx = x0 - 3 + px;
            i32x4 v = {0,0,0,0};
            if ((unsigned)yy < 256u && (unsigned)xx < 256u)
                v = *(const i32x4*)(inb + (size_t)(yy * 256 + xx) * CPIN + slot * 8);
            *(i32x4*)&sm[((srow * SPX + px) * SGRP + slot) * 4] = v;
        }
    };
    // issue a 2-row (y0-d, y0+d) load batch into registers
    i32x4 Rp[NIT2];
    auto issue_pair = [&](int d) {
#pragma unroll
        for (int it = 0; it < NIT2; ++it) {
            const int u = tid + it * 256;
            i32x4 v = {0,0,0,0};
            if (u < 2 * NG1) {
                const int r = (u >= NG1) ? 1 : 0;
                const int uu = u - r * NG1;
                const int slot = uu & (SGR - 1), px = uu / SGR;
                const int yy = y0 + (r ? d : -d);
                const int xx = x0 - 3 + px;
                if ((unsigned)yy < 256u && (unsigned)xx < 256u)
                    v = *(const i32x4*)(inb + (size_t)(yy * 256 + xx) * CPIN + slot * 8);
            }
            Rp[it] = v;
        }
    };
    auto write_pair = [&]() {
#pragma unroll
        for (int it = 0; it < NIT2; ++it) {
            const int u = tid + it * 256;
            if (u < 2 * NG1) {
                const int r = (u >= NG1) ? 1 : 0;
                const int uu = u - r * NG1;
                const int slot = uu & (SGR - 1), px = uu / SGR;
                *(i32x4*)&sm[(((1 + r) * SPX + px) * SGRP + slot) * 4] = Rp[it];
            }
        }
    };
    // one dilated conv from the staged window, epilogue into the LDS out tile
    auto do_conv = [&](int d, const unsigned short* wfx, const float* bs, int which) {
        const short8* wp = (const short8*)wfx;
        f32x4 acc[MT_];
#pragma unroll
        for (int mt = 0; mt < MT_; ++mt) acc[mt] = (f32x4){0.f,0.f,0.f,0.f};
#pragma unroll
        for (int tap = 0; tap < 9; ++tap) {
            const int dy = tap / 3 - 1, dx = tap % 3 - 1;
            const int rl = (dy == 0) ? 0 : (dy < 0 ? 1 : 2);
            short8 af[MT_][KK];
#pragma unroll
            for (int mt = 0; mt < MT_; ++mt)
#pragma unroll
                for (int kk = 0; kk < KK; ++kk)
                    af[mt][kk] = wp[((tap * MT_ + mt) * KK + kk) * 64 + lane];
            const int pl = 3 + wv * 16 + col + dx * d;
#pragma unroll
            for (int kk = 0; kk < KK; ++kk) {
                short8 bf = *(const short8*)&sm[((rl * SPX + pl) * SGRP + kk * 4 + g) * 4];
#pragma unroll
                for (int mt = 0; mt < MT_; ++mt)
                    acc[mt] = __builtin_amdgcn_mfma_f32_16x16x32_bf16(af[mt][kk], bf, acc[mt], 0, 0, 0);
            }
        }
        const int px = wv * 16 + col;
#pragma unroll
        for (int mt = 0; mt < MT_; ++mt)
#pragma unroll
            for (int e = 0; e < 2; ++e) {
                const int rb = mt * 16 + g * 4 + e * 2;
                if (rb < MR) {
                    float v0 = acc[mt][e * 2]     + __ldg(bs + rb);
                    float v1 = acc[mt][e * 2 + 1] + ((rb + 1 < MR) ? __ldg(bs + rb + 1) : 0.f);
                    if (rb + 1 >= MR) v1 = 0.f;
                    sm[OUTOFF + px * ODP + ((which * MR + rb) >> 1)] = pack2(v0, v1);
                }
            }
    };

    stage_row(0, y0); stage_row(1, y0 - 1); stage_row(2, y0 + 1);
    issue_pair(2);                       // y∓2 in flight during d=1 compute
    if (tid < 64) {
#pragma unroll
        for (int dwp = 3 * MR / 2; dwp < CPP * 4; ++dwp) sm[OUTOFF + tid * ODP + dwp] = 0;
    }
    __syncthreads();

    do_conv(1, wf0, b0, 0);
    __syncthreads();
    write_pair();                        // land y∓2
    issue_pair(3);                       // y∓3 in flight during d=2 compute
    __syncthreads();

    do_conv(2, wf1, b1, 1);
    __syncthreads();
    write_pair();                        // land y∓3
    __syncthreads();

    do_conv(3, wf2, b2, 2);
    __syncthreads();

    for (int u = tid; u < 64 * CPP; u += 256) {
        const int slot = u & (CPP - 1), opx = u / CPP;
        i32x4 v = *(i32x4*)&sm[OUTOFF + opx * ODP + slot * 4];
        const size_t go = ((size_t)b * HW + (size_t)y0 * 256 + x0 + opx) * CPAD + slot * 8;
        *(i32x4*)(outb + go) = v;
    }
}

// ---------------------------------------------------------------------------
// Staged fused AFLB (+1-granule-pad LDS).
// ---------------------------------------------------------------------------
template<int KK, int RPB, int RES>
__global__ __launch_bounds__(256, 4) void aflb_p(
    const unsigned short* __restrict__ in,
    const unsigned short* __restrict__ awf, const float* __restrict__ ab,
    const unsigned short* __restrict__ fwf,
    const unsigned short* __restrict__ res,
    unsigned short* __restrict__ outb)
{
    constexpr int CPIN = KK * 32, MTT = 2 * KK, CPAD = 16 * MTT;
    constexpr int SROWS = RPB + 2, SPX = 66, SGR = KK * 4, SGRP = SGR + 1;
    constexpr int CPP = CPAD / 8, ODP = (CPP + 1) * 4;
    constexpr int NSTGDW = SROWS * SPX * SGRP * 4;
    constexpr int ATOFF = NSTGDW;
    constexpr int NATT = RPB * 64 * 9;
    constexpr int OUTOFF = ATOFF + NATT;
    __shared__ __align__(16) unsigned int sm[OUTOFF + RPB * 64 * ODP];

    const int tid = threadIdx.x;
    const int lane = tid & 63, wv = tid >> 6;
    const int col = lane & 15, g = lane >> 4;
    const int bx = blockIdx.x;
    const int xcd = bx & 7, t = bx >> 3;
    const int y0 = (RPB == 1) ? (xcd * 32 + (t & 31)) : (xcd * 32 + (t & 15) * 2);
    const int xseg = (RPB == 1) ? ((t >> 5) & 3) : ((t >> 4) & 3);
    const int x0 = xseg * 64;
    const int b = blockIdx.z;
    const unsigned short* inb = in + (size_t)b * HW * CPIN;

    for (int u = tid; u < SROWS * SPX * SGR; u += 256) {
        const int slot = u & (SGR - 1);
        const int px = (u / SGR) % SPX;
        const int row = u / (SGR * SPX);
        const int yy = y0 + row - 1, xx = x0 - 1 + px;
        i32x4 v = {0,0,0,0};
        if ((unsigned)yy < 256u && (unsigned)xx < 256u)
            v = *(const i32x4*)(inb + (size_t)(yy * 256 + xx) * CPIN + slot * 8);
        *(i32x4*)&sm[((row * SPX + px) * SGRP + slot) * 4] = v;
    }
    __syncthreads();

    const short8* awp = (const short8*)awf;
    const short8* fwp = (const short8*)fwf;

    constexpr int NF1 = (RPB == 1) ? 1 : 2;
    const int arow = (RPB == 1) ? 0 : (wv >> 1);
    const int apx0 = (RPB == 1) ? (wv * 16) : ((wv & 1) * 32);
    f32x4 aacc[NF1];
#pragma unroll
    for (int nf = 0; nf < NF1; ++nf) aacc[nf] = (f32x4){0.f,0.f,0.f,0.f};
#pragma unroll
    for (int tap = 0; tap < 9; ++tap) {
        const int dy = tap / 3 - 1, dx = tap % 3 - 1;
        const int rl = arow + dy + 1;
        short8 afa[KK];
#pragma unroll
        for (int kk = 0; kk < KK; ++kk)
            afa[kk] = awp[(tap * KK + kk) * 64 + lane];
#pragma unroll
        for (int nf = 0; nf < NF1; ++nf) {
            const int pl = 1 + apx0 + nf * 16 + col + dx;
#pragma unroll
            for (int kk = 0; kk < KK; ++kk) {
                short8 bf = *(const short8*)&sm[((rl * SPX + pl) * SGRP + kk * 4 + g) * 4];
                aacc[nf] = __builtin_amdgcn_mfma_f32_16x16x32_bf16(afa[kk], bf, aacc[nf], 0, 0, 0);
            }
        }
    }
#pragma unroll
    for (int nf = 0; nf < NF1; ++nf) {
        float v[4];
        float m = -1e30f;
#pragma unroll
        for (int r = 0; r < 4; ++r) {
            const int row = g * 4 + r;
            v[r] = (row < 9) ? (aacc[nf][r] + __ldg(ab + row)) : -1e30f;
            m = fmaxf(m, v[r]);
        }
        m = fmaxf(m, __shfl_xor(m, 16));
        m = fmaxf(m, __shfl_xor(m, 32));
        float e[4]; float s = 0.f;
#pragma unroll
        for (int r = 0; r < 4; ++r) { e[r] = (g * 4 + r < 9) ? __expf(v[r] - m) : 0.f; s += e[r]; }
        s += __shfl_xor(s, 16);
        s += __shfl_xor(s, 32);
        const float inv = 1.f / s;
        const int px = apx0 + nf * 16 + col;
#pragma unroll
        for (int r = 0; r < 4; ++r) {
            const int row = g * 4 + r;
            if (row < 9) sm[ATOFF + (arow * 64 + px) * 9 + row] = __float_as_uint(e[r] * inv);
        }
    }
    __syncthreads();

    const int prow = (RPB == 1) ? 0 : (wv >> 1);
    const int mt = (RPB == 1) ? wv : (wv & 1);
    f32x4 acc[4];
#pragma unroll
    for (int nf = 0; nf < 4; ++nf) acc[nf] = (f32x4){0.f,0.f,0.f,0.f};
#pragma unroll
    for (int tap = 0; tap < 9; ++tap) {
        const int dy = tap / 3 - 1, dx = tap % 3 - 1;
        const int rl = prow + dy + 1;
        float av[4];
#pragma unroll
        for (int nf = 0; nf < 4; ++nf)
            av[nf] = __uint_as_float(sm[ATOFF + (prow * 64 + nf * 16 + col) * 9 + tap]);
        short8 af[KK];
#pragma unroll
        for (int kk = 0; kk < KK; ++kk)
            af[kk] = fwp[((tap * MTT + mt) * KK + kk) * 64 + lane];
#pragma unroll
        for (int nf = 0; nf < 4; ++nf) {
            const int pl = 1 + nf * 16 + col + dx;
            f32x4 p = (f32x4){0.f,0.f,0.f,0.f};
#pragma unroll
            for (int kk = 0; kk < KK; ++kk) {
                short8 bf = *(const short8*)&sm[((rl * SPX + pl) * SGRP + kk * 4 + g) * 4];
                p = __builtin_amdgcn_mfma_f32_16x16x32_bf16(af[kk], bf, p, 0, 0, 0);
            }
#pragma unroll
            for (int r = 0; r < 4; ++r)
                acc[nf][r] = fmaf(av[nf], p[r], acc[nf][r]);
        }
    }
    __syncthreads();

#pragma unroll
    for (int nf = 0; nf < 4; ++nf) {
        const int px = nf * 16 + col;
        const int base = OUTOFF + ((RPB == 2 ? prow * 64 : 0) + px) * ODP;
        const int rp = mt * 8 + g * 2;
        unsigned long long w =
            (unsigned long long)pack2(acc[nf][0], acc[nf][1]) |
            ((unsigned long long)pack2(acc[nf][2], acc[nf][3]) << 32);
        *(unsigned long long*)&sm[base + rp] = w;
    }
    __syncthreads();

    constexpr int NOUT = RPB * 64 * CPP;
    for (int u = tid; u < NOUT; u += 256) {
        const int slot = u & (CPP - 1);
        const int px = (u / CPP) & 63;
        const int r = (RPB == 2) ? (u / (CPP * 64)) : 0;
        i32x4 v = *(i32x4*)&sm[OUTOFF + ((r * 64 + px) * ODP) + slot * 4];
        const size_t go = ((size_t)b * HW + (size_t)(y0 + r) * 256 + x0 + px) * CPAD + slot * 8;
        if (RES) v = addrelu4(v, *(const i32x4*)(res + go));
        *(i32x4*)(outb + go) = v;
    }
}

// ---------------------------------------------------------------------------
// Final conv 30->4 + ms_up, f32 NCHW output.
// ---------------------------------------------------------------------------
__global__ __launch_bounds__(256, 4) void final_k(
    const unsigned short* __restrict__ in,
    const unsigned short* __restrict__ wfrag,
    const float* __restrict__ bias,
    const float* __restrict__ msup, float* __restrict__ outf)
{
    constexpr int CPIN = 32, NF = 2;
    const int lane = threadIdx.x & 63, wv = threadIdx.x >> 6;
    const int col = lane & 15, g = lane >> 4;
    const int bx = blockIdx.x;
    const int xcd = bx & 7, t = bx >> 3;
    const int y = xcd * 32 + (t & 31);
    const int xh = t >> 5;
    const int b = blockIdx.z;
    const int x0 = xh * 128 + wv * 32;

    const unsigned short* inb = in + (size_t)b * HW * CPIN;
    const short8 kz = {0,0,0,0,0,0,0,0};
    const short8* wp = (const short8*)wfrag;

    f32x4 acc[NF];
#pragma unroll
    for (int nf = 0; nf < NF; ++nf) acc[nf] = (f32x4){0.f,0.f,0.f,0.f};
#pragma unroll
    for (int tap = 0; tap < 9; ++tap) {
        const int dy = tap / 3 - 1, dx = tap % 3 - 1;
        const int yy = y + dy;
        const bool yok = (unsigned)yy < 256u;
        const short8 af = wp[tap * 64 + lane];
#pragma unroll
        for (int nf = 0; nf < NF; ++nf) {
            const int xx = x0 + nf * 16 + col + dx;
            const bool ok = yok && ((unsigned)xx < 256u);
            const int pix = ok ? (yy * 256 + xx) : 0;
            short8 bf = *(const short8*)(inb + (size_t)pix * CPIN + g * 8);
            if (!ok) bf = kz;
            acc[nf] = __builtin_amdgcn_mfma_f32_16x16x32_bf16(af, bf, acc[nf], 0, 0, 0);
        }
    }
#pragma unroll
    for (int nf = 0; nf < NF; ++nf) {
        const int pix = y * 256 + x0 + nf * 16 + col;
        if (g == 0) {
#pragma unroll
            for (int r = 0; r < 4; ++r) {
                const size_t oi = ((size_t)b * 4 + r) * HW + pix;
                outf[oi] = acc[nf][r] + __ldg(bias + r) + msup[oi];
            }
        }
    }
}

// ---------------------------------------------------------------------------
// Weight prep (parallel, shift-based indexing).
// ---------------------------------------------------------------------------
struct PrepDesc { const float* src; int cout, cin, kksh, mtsh, flags, dstoff, n; };
struct PrepArgs { PrepDesc d[18]; };

__global__ __launch_bounds__(256) void prep_k(PrepArgs pa, unsigned short* __restrict__ wb)
{
    const PrepDesc d = pa.d[blockIdx.y];
    const int e = blockIdx.x * 256 + threadIdx.x;
    if (e >= d.n) return;
    const int j = e & 7;
    const int lane = (e >> 3) & 63;
    const int i512 = e >> 9;
    const int kk = i512 & ((1 << d.kksh) - 1);
    const int mt = (i512 >> d.kksh) & ((1 << d.mtsh) - 1);
    const int tap = i512 >> (d.kksh + d.mtsh);
    const int rpos = mt * 16 + (lane & 15);
    const int kpos = kk * 32 + (lane >> 4) * 8 + j;
    int o = rpos, ic = kpos;
    bool ok = true;
    if (d.flags & 2) {
        if (rpos < 30) o = rpos;
        else if (rpos >= 32 && rpos < 62) o = rpos - 2;
        else ok = false;
    }
    if (d.flags & 1) {
        if (kpos < 30) ic = kpos;
        else if (kpos >= 32 && kpos < 62) ic = kpos - 2;
        else ok = false;
    }
    float v = 0.f;
    if (ok && o < d.cout && ic < d.cin) v = d.src[(o * d.cin + ic) * 9 + tap];
    wb[d.dstoff + e] = f2bf(v);
}

// ---------------------------------------------------------------------------
// up-conv (ms_org 4->64 @64x64, f32 NCHW) — small, VALU direct conv.
// ---------------------------------------------------------------------------
template<int CIN, int COUT, int OCB, int H, int W>
__launch_bounds__(256)
__global__ void upconv_k(const float* __restrict__ in, const float* __restrict__ wgt,
                         const float* __restrict__ bias, float* __restrict__ out)
{
    constexpr int HWp = H * W;
    constexpr int NOCB = COUT / OCB;
    const int tx = threadIdx.x;
    const int lx = tx & 63, ly = tx >> 6;
    const int gx = blockIdx.x * 64 + lx;
    const int gy = blockIdx.y * 4 + ly;
    const int b = blockIdx.z / NOCB;
    const int ocb = blockIdx.z % NOCB;
    const int pixp = gy * W + gx;
    const float* inb = in + (size_t)b * CIN * HWp;

    int off[9]; float mul[9];
#pragma unroll
    for (int dy = 0; dy < 3; ++dy)
#pragma unroll
        for (int dx = 0; dx < 3; ++dx) {
            int p = dy * 3 + dx;
            int yy = gy + dy - 1, xx = gx + dx - 1;
            bool okp = ((unsigned)yy < (unsigned)H) && ((unsigned)xx < (unsigned)W);
            off[p] = okp ? (yy * W + xx) : 0;
            mul[p] = okp ? 1.f : 0.f;
        }
    float acc[OCB];
#pragma unroll
    for (int o = 0; o < OCB; ++o) acc[o] = 0.f;
    const float* wbase = wgt + (size_t)(ocb * OCB) * CIN * 9;
#pragma unroll
    for (int ic = 0; ic < CIN; ++ic) {
        const float* ip = inb + (size_t)ic * HWp;
        float tv[9];
#pragma unroll
        for (int p = 0; p < 9; ++p) tv[p] = __ldg(ip + off[p]) * mul[p];
#pragma unroll
        for (int o = 0; o < OCB; ++o) {
            const float* wq = wbase + (size_t)(o * CIN + ic) * 9;
#pragma unroll
            for (int p = 0; p < 9; ++p) acc[o] = fmaf(tv[p], wq[p], acc[o]);
        }
    }
#pragma unroll
    for (int o = 0; o < OCB; ++o)
        out[((size_t)b * COUT + ocb * OCB + o) * HWp + pixp] = acc[o] + __ldg(bias + ocb * OCB + o);
}

// ---------------------------------------------------------------------------
// Build data1 (prelu(pixshuf(t_up))||pan) and ms_up as NHWC bf16 pad32.
// ---------------------------------------------------------------------------
__global__ __launch_bounds__(256) void build_inputs(
    const float* __restrict__ tup, const float* __restrict__ pan,
    const float* __restrict__ aup, const float* __restrict__ msup,
    unsigned short* __restrict__ data1, unsigned short* __restrict__ msb)
{
    const int i = blockIdx.x * 256 + threadIdx.x;
    const int b = i >> 16, pixp = i & 65535;
    const int y = pixp >> 8, x = pixp & 255;
    unsigned short o[32];
#pragma unroll
    for (int c = 0; c < 32; ++c) o[c] = 0;
    unsigned short* dst;
    if (blockIdx.y == 0) {
        const float a = __ldg(aup);
#pragma unroll
        for (int c = 0; c < 4; ++c) {
            const int ch = c * 16 + (y & 3) * 4 + (x & 3);
            float v = tup[(((size_t)b * 64 + ch) << 12) + ((y >> 2) << 6) + (x >> 2)];
            v = (v >= 0.f) ? v : a * v;
            o[c] = f2bf(v);
        }
        o[4] = f2bf(pan[((size_t)b << 16) + pixp]);
        dst = data1;
    } else {
#pragma unroll
        for (int c = 0; c < 4; ++c)
            o[c] = f2bf(msup[(((size_t)b * 4 + c) << 16) + pixp]);
        dst = msb;
    }
    short8* dp = (short8*)(dst + (size_t)i * 32);
#pragma unroll
    for (int q = 0; q < 4; ++q) {
        short8 s;
#pragma unroll
        for (int r = 0; r < 8; ++r) s[r] = (short)o[q * 8 + r];
        dp[q] = s;
    }
}

// ---------------------------------------------------------------------------
extern "C" void kernel_launch(void* const* d_in, const int* in_sizes, int n_in,
                              void* d_out, int out_size, void* d_ws, size_t ws_size,
                              hipStream_t stream) {
    const float* ms_up  = (const float*)d_in[0];
    const float* ms_org = (const float*)d_in[1];
    const float* pan    = (const float*)d_in[2];
    const float* w_up4  = (const float*)d_in[3];
    const float* b_up4  = (const float*)d_in[4];
    const float* a_up4  = (const float*)d_in[5];
    const float* w_blk53= (const float*)d_in[6];
    const float* b_blk53= (const float*)d_in[7];
    const float* a_blk53= (const float*)d_in[8];
    const float* w_blk43= (const float*)d_in[9];
    const float* b_blk43= (const float*)d_in[10];
    const float* a_blk43= (const float*)d_in[11];
    const float* w1a=(const float*)d_in[12]; const float* b1a=(const float*)d_in[13];
    const float* w1b=(const float*)d_in[14]; const float* b1b=(const float*)d_in[15];
    const float* w1c=(const float*)d_in[16]; const float* b1c=(const float*)d_in[17];
    const float* aw1=(const float*)d_in[18]; const float* ab1=(const float*)d_in[19];
    const float* fw1=(const float*)d_in[20];
    const float* aw2=(const float*)d_in[21]; const float* ab2=(const float*)d_in[22];
    const float* fw2=(const float*)d_in[23];
    const float* w_blk2=(const float*)d_in[24]; const float* b_blk2=(const float*)d_in[25]; const float* a_blk2=(const float*)d_in[26];
    const float* w2a=(const float*)d_in[27]; const float* b2a=(const float*)d_in[28];
    const float* w2b=(const float*)d_in[29]; const float* b2b=(const float*)d_in[30];
    const float* w2c=(const float*)d_in[31]; const float* b2c=(const float*)d_in[32];
    const float* aw3=(const float*)d_in[33]; const float* ab3=(const float*)d_in[34];
    const float* fw3=(const float*)d_in[35];
    const float* aw4=(const float*)d_in[36]; const float* ab4=(const float*)d_in[37];
    const float* fw4=(const float*)d_in[38];
    const float* w_c6=(const float*)d_in[39]; const float* b_c6=(const float*)d_in[40];

    float* out = (float*)d_out;
    char* ws = (char*)d_ws;

    const size_t BIG = (size_t)2 * HW * 64 * 2;   // 16.78 MB (NHWC pad64 bf16)
    const size_t HALF = BIG / 2;
    unsigned short* bufA = (unsigned short*)(ws);
    unsigned short* bufB = (unsigned short*)(ws + BIG);
    unsigned short* bufC = (unsigned short*)(ws + 2 * BIG);
    unsigned short* data1 = bufC;
    float*          t_up  = (float*)(ws + 2 * BIG + HALF);
    unsigned short* msb   = bufB;
    unsigned short* bufD = bufC;
    unsigned short* bufE = bufB;
    unsigned short* bufF = bufA;
    unsigned short* wb = (unsigned short*)(ws + 3 * BIG);

    if (ws_size < 3 * BIG + 1000000) return;

    PrepArgs pa;
    int off = 0, li = 0;
    auto add = [&](const float* s, int cout, int cin, int mtsh, int kksh, int flags) {
        const int n = 9 << (mtsh + kksh + 9);
        pa.d[li].src = s; pa.d[li].cout = cout; pa.d[li].cin = cin;
        pa.d[li].kksh = kksh; pa.d[li].mtsh = mtsh; pa.d[li].flags = flags;
        pa.d[li].dstoff = off; pa.d[li].n = n;
        int ret = off; off += n; ++li; return ret;
    };
    const int o_blk43 = add(w_blk43, 30, 4, 1, 0, 0);
    const int o_blk53 = add(w_blk53, 30, 5, 1, 0, 0);
    const int o_w1a   = add(w1a, 20, 60, 1, 1, 1);
    const int o_w1b   = add(w1b, 20, 60, 1, 1, 1);
    const int o_w1c   = add(w1c, 20, 60, 1, 1, 1);
    const int o_aw1   = add(aw1,  9, 60, 0, 1, 0);
    const int o_fw1   = add(fw1, 60, 60, 2, 1, 0);
    const int o_aw2   = add(aw2,  9, 60, 0, 1, 0);
    const int o_fw2   = add(fw2, 60, 60, 2, 1, 2);
    const int o_blk2  = add(w_blk2, 30, 60, 1, 1, 1);
    const int o_w2a   = add(w2a, 10, 30, 0, 0, 0);
    const int o_w2b   = add(w2b, 10, 30, 0, 0, 0);
    const int o_w2c   = add(w2c, 10, 30, 0, 0, 0);
    const int o_aw3   = add(aw3,  9, 30, 0, 0, 0);
    const int o_fw3   = add(fw3, 30, 30, 1, 0, 0);
    const int o_aw4   = add(aw4,  9, 30, 0, 0, 0);
    const int o_fw4   = add(fw4, 30, 30, 1, 0, 0);
    const int o_c6    = add(w_c6,  4, 30, 0, 0, 0);

    prep_k<<<dim3(144, 18), 256, 0, stream>>>(pa, wb);

    upconv_k<4, 64, 16, 64, 64><<<dim3(1, 16, 8), 256, 0, stream>>>(ms_org, w_up4, b_up4, t_up);
    build_inputs<<<dim3(512, 2), 256, 0, stream>>>(t_up, pan, a_up4, ms_up, data1, msb);

    const dim3 B256(256);
    const dim3 G1(1024, 1, 2);   // 64-px staged kernels
    const dim3 GH(512, 1, 2);    // RPB=2 staged / final

    // out1 (bufA, pad64, split-60): blk43 -> rows 0..29, blk53 -> rows 32..61
    sconv_k<1,1><<<G1,B256,0,stream>>>(msb,   wb+o_blk43, b_blk43, a_blk43, bufA, 64, 0);
    sconv_k<1,1><<<G1,B256,0,stream>>>(data1, wb+o_blk53, b_blk53, a_blk53, bufA, 64, 32);

    // ---- rmrs1 (60 ch) ----
    trident_s<2,20><<<G1,B256,0,stream>>>(bufA, wb+o_w1a, wb+o_w1b, wb+o_w1c, b1a, b1b, b1c, bufB);
    aflb_p<2,1,0><<<G1,B256,0,stream>>>(bufB, wb+o_aw1, ab1, wb+o_fw1, nullptr, bufC);
    aflb_p<2,1,1><<<G1,B256,0,stream>>>(bufC, wb+o_aw2, ab2, wb+o_fw2, bufA,   bufB);

    // blk2: out2 -> 30ch (bufD pad32)
    sconv_k<2,1><<<G1,B256,0,stream>>>(bufB, wb+o_blk2, b_blk2, a_blk2, bufD, 32, 0);

    // ---- rmrs2 (30 ch) ----
    trident_s<1,10><<<G1,B256,0,stream>>>(bufD, wb+o_w2a, wb+o_w2b, wb+o_w2c, b2a, b2b, b2c, bufE);
    aflb_p<1,2,0><<<GH,B256,0,stream>>>(bufE, wb+o_aw3, ab3, wb+o_fw3, nullptr, bufF);
    aflb_p<1,2,1><<<GH,B256,0,stream>>>(bufF, wb+o_aw4, ab4, wb+o_fw4, bufD,   bufE);

    // final: conv 30->4 + ms_up (f32 NCHW out)
    final_k<<<GH,B256,0,stream>>>(bufE, wb+o_c6, b_c6, ms_up, out);
}